// Round 1
// baseline (2153.950 us; speedup 1.0000x reference)
//
#include <hip/hip_runtime.h>
#include <math.h>

#define NV 6
#define FHH 32
#define FWW 96
#define PIMG (FHH*FWW)   // 3072
#define HH 64
#define WWD 64
#define PBEV (HH*WWD)    // 4096
#define HEADS 4
#define DHD 32
#define KROWS 288        // 6*4*12 keys per window
#define BN_S 0.9999950000374996f
#define LN_EPS 1e-5f
#define ATT_SCALE 0.17677669529663687f  // 32^-0.5

__device__ __forceinline__ float gelu_f(float x) {
    return 0.5f * x * (1.0f + erff(x * 0.70710678118654752f));
}

// block reduce over 128 threads (2 waves)
__device__ __forceinline__ float blockSum128(float v, float* red, int tid) {
    #pragma unroll
    for (int o = 32; o > 0; o >>= 1) v += __shfl_down(v, o, 64);
    __syncthreads();
    if ((tid & 63) == 0) red[tid >> 6] = v;
    __syncthreads();
    return red[0] + red[1];
}

// ---------------- geometry: key/val  [n][h][w][128] channel-last ----------------
__global__ void k_imgkv(const float* __restrict__ feature, const float* __restrict__ I_inv,
                        const float* __restrict__ E_inv, const float* __restrict__ ie_w,
                        const float* __restrict__ ce_w, const float* __restrict__ fp_w,
                        const float* __restrict__ fl_w,
                        float* __restrict__ key, float* __restrict__ val) {
    const int TILE = 16;
    int n  = blockIdx.y;
    int p0 = blockIdx.x * TILE;
    int tid = threadIdx.x;            // 0..127 (= channel d)
    __shared__ float fsh[TILE][128];
    __shared__ float red[2];

    for (int pos = 0; pos < TILE; ++pos) {
        float fv = feature[((size_t)(n * 128 + tid)) * PIMG + p0 + pos];
        fsh[pos][tid] = fmaxf(fv * BN_S, 0.0f);
    }
    const float* E  = E_inv + n * 16;
    const float* Ii = I_inv + n * 9;
    float cemb = E[3]  * ce_w[tid*4+0] + E[7]  * ce_w[tid*4+1]
               + E[11] * ce_w[tid*4+2] + E[15] * ce_w[tid*4+3];
    __syncthreads();

    for (int pos = 0; pos < TILE; ++pos) {
        int p = p0 + pos;
        int h = p / FWW, w = p % FWW;
        float gx = (float)w * (768.0f / 95.0f);
        float gy = (float)h * (256.0f / 31.0f);
        float c0 = Ii[0]*gx + Ii[1]*gy + Ii[2];
        float c1 = Ii[3]*gx + Ii[4]*gy + Ii[5];
        float c2 = Ii[6]*gx + Ii[7]*gy + Ii[8];
        float d0 = E[0]*c0  + E[1]*c1  + E[2]*c2  + E[3];
        float d1 = E[4]*c0  + E[5]*c1  + E[6]*c2  + E[7];
        float d2 = E[8]*c0  + E[9]*c1  + E[10]*c2 + E[11];
        float d3 = E[12]*c0 + E[13]*c1 + E[14]*c2 + E[15];
        float emb = d0*ie_w[tid*4+0] + d1*ie_w[tid*4+1]
                  + d2*ie_w[tid*4+2] + d3*ie_w[tid*4+3] - cemb;
        float ss = blockSum128(emb * emb, red, tid);
        float imgn = emb / (sqrtf(ss) + 1e-7f);

        float ka = imgn, va = 0.0f;
        const float* fpr = fp_w + tid * 128;
        const float* flr = fl_w + tid * 128;
        #pragma unroll 8
        for (int c = 0; c < 128; ++c) {
            float fc = fsh[pos][c];
            ka += fc * fpr[c];
            va += fc * flr[c];
        }
        size_t o = ((size_t)(n * PIMG + p)) * 128 + tid;
        key[o] = ka;
        val[o] = va;
    }
}

// ---------------- query  [n][h][w][128] ----------------
__global__ void k_query(const float* __restrict__ x, const float* __restrict__ bev,
                        const float* __restrict__ be_w, const float* __restrict__ be_b,
                        const float* __restrict__ E_inv, const float* __restrict__ ce_w,
                        float* __restrict__ query) {
    const int TILE = 16;
    int n  = blockIdx.y;
    int p0 = blockIdx.x * TILE;
    int tid = threadIdx.x;
    __shared__ float red[2];
    const float* E = E_inv + n * 16;
    float cemb = E[3]  * ce_w[tid*4+0] + E[7]  * ce_w[tid*4+1]
               + E[11] * ce_w[tid*4+2] + E[15] * ce_w[tid*4+3];
    float bw0 = be_w[tid*2+0], bw1 = be_w[tid*2+1], bb = be_b[tid];
    for (int pos = 0; pos < TILE; ++pos) {
        int p = p0 + pos;
        float emb = bev[p]*bw0 + bev[PBEV + p]*bw1 + bb - cemb;
        float ss = blockSum128(emb * emb, red, tid);
        float qv = emb / (sqrtf(ss) + 1e-7f) + x[(size_t)tid * PBEV + p];
        query[((size_t)(n * PBEV + p)) * 128 + tid] = qv;
    }
}

// ---------------- LN + 128x128 projection (row-wise) ----------------
__global__ void k_lnproj(const float* __restrict__ in, const float* __restrict__ W,
                         const float* __restrict__ b, float* __restrict__ out) {
    const int ROWS = 8;
    int tid = threadIdx.x;   // 128
    __shared__ float ln[128];
    __shared__ float red[2];
    for (int rr = 0; rr < ROWS; ++rr) {
        size_t r = (size_t)blockIdx.x * ROWS + rr;
        float xv = in[r * 128 + tid];
        float mu  = blockSum128(xv, red, tid) * (1.0f / 128.0f);
        float d   = xv - mu;
        float var = blockSum128(d * d, red, tid) * (1.0f / 128.0f);
        float lv  = d * rsqrtf(var + LN_EPS);
        __syncthreads();
        ln[tid] = lv;
        __syncthreads();
        float acc = b[tid];
        const float* wr = W + tid * 128;
        #pragma unroll 8
        for (int i = 0; i < 128; ++i) acc += ln[i] * wr[i];
        out[r * 128 + tid] = acc;
    }
}

// ---------------- attention core (per window l, per head m) ----------------
// MODE 1: attn1, Q=384 (q rows differ per view). MODE 2: attn2, Q=64 (broadcast q).
template <int MODE>
__global__ void k_attn(const float* __restrict__ qh, const float* __restrict__ kh,
                       const float* __restrict__ vh, float* __restrict__ a_out) {
    const int Q = (MODE == 1) ? 384 : 64;
    int l  = blockIdx.x;          // 0..63
    int m  = blockIdx.y;          // head
    int xw = l >> 3, yw = l & 7;
    int tid = threadIdx.x;        // blockDim == Q

    __shared__ float khl[KROWS * DHD];
    __shared__ float vhl[KROWS * DHD];

    for (int idx = tid; idx < KROWS * DHD; idx += Q) {
        int row = idx >> 5, j = idx & 31;
        int n = row / 48, kk = row % 48;
        int k1 = kk / 12, k2 = kk % 12;
        int h, w;
        if (MODE == 1) { h = xw * 4 + k1;  w = yw * 12 + k2; }
        else           { h = k1 * 8 + xw;  w = k2 * 8 + yw;  }
        size_t src = ((size_t)((n * FHH + h) * FWW + w)) * 128 + m * DHD + j;
        khl[idx] = kh[src];
        vhl[idx] = vh[src];
    }

    float qr[DHD];
    {
        size_t qrow;
        if (MODE == 1) {
            int n = tid / 64, ww = tid % 64;
            int w1 = ww >> 3, w2 = ww & 7;
            int h = xw * 8 + w1, w = yw * 8 + w2;
            qrow = (size_t)(n * PBEV + h * WWD + w);
        } else {
            int w1 = tid >> 3, w2 = tid & 7;
            int h = w1 * 8 + xw, w = w2 * 8 + yw;
            qrow = (size_t)(h * WWD + w);
        }
        const float* qp = qh + qrow * 128 + m * DHD;
        #pragma unroll
        for (int j = 0; j < DHD; ++j) qr[j] = qp[j];
    }
    __syncthreads();

    // pass 1: running max + sum
    float mmax = -1e30f, ssum = 0.0f;
    for (int k = 0; k < KROWS; ++k) {
        const float* kp = khl + k * DHD;
        float s0 = 0.f, s1 = 0.f, s2 = 0.f, s3 = 0.f;
        #pragma unroll
        for (int j = 0; j < DHD; j += 4) {
            s0 += qr[j+0] * kp[j+0];
            s1 += qr[j+1] * kp[j+1];
            s2 += qr[j+2] * kp[j+2];
            s3 += qr[j+3] * kp[j+3];
        }
        float d = ((s0 + s1) + (s2 + s3)) * ATT_SCALE;
        float nm = fmaxf(mmax, d);
        ssum = ssum * __expf(mmax - nm) + __expf(d - nm);
        mmax = nm;
    }
    // pass 2: weighted V accumulation
    float acc[DHD];
    #pragma unroll
    for (int j = 0; j < DHD; ++j) acc[j] = 0.0f;
    for (int k = 0; k < KROWS; ++k) {
        const float* kp = khl + k * DHD;
        float s0 = 0.f, s1 = 0.f, s2 = 0.f, s3 = 0.f;
        #pragma unroll
        for (int j = 0; j < DHD; j += 4) {
            s0 += qr[j+0] * kp[j+0];
            s1 += qr[j+1] * kp[j+1];
            s2 += qr[j+2] * kp[j+2];
            s3 += qr[j+3] * kp[j+3];
        }
        float d = ((s0 + s1) + (s2 + s3)) * ATT_SCALE;
        float p = __expf(d - mmax);
        const float* vp = vhl + k * DHD;
        #pragma unroll
        for (int j = 0; j < DHD; ++j) acc[j] += p * vp[j];
    }
    float inv = 1.0f / ssum;
    float* ap = a_out + ((size_t)(l * Q + tid)) * 128 + m * DHD;
    #pragma unroll
    for (int j = 0; j < DHD; ++j) ap[j] = acc[j] * inv;
}

// ---------------- attention output proj (+mean over views for MODE1) + skip ----------------
// MODE 1: mean over 6 views, skip = x (channel-first), window h=x*8+w1.
// MODE 2: no mean, skip = q_img (channel-last), grid window h=w1*8+x.
template <int MODE>
__global__ void k_projout(const float* __restrict__ a, const float* __restrict__ pw,
                          const float* __restrict__ pb, const float* __restrict__ skip,
                          float* __restrict__ out) {
    const int ROWS = 8;
    int tid = threadIdx.x;   // 128
    __shared__ float ar[128];
    for (int rr = 0; rr < ROWS; ++rr) {
        int r = blockIdx.x * ROWS + rr;     // 0..4095
        int l = r >> 6, ww = r & 63;
        int xw = l >> 3, yw = l & 7, w1 = ww >> 3, w2 = ww & 7;
        int h, w;
        if (MODE == 1) { h = xw * 8 + w1; w = yw * 8 + w2; }
        else           { h = w1 * 8 + xw; w = w2 * 8 + yw; }
        float av;
        if (MODE == 1) {
            float s = 0.0f;
            #pragma unroll
            for (int n = 0; n < 6; ++n)
                s += a[((size_t)(l * 384) + n * 64 + ww) * 128 + tid];
            av = s * (1.0f / 6.0f);
        } else {
            av = a[((size_t)(l * 64) + ww) * 128 + tid];
        }
        __syncthreads();
        ar[tid] = av;
        __syncthreads();
        float acc = pb[tid];
        const float* wr = pw + tid * 128;
        #pragma unroll 8
        for (int i = 0; i < 128; ++i) acc += ar[i] * wr[i];
        int hw = h * WWD + w;
        float sk = (MODE == 1) ? skip[(size_t)tid * PBEV + hw]
                               : skip[(size_t)hw * 128 + tid];
        out[(size_t)hw * 128 + tid] = acc + sk;
    }
}

// ---------------- MLP (optionally with LN), residual, in-place ----------------
template <int USE_LN>
__global__ void k_mlp(float* __restrict__ io, const float* __restrict__ W1,
                      const float* __restrict__ b1, const float* __restrict__ W2,
                      const float* __restrict__ b2) {
    const int ROWS = 4;
    int tid = threadIdx.x;   // 128
    __shared__ float xn[128];
    __shared__ float g[256];
    __shared__ float red[2];
    for (int rr = 0; rr < ROWS; ++rr) {
        size_t r = (size_t)blockIdx.x * ROWS + rr;
        float xv = io[r * 128 + tid];
        float nv = xv;
        if (USE_LN) {
            float mu  = blockSum128(xv, red, tid) * (1.0f / 128.0f);
            float d   = xv - mu;
            float var = blockSum128(d * d, red, tid) * (1.0f / 128.0f);
            nv = d * rsqrtf(var + LN_EPS);
        }
        __syncthreads();
        xn[tid] = nv;
        __syncthreads();
        #pragma unroll
        for (int u = tid; u < 256; u += 128) {
            float acc = b1[u];
            const float* wr = W1 + (size_t)u * 128;
            #pragma unroll 8
            for (int i = 0; i < 128; ++i) acc += xn[i] * wr[i];
            g[u] = gelu_f(acc);
        }
        __syncthreads();
        float acc = b2[tid];
        const float* w2r = W2 + (size_t)tid * 256;
        #pragma unroll 8
        for (int j = 0; j < 256; ++j) acc += g[j] * w2r[j];
        io[r * 128 + tid] = xv + acc;
        __syncthreads();
    }
}

// ---------------- postnorm LN + MBConv expand ----------------
__global__ void k_expand(const float* __restrict__ in, const float* __restrict__ ew,
                         float* __restrict__ zln, float* __restrict__ ex) {
    const int ROWS = 4;
    int tid = threadIdx.x;   // 128
    __shared__ float xn[128];
    __shared__ float red[2];
    for (int rr = 0; rr < ROWS; ++rr) {
        size_t r = (size_t)blockIdx.x * ROWS + rr;
        float xv = in[r * 128 + tid];
        float mu  = blockSum128(xv, red, tid) * (1.0f / 128.0f);
        float d   = xv - mu;
        float var = blockSum128(d * d, red, tid) * (1.0f / 128.0f);
        float nv = d * rsqrtf(var + LN_EPS);
        zln[r * 128 + tid] = nv;
        __syncthreads();
        xn[tid] = nv;
        __syncthreads();
        #pragma unroll
        for (int u = tid; u < 512; u += 128) {
            float acc = 0.0f;
            const float* wr = ew + (size_t)u * 128;
            #pragma unroll 8
            for (int i = 0; i < 128; ++i) acc += xn[i] * wr[i];
            ex[r * 512 + u] = gelu_f(acc * BN_S);
        }
        __syncthreads();
    }
}

// ---------------- depthwise 3x3 conv (channel-last) + gelu + SE partial sums ----------------
__global__ void k_dwconv(const float* __restrict__ ex, const float* __restrict__ dwgt,
                         float* __restrict__ dwout, float* __restrict__ separt) {
    const int TILE = 16;
    int ch  = threadIdx.x;          // 0..511
    int hw0 = blockIdx.x * TILE;
    float wreg[9];
    #pragma unroll
    for (int t = 0; t < 9; ++t) wreg[t] = dwgt[ch * 9 + t];
    float sacc = 0.0f;
    for (int t = 0; t < TILE; ++t) {
        int hw = hw0 + t;
        int h = hw >> 6, w = hw & 63;
        float s = 0.0f;
        #pragma unroll
        for (int dy = -1; dy <= 1; ++dy) {
            int h2 = h + dy;
            if (h2 < 0 || h2 >= 64) continue;
            #pragma unroll
            for (int dx = -1; dx <= 1; ++dx) {
                int w2 = w + dx;
                if (w2 < 0 || w2 >= 64) continue;
                s += ex[((size_t)(h2 * 64 + w2)) * 512 + ch] * wreg[(dy + 1) * 3 + (dx + 1)];
            }
        }
        float o = gelu_f(s * BN_S);
        dwout[(size_t)hw * 512 + ch] = o;
        sacc += o;
    }
    separt[(size_t)blockIdx.x * 512 + ch] = sacc;
}

// ---------------- SE: reduce partials -> gelu(s1) -> sigmoid(s2) ----------------
__global__ void k_se(const float* __restrict__ separt, int nparts,
                     const float* __restrict__ s1w, const float* __restrict__ s1b,
                     const float* __restrict__ s2w, const float* __restrict__ s2b,
                     float* __restrict__ se) {
    __shared__ float mean[512];
    __shared__ float s1[32];
    int tid = threadIdx.x;   // 512
    float s = 0.0f;
    for (int b = 0; b < nparts; ++b) s += separt[(size_t)b * 512 + tid];
    mean[tid] = s * (1.0f / 4096.0f);
    __syncthreads();
    if (tid < 32) {
        float acc = s1b[tid];
        const float* wr = s1w + (size_t)tid * 512;
        for (int c = 0; c < 512; ++c) acc += mean[c] * wr[c];
        s1[tid] = gelu_f(acc);
    }
    __syncthreads();
    float acc = s2b[tid];
    const float* wr = s2w + (size_t)tid * 32;
    #pragma unroll
    for (int j = 0; j < 32; ++j) acc += s1[j] * wr[j];
    se[tid] = 1.0f / (1.0f + __expf(-acc));
}

// ---------------- MBConv project + residual (channel-last out) ----------------
__global__ void k_mbproj(const float* __restrict__ dw, const float* __restrict__ se,
                         const float* __restrict__ pw, const float* __restrict__ zln,
                         float* __restrict__ out) {
    const int ROWS = 4;
    int tid = threadIdx.x;  // 128
    __shared__ float col[512];
    for (int rr = 0; rr < ROWS; ++rr) {
        size_t r = (size_t)blockIdx.x * ROWS + rr;
        __syncthreads();
        #pragma unroll
        for (int c = tid; c < 512; c += 128) col[c] = dw[r * 512 + c] * se[c];
        __syncthreads();
        float acc = 0.0f;
        const float* wr = pw + (size_t)tid * 512;
        #pragma unroll 8
        for (int c = 0; c < 512; ++c) acc += col[c] * wr[c];
        out[r * 128 + tid] = acc * BN_S + zln[r * 128 + tid];
    }
}

// ---------------- final projection + gelu + transpose to [D][H*W] ----------------
__global__ void k_projfin(const float* __restrict__ in, const float* __restrict__ W,
                          const float* __restrict__ b, float* __restrict__ out) {
    const int ROWS = 8;
    int tid = threadIdx.x;   // 128
    __shared__ float xr[128];
    for (int rr = 0; rr < ROWS; ++rr) {
        size_t r = (size_t)blockIdx.x * ROWS + rr;   // hw
        __syncthreads();
        xr[tid] = in[r * 128 + tid];
        __syncthreads();
        float acc = b[tid];
        const float* wr = W + (size_t)tid * 128;
        #pragma unroll 8
        for (int i = 0; i < 128; ++i) acc += xr[i] * wr[i];
        out[(size_t)tid * PBEV + r] = gelu_f(acc);
    }
}

extern "C" void kernel_launch(void* const* d_in, const int* in_sizes, int n_in,
                              void* d_out, int out_size, void* d_ws, size_t ws_size,
                              hipStream_t stream) {
    (void)in_sizes; (void)n_in; (void)out_size; (void)ws_size;
    const float* x      = (const float*)d_in[1];
    const float* feat   = (const float*)d_in[2];
    const float* I_inv  = (const float*)d_in[3];
    const float* E_inv  = (const float*)d_in[4];
    const float* bev    = (const float*)d_in[5];
    const float* fl_w   = (const float*)d_in[6];
    const float* fp_w   = (const float*)d_in[7];
    const float* be_w   = (const float*)d_in[8];
    const float* be_b   = (const float*)d_in[9];
    const float* ie_w   = (const float*)d_in[10];
    const float* ce_w   = (const float*)d_in[11];
    const float* a1_qw  = (const float*)d_in[12];
    const float* a1_qb  = (const float*)d_in[13];
    const float* a1_kw  = (const float*)d_in[14];
    const float* a1_kb  = (const float*)d_in[15];
    const float* a1_vw  = (const float*)d_in[16];
    const float* a1_vb  = (const float*)d_in[17];
    const float* a1_pw  = (const float*)d_in[18];
    const float* a1_pb  = (const float*)d_in[19];
    const float* a2_qw  = (const float*)d_in[20];
    const float* a2_qb  = (const float*)d_in[21];
    const float* a2_kw  = (const float*)d_in[22];
    const float* a2_kb  = (const float*)d_in[23];
    const float* a2_vw  = (const float*)d_in[24];
    const float* a2_vb  = (const float*)d_in[25];
    const float* a2_pw  = (const float*)d_in[26];
    const float* a2_pb  = (const float*)d_in[27];
    const float* m1_w1  = (const float*)d_in[28];
    const float* m1_b1  = (const float*)d_in[29];
    const float* m1_w2  = (const float*)d_in[30];
    const float* m1_b2  = (const float*)d_in[31];
    const float* m2_w1  = (const float*)d_in[32];
    const float* m2_b1  = (const float*)d_in[33];
    const float* m2_w2  = (const float*)d_in[34];
    const float* m2_b2  = (const float*)d_in[35];
    const float* mb_ew  = (const float*)d_in[36];
    const float* mb_dw  = (const float*)d_in[37];
    const float* mb_s1w = (const float*)d_in[38];
    const float* mb_s1b = (const float*)d_in[39];
    const float* mb_s2w = (const float*)d_in[40];
    const float* mb_s2b = (const float*)d_in[41];
    const float* mb_pw  = (const float*)d_in[42];
    const float* pm_w1  = (const float*)d_in[43];
    const float* pm_b1  = (const float*)d_in[44];
    const float* pm_w2  = (const float*)d_in[45];
    const float* pm_b2  = (const float*)d_in[46];
    const float* po_w   = (const float*)d_in[47];
    const float* po_b   = (const float*)d_in[48];

    float* ws = (float*)d_ws;
    // arena (floats); stage-based reuse
    float* key    = ws + 0;          // 2359296
    float* val    = ws + 2359296;    // 2359296
    float* query  = ws + 4718592;    // 3145728  -> reused as expand
    float* qh     = ws + 7864320;    // 3145728  (qh1, later qh2)
    float* khb    = ws + 11010048;   // 2359296  (kh1/kh2, later separt/se/mbout)
    float* vhb    = ws + 13369344;   // 2359296
    float* abuf   = ws + 15728640;   // 3145728  (a1/a2, later dwout)
    float* qimg   = ws + 18874368;   // 524288
    float* qimg2  = ws + 19398656;   // 524288
    float* zln    = ws + 19922944;   // 524288
    float* expandb = query;          // 2097152 (query dead)
    float* dwout   = abuf;           // 2097152 (a dead)
    float* separt  = khb;            // 131072  (kh dead)
    float* sebuf   = khb + 131072;   // 512
    float* mbout   = khb + 131584;   // 524288

    // stage 0: geometry + key/val/query
    k_imgkv<<<dim3(PIMG / 16, NV), 128, 0, stream>>>(feat, I_inv, E_inv, ie_w, ce_w,
                                                     fp_w, fl_w, key, val);
    k_query<<<dim3(PBEV / 16, NV), 128, 0, stream>>>(x, bev, be_w, be_b, E_inv, ce_w, query);

    // stage 1: attn1
    k_lnproj<<<24576 / 8, 128, 0, stream>>>(query, a1_qw, a1_qb, qh);
    k_lnproj<<<18432 / 8, 128, 0, stream>>>(key,   a1_kw, a1_kb, khb);
    k_lnproj<<<18432 / 8, 128, 0, stream>>>(val,   a1_vw, a1_vb, vhb);
    k_attn<1><<<dim3(64, HEADS), 384, 0, stream>>>(qh, khb, vhb, abuf);
    k_projout<1><<<512, 128, 0, stream>>>(abuf, a1_pw, a1_pb, x, qimg);
    k_mlp<1><<<1024, 128, 0, stream>>>(qimg, m1_w1, m1_b1, m1_w2, m1_b2);

    // stage 2: attn2 (broadcast queries -> 64 unique rows/window)
    k_lnproj<<<4096 / 8, 128, 0, stream>>>(qimg, a2_qw, a2_qb, qh);
    k_lnproj<<<18432 / 8, 128, 0, stream>>>(key, a2_kw, a2_kb, khb);
    k_lnproj<<<18432 / 8, 128, 0, stream>>>(val, a2_vw, a2_vb, vhb);
    k_attn<2><<<dim3(64, HEADS), 64, 0, stream>>>(qh, khb, vhb, abuf);
    k_projout<2><<<512, 128, 0, stream>>>(abuf, a2_pw, a2_pb, qimg, qimg2);
    k_mlp<1><<<1024, 128, 0, stream>>>(qimg2, m2_w1, m2_b1, m2_w2, m2_b2);

    // stage 3: postnorm + MBConv + FFN + proj_out
    k_expand<<<1024, 128, 0, stream>>>(qimg2, mb_ew, zln, expandb);
    k_dwconv<<<4096 / 16, 512, 0, stream>>>(expandb, mb_dw, dwout, separt);
    k_se<<<1, 512, 0, stream>>>(separt, 4096 / 16, mb_s1w, mb_s1b, mb_s2w, mb_s2b, sebuf);
    k_mbproj<<<1024, 128, 0, stream>>>(dwout, sebuf, mb_pw, zln, mbout);
    k_mlp<0><<<1024, 128, 0, stream>>>(mbout, pm_w1, pm_b1, pm_w2, pm_b2);
    k_projfin<<<512, 128, 0, stream>>>(mbout, po_w, po_b, (float*)d_out);
}

// Round 2
// 702.329 us; speedup vs baseline: 3.0669x; 3.0669x over previous
//
#include <hip/hip_runtime.h>
#include <math.h>

#define NV 6
#define FHH 32
#define FWW 96
#define PIMG (FHH*FWW)   // 3072
#define HH 64
#define WWD 64
#define PBEV (HH*WWD)    // 4096
#define HEADS 4
#define DHD 32
#define KROWS 288
#define BN_S 0.9999950000374996f
#define LN_EPS 1e-5f
#define ATT_SCALE 0.17677669529663687f  // 32^-0.5

__device__ __forceinline__ float gelu_f(float x) {
    return 0.5f * x * (1.0f + erff(x * 0.70710678118654752f));
}

__device__ __forceinline__ float blockSum128(float v, float* red, int tid) {
    #pragma unroll
    for (int o = 32; o > 0; o >>= 1) v += __shfl_down(v, o, 64);
    __syncthreads();
    if ((tid & 63) == 0) red[tid >> 6] = v;
    __syncthreads();
    return red[0] + red[1];
}

// ---------- feature transpose + BN*relu : [n][128][3072] -> [n*3072][128] ----------
__global__ void k_trans(const float* __restrict__ feature, float* __restrict__ f_cl) {
    __shared__ float tile[32][33];
    int n = blockIdx.z, c0 = blockIdx.y * 32, p0 = blockIdx.x * 32;
    int tp = threadIdx.x & 31, tg = threadIdx.x >> 5;   // tg 0..7
    #pragma unroll
    for (int i = 0; i < 4; ++i) {
        int c = tg + 8 * i;
        tile[c][tp] = feature[((size_t)(n * 128 + c0 + c)) * PIMG + p0 + tp];
    }
    __syncthreads();
    int cw = threadIdx.x & 31, pg = threadIdx.x >> 5;
    #pragma unroll
    for (int i = 0; i < 4; ++i) {
        int p = pg + 8 * i;
        float v = fmaxf(tile[cw][p] * BN_S, 0.0f);
        f_cl[((size_t)(n * PIMG + p0 + p)) * 128 + c0 + cw] = v;
    }
}

// ---------- geometric image embedding -> kinit [n*3072][128] ----------
__global__ void k_embed(const float* __restrict__ I_inv, const float* __restrict__ E_inv,
                        const float* __restrict__ ie_w, const float* __restrict__ ce_w,
                        float* __restrict__ kinit) {
    const int TILE = 16;
    int n = blockIdx.y, p0 = blockIdx.x * TILE, t = threadIdx.x;
    __shared__ float red[2];
    const float* E  = E_inv + n * 16;
    const float* Ii = I_inv + n * 9;
    float cemb = E[3]  * ce_w[t*4+0] + E[7]  * ce_w[t*4+1]
               + E[11] * ce_w[t*4+2] + E[15] * ce_w[t*4+3];
    for (int pos = 0; pos < TILE; ++pos) {
        int p = p0 + pos;
        int h = p / FWW, w = p % FWW;
        float gx = (float)w * (768.0f / 95.0f);
        float gy = (float)h * (256.0f / 31.0f);
        float c0 = Ii[0]*gx + Ii[1]*gy + Ii[2];
        float c1 = Ii[3]*gx + Ii[4]*gy + Ii[5];
        float c2 = Ii[6]*gx + Ii[7]*gy + Ii[8];
        float d0 = E[0]*c0  + E[1]*c1  + E[2]*c2  + E[3];
        float d1 = E[4]*c0  + E[5]*c1  + E[6]*c2  + E[7];
        float d2 = E[8]*c0  + E[9]*c1  + E[10]*c2 + E[11];
        float d3 = E[12]*c0 + E[13]*c1 + E[14]*c2 + E[15];
        float emb = d0*ie_w[t*4+0] + d1*ie_w[t*4+1]
                  + d2*ie_w[t*4+2] + d3*ie_w[t*4+3] - cemb;
        float ss = blockSum128(emb * emb, red, t);
        kinit[((size_t)(n * PIMG + p)) * 128 + t] = emb / (sqrtf(ss) + 1e-7f);
    }
}

// ---------- query [n*4096][128] ----------
__global__ void k_query(const float* __restrict__ x, const float* __restrict__ bev,
                        const float* __restrict__ be_w, const float* __restrict__ be_b,
                        const float* __restrict__ E_inv, const float* __restrict__ ce_w,
                        float* __restrict__ query) {
    const int TILE = 16;
    int n = blockIdx.y, p0 = blockIdx.x * TILE, t = threadIdx.x;
    __shared__ float red[2];
    const float* E = E_inv + n * 16;
    float cemb = E[3]  * ce_w[t*4+0] + E[7]  * ce_w[t*4+1]
               + E[11] * ce_w[t*4+2] + E[15] * ce_w[t*4+3];
    float bw0 = be_w[t*2+0], bw1 = be_w[t*2+1], bb = be_b[t];
    for (int pos = 0; pos < TILE; ++pos) {
        int p = p0 + pos;
        float emb = bev[p]*bw0 + bev[PBEV + p]*bw1 + bb - cemb;
        float ss = blockSum128(emb * emb, red, t);
        float qv = emb / (sqrtf(ss) + 1e-7f) + x[(size_t)t * PBEV + p];
        query[((size_t)(n * PBEV + p)) * 128 + t] = qv;
    }
}

// ---------- generic tiled f32 GEMM: out[r][c] = epi( (LN?)A[r] . W[c] ) ----------
// ACT: 0 none, 1 gelu.  ADDM: 0 none, 1 row-major addb[r*NO+c], 2 chan-first addb[c*4096+r]
// STM: 0 row-major, 1 chan-first out[c*4096+r].  ASCL: scale A columns by ascale[]
template<int NI, int NO, int BR, int MR, int LNF, int BIASF, int ACT, int SCL,
         int ADDM, int STM, int ASCL>
__global__ __launch_bounds__(256)
void k_gemm(const float* __restrict__ A, const float* __restrict__ W,
            const float* __restrict__ bias, const float* __restrict__ addb,
            const float* __restrict__ ascale, float* __restrict__ out) {
    constexpr int CG  = NO / 8;
    constexpr int RG  = 256 / CG;
    constexpr int NIP = NI + 4;
    constexpr int NOP = NO + 4;
    __shared__ float a_lds[BR][NIP];
    __shared__ float w_lds[32][NOP];
    const int t  = threadIdx.x;
    const int rb = blockIdx.x * BR;

    constexpr int AF4 = (BR * NI / 4) / 256;
    #pragma unroll
    for (int i = 0; i < AF4; ++i) {
        int f4 = i * 256 + t;
        int row = f4 / (NI / 4), q = f4 % (NI / 4);
        float4 v = *(const float4*)&A[(size_t)(rb + row) * NI + 4 * q];
        if constexpr (ASCL) {
            float4 sc = *(const float4*)&ascale[4 * q];
            v.x *= sc.x; v.y *= sc.y; v.z *= sc.z; v.w *= sc.w;
        }
        *(float4*)&a_lds[row][4 * q] = v;
    }
    __syncthreads();

    if constexpr (LNF) {
        constexpr int TPR = 256 / BR;
        constexpr int CPT = NI / TPR;
        int row = t / TPR, seg = t % TPR, base = seg * CPT;
        float sum = 0.f;
        #pragma unroll
        for (int j = 0; j < CPT / 4; ++j) {
            float4 v = *(float4*)&a_lds[row][base + 4 * j];
            sum += (v.x + v.y) + (v.z + v.w);
        }
        #pragma unroll
        for (int o = 1; o < TPR; o <<= 1) sum += __shfl_xor(sum, o, 64);
        float mu = sum * (1.0f / NI);
        float ss = 0.f;
        #pragma unroll
        for (int j = 0; j < CPT / 4; ++j) {
            float4 v = *(float4*)&a_lds[row][base + 4 * j];
            float a = v.x - mu, b = v.y - mu, c = v.z - mu, d = v.w - mu;
            ss += (a * a + b * b) + (c * c + d * d);
        }
        #pragma unroll
        for (int o = 1; o < TPR; o <<= 1) ss += __shfl_xor(ss, o, 64);
        float rs = rsqrtf(ss * (1.0f / NI) + LN_EPS);
        #pragma unroll
        for (int j = 0; j < CPT / 4; ++j) {
            float4 v = *(float4*)&a_lds[row][base + 4 * j];
            v.x = (v.x - mu) * rs; v.y = (v.y - mu) * rs;
            v.z = (v.z - mu) * rs; v.w = (v.w - mu) * rs;
            *(float4*)&a_lds[row][base + 4 * j] = v;
        }
        __syncthreads();
    }

    const int cg = t % CG, rg = t / CG;
    const int c0 = cg * 8, r0 = rg * MR;
    float acc[MR][8];
    #pragma unroll
    for (int i = 0; i < MR; ++i)
        #pragma unroll
        for (int j = 0; j < 8; ++j) acc[i][j] = 0.f;

    constexpr int NCH = NI / 32;
    constexpr int WF4 = NO / 32;
    #pragma unroll 1
    for (int ch = 0; ch < NCH; ++ch) {
        int k0 = ch * 32;
        if (ch) __syncthreads();
        #pragma unroll
        for (int i = 0; i < WF4; ++i) {
            int f4 = i * 256 + t;
            int c = f4 >> 3, kq = f4 & 7;
            float4 v = *(const float4*)&W[(size_t)c * NI + k0 + 4 * kq];
            w_lds[4 * kq + 0][c] = v.x; w_lds[4 * kq + 1][c] = v.y;
            w_lds[4 * kq + 2][c] = v.z; w_lds[4 * kq + 3][c] = v.w;
        }
        __syncthreads();
        #pragma unroll
        for (int kk = 0; kk < 32; ++kk) {
            float4 w0 = *(float4*)&w_lds[kk][c0];
            float4 w1 = *(float4*)&w_lds[kk][c0 + 4];
            #pragma unroll
            for (int i = 0; i < MR; ++i) {
                float a = a_lds[r0 + i][k0 + kk];
                acc[i][0] += a * w0.x; acc[i][1] += a * w0.y;
                acc[i][2] += a * w0.z; acc[i][3] += a * w0.w;
                acc[i][4] += a * w1.x; acc[i][5] += a * w1.y;
                acc[i][6] += a * w1.z; acc[i][7] += a * w1.w;
            }
        }
    }

    // epilogue: +bias -> *BN_S -> act -> +add -> store
    float bi[8];
    if constexpr (BIASF) {
        #pragma unroll
        for (int j = 0; j < 8; ++j) bi[j] = bias[c0 + j];
    }
    #pragma unroll
    for (int i = 0; i < MR; ++i)
        #pragma unroll
        for (int j = 0; j < 8; ++j) {
            float v = acc[i][j];
            if constexpr (BIASF) v += bi[j];
            if constexpr (SCL)   v *= BN_S;
            if constexpr (ACT)   v = gelu_f(v);
            acc[i][j] = v;
        }
    if constexpr (ADDM == 1) {
        #pragma unroll
        for (int i = 0; i < MR; ++i) {
            float4 a0 = *(const float4*)&addb[(size_t)(rb + r0 + i) * NO + c0];
            float4 a1 = *(const float4*)&addb[(size_t)(rb + r0 + i) * NO + c0 + 4];
            acc[i][0] += a0.x; acc[i][1] += a0.y; acc[i][2] += a0.z; acc[i][3] += a0.w;
            acc[i][4] += a1.x; acc[i][5] += a1.y; acc[i][6] += a1.z; acc[i][7] += a1.w;
        }
    }
    if constexpr (ADDM == 2) {  // MR==4
        #pragma unroll
        for (int j = 0; j < 8; ++j) {
            float4 ax = *(const float4*)&addb[(size_t)(c0 + j) * PBEV + rb + r0];
            acc[0][j] += ax.x; acc[1][j] += ax.y; acc[2][j] += ax.z; acc[3][j] += ax.w;
        }
    }
    if constexpr (STM == 0) {
        #pragma unroll
        for (int i = 0; i < MR; ++i) {
            float4 o0 = {acc[i][0], acc[i][1], acc[i][2], acc[i][3]};
            float4 o1 = {acc[i][4], acc[i][5], acc[i][6], acc[i][7]};
            *(float4*)&out[(size_t)(rb + r0 + i) * NO + c0]     = o0;
            *(float4*)&out[(size_t)(rb + r0 + i) * NO + c0 + 4] = o1;
        }
    } else {  // MR==4, chan-first
        #pragma unroll
        for (int j = 0; j < 8; ++j) {
            float4 o = {acc[0][j], acc[1][j], acc[2][j], acc[3][j]};
            *(float4*)&out[(size_t)(c0 + j) * PBEV + rb + r0] = o;
        }
    }
}

// ---------- attention 1: single-pass flash, 2 q-rows/thread ----------
__global__ __launch_bounds__(192)
void k_attn1(const float* __restrict__ qh, const float* __restrict__ kh,
             const float* __restrict__ vh, float* __restrict__ abuf) {
    const int l = blockIdx.x, m = blockIdx.y;
    const int xw = l >> 3, yw = l & 7;
    const int t = threadIdx.x;
    __shared__ float kls[KROWS][32];
    __shared__ float vls[KROWS][32];
    #pragma unroll
    for (int i = 0; i < 12; ++i) {
        int f4 = i * 192 + t;                // 2304
        int row = f4 >> 3, q4 = f4 & 7;
        int n = row / 48, kk = row % 48;
        int k1 = kk / 12, k2 = kk % 12;
        int h = xw * 4 + k1, w = yw * 12 + k2;
        size_t src = ((size_t)(n * PIMG + h * FWW + w)) * 128 + m * DHD + 4 * q4;
        *(float4*)&kls[row][4 * q4] = *(const float4*)&kh[src];
        *(float4*)&vls[row][4 * q4] = *(const float4*)&vh[src];
    }
    float qr[2][32];
    int ww_[2], n_[2];
    #pragma unroll
    for (int b = 0; b < 2; ++b) {
        int q = t + 192 * b;
        int n = q >> 6, ww = q & 63;
        int w1 = ww >> 3, w2 = ww & 7;
        int h = xw * 8 + w1, w = yw * 8 + w2;
        const float* qp = qh + ((size_t)(n * PBEV + h * WWD + w)) * 128 + m * DHD;
        #pragma unroll
        for (int j4 = 0; j4 < 8; ++j4)
            *(float4*)&qr[b][4 * j4] = *(const float4*)&qp[4 * j4];
        ww_[b] = ww; n_[b] = n;
    }
    __syncthreads();

    float mr[2] = {-1e30f, -1e30f}, sum[2] = {0.f, 0.f};
    float acc[2][32];
    #pragma unroll
    for (int b = 0; b < 2; ++b)
        #pragma unroll
        for (int j = 0; j < 32; ++j) acc[b][j] = 0.f;

    for (int k = 0; k < KROWS; ++k) {
        float kp[32];
        #pragma unroll
        for (int j4 = 0; j4 < 8; ++j4)
            *(float4*)&kp[4 * j4] = *(const float4*)&kls[k][4 * j4];
        float p[2];
        #pragma unroll
        for (int b = 0; b < 2; ++b) {
            float s0 = 0.f, s1 = 0.f, s2 = 0.f, s3 = 0.f;
            #pragma unroll
            for (int j = 0; j < 32; j += 4) {
                s0 += qr[b][j]   * kp[j];   s1 += qr[b][j+1] * kp[j+1];
                s2 += qr[b][j+2] * kp[j+2]; s3 += qr[b][j+3] * kp[j+3];
            }
            float d = ((s0 + s1) + (s2 + s3)) * ATT_SCALE;
            if (d > mr[b] + 8.0f) {
                float f = __expf(mr[b] - d);
                sum[b] *= f;
                #pragma unroll
                for (int j = 0; j < 32; ++j) acc[b][j] *= f;
                mr[b] = d;
            }
            p[b] = __expf(d - mr[b]);
            sum[b] += p[b];
        }
        float vp[32];
        #pragma unroll
        for (int j4 = 0; j4 < 8; ++j4)
            *(float4*)&vp[4 * j4] = *(const float4*)&vls[k][4 * j4];
        #pragma unroll
        for (int j = 0; j < 32; ++j) {
            acc[0][j] += p[0] * vp[j];
            acc[1][j] += p[1] * vp[j];
        }
    }
    #pragma unroll
    for (int b = 0; b < 2; ++b) {
        float inv = 1.0f / sum[b];
        float* ap = abuf + ((size_t)((l * 64 + ww_[b]) * 6 + n_[b])) * 128 + m * DHD;
        #pragma unroll
        for (int j4 = 0; j4 < 8; ++j4) {
            float4 o = {acc[b][4*j4] * inv, acc[b][4*j4+1] * inv,
                        acc[b][4*j4+2] * inv, acc[b][4*j4+3] * inv};
            *(float4*)&ap[4 * j4] = o;
        }
    }
}

// ---------- attention 2: broadcast q (64 rows/window), 2-way key split ----------
__global__ __launch_bounds__(128)
void k_attn2(const float* __restrict__ qh, const float* __restrict__ kh,
             const float* __restrict__ vh, float* __restrict__ abuf2) {
    const int l = blockIdx.x, m = blockIdx.y;
    const int xw = l >> 3, yw = l & 7;
    const int t = threadIdx.x;
    __shared__ float kls[KROWS][32];
    __shared__ float vls[KROWS][32];
    #pragma unroll
    for (int i = 0; i < 18; ++i) {
        int f4 = i * 128 + t;                // 2304
        int row = f4 >> 3, q4 = f4 & 7;
        int n = row / 48, kk = row % 48;
        int k1 = kk / 12, k2 = kk % 12;
        int h = k1 * 8 + xw, w = k2 * 8 + yw;
        size_t src = ((size_t)(n * PIMG + h * FWW + w)) * 128 + m * DHD + 4 * q4;
        *(float4*)&kls[row][4 * q4] = *(const float4*)&kh[src];
        *(float4*)&vls[row][4 * q4] = *(const float4*)&vh[src];
    }
    const int wv = t >> 6, q = t & 63;
    const int w1 = q >> 3, w2 = q & 7;
    const int h = w1 * 8 + xw, w = w2 * 8 + yw;
    float qr[32];
    const float* qp = qh + ((size_t)(h * WWD + w)) * 128 + m * DHD;
    #pragma unroll
    for (int j4 = 0; j4 < 8; ++j4)
        *(float4*)&qr[4 * j4] = *(const float4*)&qp[4 * j4];
    __syncthreads();

    float mr = -1e30f, sum = 0.f, acc[32];
    #pragma unroll
    for (int j = 0; j < 32; ++j) acc[j] = 0.f;
    const int kbeg = wv * 144, kend = kbeg + 144;
    for (int k = kbeg; k < kend; ++k) {
        float kp[32];
        #pragma unroll
        for (int j4 = 0; j4 < 8; ++j4)
            *(float4*)&kp[4 * j4] = *(const float4*)&kls[k][4 * j4];
        float s0 = 0.f, s1 = 0.f, s2 = 0.f, s3 = 0.f;
        #pragma unroll
        for (int j = 0; j < 32; j += 4) {
            s0 += qr[j]   * kp[j];   s1 += qr[j+1] * kp[j+1];
            s2 += qr[j+2] * kp[j+2]; s3 += qr[j+3] * kp[j+3];
        }
        float d = ((s0 + s1) + (s2 + s3)) * ATT_SCALE;
        if (d > mr + 8.0f) {
            float f = __expf(mr - d);
            sum *= f;
            #pragma unroll
            for (int j = 0; j < 32; ++j) acc[j] *= f;
            mr = d;
        }
        float p = __expf(d - mr);
        sum += p;
        #pragma unroll
        for (int j = 0; j < 32; ++j) acc[j] += p * vls[k][j];
    }
    __syncthreads();
    float* mrg = &kls[0][0];
    if (wv == 1) {
        mrg[q * 36 + 0] = mr;
        mrg[q * 36 + 1] = sum;
        #pragma unroll
        for (int j = 0; j < 32; ++j) mrg[q * 36 + 2 + j] = acc[j];
    }
    __syncthreads();
    if (wv == 0) {
        float m1 = mrg[q * 36], s1v = mrg[q * 36 + 1];
        float nm = fmaxf(mr, m1);
        float f0 = __expf(mr - nm), f1 = __expf(m1 - nm);
        float inv = 1.0f / (sum * f0 + s1v * f1);
        float* ap = abuf2 + ((size_t)(h * WWD + w)) * 128 + m * DHD;
        #pragma unroll
        for (int j4 = 0; j4 < 8; ++j4) {
            float4 o;
            o.x = (acc[4*j4]   * f0 + mrg[q*36+2+4*j4]   * f1) * inv;
            o.y = (acc[4*j4+1] * f0 + mrg[q*36+3+4*j4]   * f1) * inv;
            o.z = (acc[4*j4+2] * f0 + mrg[q*36+4+4*j4]   * f1) * inv;
            o.w = (acc[4*j4+3] * f0 + mrg[q*36+5+4*j4]   * f1) * inv;
            *(float4*)&ap[4 * j4] = o;
        }
    }
}

// ---------- mean over 6 views + window->hw permute ----------
__global__ void k_mean(const float* __restrict__ abuf, float* __restrict__ amean) {
    int t = threadIdx.x;
    for (int rr = 0; rr < 8; ++rr) {
        int hw = blockIdx.x * 8 + rr;
        int h = hw >> 6, w = hw & 63;
        int xw = h >> 3, w1 = h & 7, yw = w >> 3, w2 = w & 7;
        int l = xw * 8 + yw, ww = w1 * 8 + w2;
        const float* src = abuf + ((size_t)(l * 64 + ww)) * 6 * 128;
        float s = 0.f;
        #pragma unroll
        for (int n = 0; n < 6; ++n) s += src[n * 128 + t];
        amean[(size_t)hw * 128 + t] = s * (1.0f / 6.0f);
    }
}

// ---------- row LayerNorm ----------
__global__ void k_lnrows(const float* __restrict__ in, float* __restrict__ out) {
    __shared__ float red[2];
    int t = threadIdx.x;
    for (int rr = 0; rr < 8; ++rr) {
        size_t r = (size_t)blockIdx.x * 8 + rr;
        float v = in[r * 128 + t];
        float mu = blockSum128(v, red, t) * (1.0f / 128.0f);
        float d = v - mu;
        float var = blockSum128(d * d, red, t) * (1.0f / 128.0f);
        out[r * 128 + t] = d * rsqrtf(var + LN_EPS);
    }
}

// ---------- depthwise 3x3 + gelu + SE partials ----------
__global__ void k_dwconv(const float* __restrict__ ex, const float* __restrict__ dwgt,
                         float* __restrict__ dwout, float* __restrict__ separt) {
    const int TILE = 16;
    int ch = threadIdx.x;
    int hw0 = blockIdx.x * TILE;
    float wreg[9];
    #pragma unroll
    for (int i = 0; i < 9; ++i) wreg[i] = dwgt[ch * 9 + i];
    float sacc = 0.f;
    for (int ti = 0; ti < TILE; ++ti) {
        int hw = hw0 + ti;
        int h = hw >> 6, w = hw & 63;
        float s = 0.f;
        #pragma unroll
        for (int dy = -1; dy <= 1; ++dy) {
            int h2 = h + dy;
            if (h2 < 0 || h2 >= 64) continue;
            #pragma unroll
            for (int dx = -1; dx <= 1; ++dx) {
                int w2 = w + dx;
                if (w2 < 0 || w2 >= 64) continue;
                s += ex[((size_t)(h2 * 64 + w2)) * 512 + ch] * wreg[(dy + 1) * 3 + (dx + 1)];
            }
        }
        float o = gelu_f(s * BN_S);
        dwout[(size_t)hw * 512 + ch] = o;
        sacc += o;
    }
    separt[(size_t)blockIdx.x * 512 + ch] = sacc;
}

// ---------- SE ----------
__global__ void k_se(const float* __restrict__ separt, int nparts,
                     const float* __restrict__ s1w, const float* __restrict__ s1b,
                     const float* __restrict__ s2w, const float* __restrict__ s2b,
                     float* __restrict__ se) {
    __shared__ float mean[512];
    __shared__ float s1[32];
    int tid = threadIdx.x;
    float s = 0.f;
    for (int b = 0; b < nparts; ++b) s += separt[(size_t)b * 512 + tid];
    mean[tid] = s * (1.0f / 4096.0f);
    __syncthreads();
    if (tid < 32) {
        float acc = s1b[tid];
        const float* wr = s1w + (size_t)tid * 512;
        for (int c = 0; c < 512; ++c) acc += mean[c] * wr[c];
        s1[tid] = gelu_f(acc);
    }
    __syncthreads();
    float acc = s2b[tid];
    const float* wr = s2w + (size_t)tid * 32;
    #pragma unroll
    for (int j = 0; j < 32; ++j) acc += s1[j] * wr[j];
    se[tid] = 1.0f / (1.0f + __expf(-acc));
}

extern "C" void kernel_launch(void* const* d_in, const int* in_sizes, int n_in,
                              void* d_out, int out_size, void* d_ws, size_t ws_size,
                              hipStream_t stream) {
    (void)in_sizes; (void)n_in; (void)out_size; (void)ws_size;
    const float* x      = (const float*)d_in[1];
    const float* feat   = (const float*)d_in[2];
    const float* I_inv  = (const float*)d_in[3];
    const float* E_inv  = (const float*)d_in[4];
    const float* bev    = (const float*)d_in[5];
    const float* fl_w   = (const float*)d_in[6];
    const float* fp_w   = (const float*)d_in[7];
    const float* be_w   = (const float*)d_in[8];
    const float* be_b   = (const float*)d_in[9];
    const float* ie_w   = (const float*)d_in[10];
    const float* ce_w   = (const float*)d_in[11];
    const float* a1_qw  = (const float*)d_in[12];
    const float* a1_qb  = (const float*)d_in[13];
    const float* a1_kw  = (const float*)d_in[14];
    const float* a1_kb  = (const float*)d_in[15];
    const float* a1_vw  = (const float*)d_in[16];
    const float* a1_vb  = (const float*)d_in[17];
    const float* a1_pw  = (const float*)d_in[18];
    const float* a1_pb  = (const float*)d_in[19];
    const float* a2_qw  = (const float*)d_in[20];
    const float* a2_qb  = (const float*)d_in[21];
    const float* a2_kw  = (const float*)d_in[22];
    const float* a2_kb  = (const float*)d_in[23];
    const float* a2_vw  = (const float*)d_in[24];
    const float* a2_vb  = (const float*)d_in[25];
    const float* a2_pw  = (const float*)d_in[26];
    const float* a2_pb  = (const float*)d_in[27];
    const float* m1_w1  = (const float*)d_in[28];
    const float* m1_b1  = (const float*)d_in[29];
    const float* m1_w2  = (const float*)d_in[30];
    const float* m1_b2  = (const float*)d_in[31];
    const float* m2_w1  = (const float*)d_in[32];
    const float* m2_b1  = (const float*)d_in[33];
    const float* m2_w2  = (const float*)d_in[34];
    const float* m2_b2  = (const float*)d_in[35];
    const float* mb_ew  = (const float*)d_in[36];
    const float* mb_dw  = (const float*)d_in[37];
    const float* mb_s1w = (const float*)d_in[38];
    const float* mb_s1b = (const float*)d_in[39];
    const float* mb_s2w = (const float*)d_in[40];
    const float* mb_s2b = (const float*)d_in[41];
    const float* mb_pw  = (const float*)d_in[42];
    const float* pm_w1  = (const float*)d_in[43];
    const float* pm_b1  = (const float*)d_in[44];
    const float* pm_w2  = (const float*)d_in[45];
    const float* pm_b2  = (const float*)d_in[46];
    const float* po_w   = (const float*)d_in[47];
    const float* po_b   = (const float*)d_in[48];

    float* ws = (float*)d_ws;
    float* segA   = ws + 0;         // 2359296  f_cl -> kh1 -> kh2
    float* segB   = ws + 2359296;   // 2359296  kinit -> vh1 -> vh2
    float* key    = ws + 4718592;   // 2359296
    float* val    = ws + 7077888;   // 2359296
    float* segE   = ws + 9437184;   // 3145728  query -> abuf1 -> expand
    float* segF   = ws + 12582912;  // 3145728  qh1 -> qh2 -> dwout
    float* amean  = ws + 15728640;  // 524288
    float* qimg   = ws + 16252928;  // 524288
    float* gbuf   = ws + 16777216;  // 1048576
    float* qimg2  = ws + 17825792;  // 524288
    float* zln    = ws + 18350080;  // 524288
    float* abuf2  = ws + 18874368;  // 524288
    float* mbout  = ws + 19398656;  // 524288
    float* separt = ws + 19922944;  // 131072
    float* sebuf  = ws + 20054016;  // 512

    // stage 0: layout transforms + embeddings
    k_trans<<<dim3(96, 4, 6), 256, 0, stream>>>(feat, segA);
    k_embed<<<dim3(192, 6), 128, 0, stream>>>(I_inv, E_inv, ie_w, ce_w, segB);
    k_gemm<128,128,64,4, 0,0,0,0, 1,0,0><<<288, 256, 0, stream>>>(segA, fp_w, nullptr, segB, nullptr, key);
    k_gemm<128,128,64,4, 0,0,0,0, 0,0,0><<<288, 256, 0, stream>>>(segA, fl_w, nullptr, nullptr, nullptr, val);
    k_query<<<dim3(256, 6), 128, 0, stream>>>(x, bev, be_w, be_b, E_inv, ce_w, segE);

    // stage 1: attn1 + MLP1
    k_gemm<128,128,64,4, 1,1,0,0, 0,0,0><<<384, 256, 0, stream>>>(segE, a1_qw, a1_qb, nullptr, nullptr, segF);
    k_gemm<128,128,64,4, 1,1,0,0, 0,0,0><<<288, 256, 0, stream>>>(key,  a1_kw, a1_kb, nullptr, nullptr, segA);
    k_gemm<128,128,64,4, 1,1,0,0, 0,0,0><<<288, 256, 0, stream>>>(val,  a1_vw, a1_vb, nullptr, nullptr, segB);
    k_attn1<<<dim3(64, HEADS), 192, 0, stream>>>(segF, segA, segB, segE);
    k_mean<<<512, 128, 0, stream>>>(segE, amean);
    k_gemm<128,128,64,4, 0,1,0,0, 2,0,0><<<64, 256, 0, stream>>>(amean, a1_pw, a1_pb, x, nullptr, qimg);
    k_gemm<128,256,32,4, 1,1,1,0, 0,0,0><<<128, 256, 0, stream>>>(qimg, m1_w1, m1_b1, nullptr, nullptr, gbuf);
    k_gemm<256,128,32,2, 0,1,0,0, 1,0,0><<<128, 256, 0, stream>>>(gbuf, m1_w2, m1_b2, qimg, nullptr, qimg);

    // stage 2: attn2 + MLP2
    k_gemm<128,128,64,4, 1,1,0,0, 0,0,0><<<64, 256, 0, stream>>>(qimg, a2_qw, a2_qb, nullptr, nullptr, segF);
    k_gemm<128,128,64,4, 1,1,0,0, 0,0,0><<<288, 256, 0, stream>>>(key,  a2_kw, a2_kb, nullptr, nullptr, segA);
    k_gemm<128,128,64,4, 1,1,0,0, 0,0,0><<<288, 256, 0, stream>>>(val,  a2_vw, a2_vb, nullptr, nullptr, segB);
    k_attn2<<<dim3(64, HEADS), 128, 0, stream>>>(segF, segA, segB, abuf2);
    k_gemm<128,128,64,4, 0,1,0,0, 1,0,0><<<64, 256, 0, stream>>>(abuf2, a2_pw, a2_pb, qimg, nullptr, qimg2);
    k_gemm<128,256,32,4, 1,1,1,0, 0,0,0><<<128, 256, 0, stream>>>(qimg2, m2_w1, m2_b1, nullptr, nullptr, gbuf);
    k_gemm<256,128,32,2, 0,1,0,0, 1,0,0><<<128, 256, 0, stream>>>(gbuf, m2_w2, m2_b2, qimg2, nullptr, qimg2);

    // stage 3: postnorm + MBConv + FFN + proj_out
    k_lnrows<<<512, 128, 0, stream>>>(qimg2, zln);
    k_gemm<128,512,16,4, 0,0,1,1, 0,0,0><<<256, 256, 0, stream>>>(zln, mb_ew, nullptr, nullptr, nullptr, segE);
    k_dwconv<<<256, 512, 0, stream>>>(segE, mb_dw, segF, separt);
    k_se<<<1, 512, 0, stream>>>(separt, 256, mb_s1w, mb_s1b, mb_s2w, mb_s2b, sebuf);
    k_gemm<512,128,16,1, 0,0,0,1, 1,0,1><<<256, 256, 0, stream>>>(segF, mb_pw, nullptr, zln, sebuf, mbout);
    k_gemm<128,256,32,4, 0,1,1,0, 0,0,0><<<128, 256, 0, stream>>>(mbout, pm_w1, pm_b1, nullptr, nullptr, gbuf);
    k_gemm<256,128,32,2, 0,1,0,0, 1,0,0><<<128, 256, 0, stream>>>(gbuf, pm_w2, pm_b2, mbout, nullptr, mbout);
    k_gemm<128,128,64,4, 0,1,1,0, 0,1,0><<<64, 256, 0, stream>>>(mbout, po_w, po_b, nullptr, nullptr, (float*)d_out);
}

// Round 3
// 602.038 us; speedup vs baseline: 3.5778x; 1.1666x over previous
//
#include <hip/hip_runtime.h>
#include <math.h>

#define NV 6
#define FHH 32
#define FWW 96
#define PIMG (FHH*FWW)   // 3072
#define HH 64
#define WWD 64
#define PBEV (HH*WWD)    // 4096
#define HEADS 4
#define DHD 32
#define KROWS 288
#define BN_S 0.9999950000374996f
#define LN_EPS 1e-5f
#define ATT_SCALE 0.17677669529663687f  // 32^-0.5

__device__ __forceinline__ float gelu_f(float x) {
    return 0.5f * x * (1.0f + erff(x * 0.70710678118654752f));
}

__device__ __forceinline__ float blockSum128(float v, float* red, int tid) {
    #pragma unroll
    for (int o = 32; o > 0; o >>= 1) v += __shfl_down(v, o, 64);
    __syncthreads();
    if ((tid & 63) == 0) red[tid >> 6] = v;
    __syncthreads();
    return red[0] + red[1];
}

// ---------- feature transpose + BN*relu : [n][128][3072] -> [n*3072][128] ----------
__global__ void k_trans(const float* __restrict__ feature, float* __restrict__ f_cl) {
    __shared__ float tile[32][33];
    int n = blockIdx.z, c0 = blockIdx.y * 32, p0 = blockIdx.x * 32;
    int tp = threadIdx.x & 31, tg = threadIdx.x >> 5;
    #pragma unroll
    for (int i = 0; i < 4; ++i) {
        int c = tg + 8 * i;
        tile[c][tp] = feature[((size_t)(n * 128 + c0 + c)) * PIMG + p0 + tp];
    }
    __syncthreads();
    int cw = threadIdx.x & 31, pg = threadIdx.x >> 5;
    #pragma unroll
    for (int i = 0; i < 4; ++i) {
        int p = pg + 8 * i;
        float v = fmaxf(tile[cw][p] * BN_S, 0.0f);
        f_cl[((size_t)(n * PIMG + p0 + p)) * 128 + c0 + cw] = v;
    }
}

// ---------- geometric image embedding -> kinit [n*3072][128] ----------
__global__ void k_embed(const float* __restrict__ I_inv, const float* __restrict__ E_inv,
                        const float* __restrict__ ie_w, const float* __restrict__ ce_w,
                        float* __restrict__ kinit) {
    const int TILE = 16;
    int n = blockIdx.y, p0 = blockIdx.x * TILE, t = threadIdx.x;
    __shared__ float red[2];
    const float* E  = E_inv + n * 16;
    const float* Ii = I_inv + n * 9;
    float cemb = E[3]  * ce_w[t*4+0] + E[7]  * ce_w[t*4+1]
               + E[11] * ce_w[t*4+2] + E[15] * ce_w[t*4+3];
    for (int pos = 0; pos < TILE; ++pos) {
        int p = p0 + pos;
        int h = p / FWW, w = p % FWW;
        float gx = (float)w * (768.0f / 95.0f);
        float gy = (float)h * (256.0f / 31.0f);
        float c0 = Ii[0]*gx + Ii[1]*gy + Ii[2];
        float c1 = Ii[3]*gx + Ii[4]*gy + Ii[5];
        float c2 = Ii[6]*gx + Ii[7]*gy + Ii[8];
        float d0 = E[0]*c0  + E[1]*c1  + E[2]*c2  + E[3];
        float d1 = E[4]*c0  + E[5]*c1  + E[6]*c2  + E[7];
        float d2 = E[8]*c0  + E[9]*c1  + E[10]*c2 + E[11];
        float d3 = E[12]*c0 + E[13]*c1 + E[14]*c2 + E[15];
        float emb = d0*ie_w[t*4+0] + d1*ie_w[t*4+1]
                  + d2*ie_w[t*4+2] + d3*ie_w[t*4+3] - cemb;
        float ss = blockSum128(emb * emb, red, t);
        kinit[((size_t)(n * PIMG + p)) * 128 + t] = emb / (sqrtf(ss) + 1e-7f);
    }
}

// ---------- query [n*4096][128] ----------
__global__ void k_query(const float* __restrict__ x, const float* __restrict__ bev,
                        const float* __restrict__ be_w, const float* __restrict__ be_b,
                        const float* __restrict__ E_inv, const float* __restrict__ ce_w,
                        float* __restrict__ query) {
    const int TILE = 16;
    int n = blockIdx.y, p0 = blockIdx.x * TILE, t = threadIdx.x;
    __shared__ float red[2];
    const float* E = E_inv + n * 16;
    float cemb = E[3]  * ce_w[t*4+0] + E[7]  * ce_w[t*4+1]
               + E[11] * ce_w[t*4+2] + E[15] * ce_w[t*4+3];
    float bw0 = be_w[t*2+0], bw1 = be_w[t*2+1], bb = be_b[t];
    for (int pos = 0; pos < TILE; ++pos) {
        int p = p0 + pos;
        float emb = bev[p]*bw0 + bev[PBEV + p]*bw1 + bb - cemb;
        float ss = blockSum128(emb * emb, red, t);
        float qv = emb / (sqrtf(ss) + 1e-7f) + x[(size_t)t * PBEV + p];
        query[((size_t)(n * PBEV + p)) * 128 + t] = qv;
    }
}

// ---------- generic tiled f32 GEMM (256 threads) ----------
// out[r][co+c] = epi( (LN?)A[r] . W[co+c] ), col panel co = blockIdx.y*NO, stride NOT.
// ADDM: 0 none, 1 row-major addb (stride NOT), 2 chan-first addb[(c)*4096+r] (set 0 only)
// STM: 0 row-major f4, 1 chan-first scalar. ASCL: scale A cols by ascale[].
// DUAL: second weight set W2/bias2 -> out2. WRLN: panel 0 writes LN(A) to aux.
template<int NI, int NO, int NOT, int BR, int MR, int LNF, int BIASF, int ACT,
         int SCL, int ADDM, int STM, int ASCL, int DUAL, int WRLN>
__global__ __launch_bounds__(256)
void k_gemm(const float* __restrict__ A, const float* __restrict__ W,
            const float* __restrict__ bias, const float* __restrict__ addb,
            const float* __restrict__ ascale, const float* __restrict__ W2,
            const float* __restrict__ bias2, float* __restrict__ out2,
            float* __restrict__ aux, float* __restrict__ out) {
    constexpr int CG = NO / 8;
    constexpr int RG = 256 / CG;
    static_assert(RG * MR == BR, "tile mismatch");
    __shared__ float a_lds[BR][NI + 4];
    __shared__ float w_lds[32][NO + 4];
    const int t  = threadIdx.x;
    const int rb = blockIdx.x * BR;
    const int co = blockIdx.y * NO;

    constexpr int AF4 = (BR * NI / 4) / 256;
    #pragma unroll
    for (int i = 0; i < AF4; ++i) {
        int f4 = i * 256 + t;
        int row = f4 / (NI / 4), q = f4 % (NI / 4);
        float4 v = *(const float4*)&A[(size_t)(rb + row) * NI + 4 * q];
        if constexpr (ASCL) {
            float4 sc = *(const float4*)&ascale[4 * q];
            v.x *= sc.x; v.y *= sc.y; v.z *= sc.z; v.w *= sc.w;
        }
        *(float4*)&a_lds[row][4 * q] = v;
    }
    __syncthreads();

    if constexpr (LNF) {
        constexpr int TPR = 256 / BR;
        constexpr int CPT = NI / TPR;
        int row = t / TPR, seg = t % TPR, base = seg * CPT;
        float sum = 0.f;
        #pragma unroll
        for (int j = 0; j < CPT / 4; ++j) {
            float4 v = *(float4*)&a_lds[row][base + 4 * j];
            sum += (v.x + v.y) + (v.z + v.w);
        }
        #pragma unroll
        for (int o = 1; o < TPR; o <<= 1) sum += __shfl_xor(sum, o, 64);
        float mu = sum * (1.0f / NI);
        float ss = 0.f;
        #pragma unroll
        for (int j = 0; j < CPT / 4; ++j) {
            float4 v = *(float4*)&a_lds[row][base + 4 * j];
            float a = v.x - mu, b = v.y - mu, c = v.z - mu, d = v.w - mu;
            ss += (a * a + b * b) + (c * c + d * d);
        }
        #pragma unroll
        for (int o = 1; o < TPR; o <<= 1) ss += __shfl_xor(ss, o, 64);
        float rs = rsqrtf(ss * (1.0f / NI) + LN_EPS);
        #pragma unroll
        for (int j = 0; j < CPT / 4; ++j) {
            float4 v = *(float4*)&a_lds[row][base + 4 * j];
            v.x = (v.x - mu) * rs; v.y = (v.y - mu) * rs;
            v.z = (v.z - mu) * rs; v.w = (v.w - mu) * rs;
            *(float4*)&a_lds[row][base + 4 * j] = v;
            if constexpr (WRLN) {
                if (blockIdx.y == 0)
                    *(float4*)&aux[(size_t)(rb + row) * NI + base + 4 * j] = v;
            }
        }
        __syncthreads();
    }

    const int cg = t % CG, rg = t / CG;
    const int c0 = cg * 8, r0 = rg * MR;
    constexpr int NCH = NI / 32;
    constexpr int WF4 = NO / 32;

    #pragma unroll 1
    for (int set = 0; set <= DUAL; ++set) {
        const float* Wc = set ? W2 : W;
        const float* bc = set ? bias2 : bias;
        float* oc = set ? out2 : out;
        float acc[MR][8];
        #pragma unroll
        for (int i = 0; i < MR; ++i)
            #pragma unroll
            for (int j = 0; j < 8; ++j) acc[i][j] = 0.f;

        #pragma unroll 1
        for (int ch = 0; ch < NCH; ++ch) {
            int k0 = ch * 32;
            if (ch || set) __syncthreads();
            #pragma unroll
            for (int i = 0; i < WF4; ++i) {
                int f4 = i * 256 + t;
                int c = f4 >> 3, kq = f4 & 7;
                float4 v = *(const float4*)&Wc[(size_t)(co + c) * NI + k0 + 4 * kq];
                w_lds[4 * kq + 0][c] = v.x; w_lds[4 * kq + 1][c] = v.y;
                w_lds[4 * kq + 2][c] = v.z; w_lds[4 * kq + 3][c] = v.w;
            }
            __syncthreads();
            #pragma unroll
            for (int kk = 0; kk < 32; ++kk) {
                float4 w0 = *(float4*)&w_lds[kk][c0];
                float4 w1 = *(float4*)&w_lds[kk][c0 + 4];
                #pragma unroll
                for (int i = 0; i < MR; ++i) {
                    float a = a_lds[r0 + i][k0 + kk];
                    acc[i][0] += a * w0.x; acc[i][1] += a * w0.y;
                    acc[i][2] += a * w0.z; acc[i][3] += a * w0.w;
                    acc[i][4] += a * w1.x; acc[i][5] += a * w1.y;
                    acc[i][6] += a * w1.z; acc[i][7] += a * w1.w;
                }
            }
        }

        float bi[8];
        if constexpr (BIASF) {
            #pragma unroll
            for (int j = 0; j < 8; ++j) bi[j] = bc[co + c0 + j];
        }
        #pragma unroll
        for (int i = 0; i < MR; ++i)
            #pragma unroll
            for (int j = 0; j < 8; ++j) {
                float v = acc[i][j];
                if constexpr (BIASF) v += bi[j];
                if constexpr (SCL)   v *= BN_S;
                if constexpr (ACT)   v = gelu_f(v);
                acc[i][j] = v;
            }
        if constexpr (ADDM == 1) {
            if (set == 0) {
                #pragma unroll
                for (int i = 0; i < MR; ++i) {
                    float4 a0 = *(const float4*)&addb[(size_t)(rb + r0 + i) * NOT + co + c0];
                    float4 a1 = *(const float4*)&addb[(size_t)(rb + r0 + i) * NOT + co + c0 + 4];
                    acc[i][0] += a0.x; acc[i][1] += a0.y; acc[i][2] += a0.z; acc[i][3] += a0.w;
                    acc[i][4] += a1.x; acc[i][5] += a1.y; acc[i][6] += a1.z; acc[i][7] += a1.w;
                }
            }
        }
        if constexpr (ADDM == 2) {
            if (set == 0) {
                #pragma unroll
                for (int j = 0; j < 8; ++j)
                    #pragma unroll
                    for (int i = 0; i < MR; ++i)
                        acc[i][j] += addb[(size_t)(co + c0 + j) * PBEV + rb + r0 + i];
            }
        }
        if constexpr (STM == 0) {
            #pragma unroll
            for (int i = 0; i < MR; ++i) {
                float4 o0 = {acc[i][0], acc[i][1], acc[i][2], acc[i][3]};
                float4 o1 = {acc[i][4], acc[i][5], acc[i][6], acc[i][7]};
                *(float4*)&oc[(size_t)(rb + r0 + i) * NOT + co + c0]     = o0;
                *(float4*)&oc[(size_t)(rb + r0 + i) * NOT + co + c0 + 4] = o1;
            }
        } else {
            #pragma unroll
            for (int j = 0; j < 8; ++j)
                #pragma unroll
                for (int i = 0; i < MR; ++i)
                    oc[(size_t)(co + c0 + j) * PBEV + rb + r0 + i] = acc[i][j];
        }
    }
}

// ---------- attention 1: 6 waves, intra-block 2-way key split, LDS merge ----------
__global__ __launch_bounds__(384)
void k_attn1(const float* __restrict__ qh, const float* __restrict__ kh,
             const float* __restrict__ vh, float* __restrict__ abuf) {
    const int l = blockIdx.x, m = blockIdx.y;
    const int xw = l >> 3, yw = l & 7;
    const int t = threadIdx.x;
    __shared__ float smem[2 * KROWS * 32];   // 73728 B
    float* kls = smem;
    float* vls = smem + KROWS * 32;
    #pragma unroll
    for (int i = 0; i < 6; ++i) {
        int f4 = i * 384 + t;                // 2304 = 288*8
        int row = f4 >> 3, q4 = f4 & 7;
        int n = row / 48, kk = row % 48;
        int k1 = kk / 12, k2 = kk % 12;
        int h = xw * 4 + k1, w = yw * 12 + k2;
        size_t src = ((size_t)(n * PIMG + h * FWW + w)) * 128 + m * DHD + 4 * q4;
        *(float4*)&kls[row * 32 + 4 * q4] = *(const float4*)&kh[src];
        *(float4*)&vls[row * 32 + 4 * q4] = *(const float4*)&vh[src];
    }
    const int wv = t / 192, p = t % 192;
    float qr[2][32];
    int ww_[2], n_[2];
    #pragma unroll
    for (int b = 0; b < 2; ++b) {
        int q = p + 192 * b;
        int n = q >> 6, ww = q & 63;
        int w1 = ww >> 3, w2 = ww & 7;
        int h = xw * 8 + w1, w = yw * 8 + w2;
        const float* qp = qh + ((size_t)(n * PBEV + h * WWD + w)) * 128 + m * DHD;
        #pragma unroll
        for (int j4 = 0; j4 < 8; ++j4)
            *(float4*)&qr[b][4 * j4] = *(const float4*)&qp[4 * j4];
        ww_[b] = ww; n_[b] = n;
    }
    __syncthreads();

    float mr[2] = {-1e30f, -1e30f}, sum[2] = {0.f, 0.f};
    float acc[2][32];
    #pragma unroll
    for (int b = 0; b < 2; ++b)
        #pragma unroll
        for (int j = 0; j < 32; ++j) acc[b][j] = 0.f;

    const int kbeg = wv * 144, kend = kbeg + 144;
    for (int k = kbeg; k < kend; ++k) {
        float kp[32];
        #pragma unroll
        for (int j4 = 0; j4 < 8; ++j4)
            *(float4*)&kp[4 * j4] = *(const float4*)&kls[k * 32 + 4 * j4];
        float pr[2];
        #pragma unroll
        for (int b = 0; b < 2; ++b) {
            float s0 = 0.f, s1 = 0.f, s2 = 0.f, s3 = 0.f;
            #pragma unroll
            for (int j = 0; j < 32; j += 4) {
                s0 += qr[b][j]   * kp[j];   s1 += qr[b][j+1] * kp[j+1];
                s2 += qr[b][j+2] * kp[j+2]; s3 += qr[b][j+3] * kp[j+3];
            }
            float d = ((s0 + s1) + (s2 + s3)) * ATT_SCALE;
            if (d > mr[b] + 8.0f) {
                float f = __expf(mr[b] - d);
                sum[b] *= f;
                #pragma unroll
                for (int j = 0; j < 32; ++j) acc[b][j] *= f;
                mr[b] = d;
            }
            pr[b] = __expf(d - mr[b]);
            sum[b] += pr[b];
        }
        float vp[32];
        #pragma unroll
        for (int j4 = 0; j4 < 8; ++j4)
            *(float4*)&vp[4 * j4] = *(const float4*)&vls[k * 32 + 4 * j4];
        #pragma unroll
        for (int j = 0; j < 32; ++j) {
            acc[0][j] += pr[0] * vp[j];
            acc[1][j] += pr[1] * vp[j];
        }
    }
    __syncthreads();
    float* pb = smem;                        // 192*68 floats = 52.2 KB
    if (wv == 1) {
        #pragma unroll
        for (int b = 0; b < 2; ++b) {
            int base = p * 68 + b * 34;
            pb[base] = mr[b]; pb[base + 1] = sum[b];
            #pragma unroll
            for (int j = 0; j < 32; ++j) pb[base + 2 + j] = acc[b][j];
        }
    }
    __syncthreads();
    if (wv == 0) {
        #pragma unroll
        for (int b = 0; b < 2; ++b) {
            int base = p * 68 + b * 34;
            float m1 = pb[base], s1 = pb[base + 1];
            float M = fmaxf(mr[b], m1);
            float f0 = __expf(mr[b] - M), f1 = __expf(m1 - M);
            float inv = 1.0f / (sum[b] * f0 + s1 * f1);
            float* ap = abuf + ((size_t)((l * 64 + ww_[b]) * 6 + n_[b])) * 128 + m * DHD;
            #pragma unroll
            for (int j4 = 0; j4 < 8; ++j4) {
                float4 o;
                o.x = (acc[b][4*j4]   * f0 + pb[base + 2 + 4*j4]   * f1) * inv;
                o.y = (acc[b][4*j4+1] * f0 + pb[base + 3 + 4*j4]   * f1) * inv;
                o.z = (acc[b][4*j4+2] * f0 + pb[base + 4 + 4*j4]   * f1) * inv;
                o.w = (acc[b][4*j4+3] * f0 + pb[base + 5 + 4*j4]   * f1) * inv;
                *(float4*)&ap[4 * j4] = o;
            }
        }
    }
}

// ---------- attention 2: 4 waves, 4-way key split, LDS merge ----------
__global__ __launch_bounds__(256)
void k_attn2(const float* __restrict__ qh, const float* __restrict__ kh,
             const float* __restrict__ vh, float* __restrict__ abuf2) {
    const int l = blockIdx.x, m = blockIdx.y;
    const int xw = l >> 3, yw = l & 7;
    const int t = threadIdx.x;
    __shared__ float smem[2 * KROWS * 32];
    float* kls = smem;
    float* vls = smem + KROWS * 32;
    #pragma unroll
    for (int i = 0; i < 9; ++i) {
        int f4 = i * 256 + t;                // 2304
        int row = f4 >> 3, q4 = f4 & 7;
        int n = row / 48, kk = row % 48;
        int k1 = kk / 12, k2 = kk % 12;
        int h = k1 * 8 + xw, w = k2 * 8 + yw;
        size_t src = ((size_t)(n * PIMG + h * FWW + w)) * 128 + m * DHD + 4 * q4;
        *(float4*)&kls[row * 32 + 4 * q4] = *(const float4*)&kh[src];
        *(float4*)&vls[row * 32 + 4 * q4] = *(const float4*)&vh[src];
    }
    const int wv = t >> 6, q = t & 63;
    const int w1 = q >> 3, w2 = q & 7;
    const int h = w1 * 8 + xw, w = w2 * 8 + yw;
    float qr[32];
    const float* qp = qh + ((size_t)(h * WWD + w)) * 128 + m * DHD;
    #pragma unroll
    for (int j4 = 0; j4 < 8; ++j4)
        *(float4*)&qr[4 * j4] = *(const float4*)&qp[4 * j4];
    __syncthreads();

    float mr = -1e30f, sum = 0.f, acc[32];
    #pragma unroll
    for (int j = 0; j < 32; ++j) acc[j] = 0.f;
    const int kbeg = wv * 72, kend = kbeg + 72;
    for (int k = kbeg; k < kend; ++k) {
        float kp[32];
        #pragma unroll
        for (int j4 = 0; j4 < 8; ++j4)
            *(float4*)&kp[4 * j4] = *(const float4*)&kls[k * 32 + 4 * j4];
        float s0 = 0.f, s1 = 0.f, s2 = 0.f, s3 = 0.f;
        #pragma unroll
        for (int j = 0; j < 32; j += 4) {
            s0 += qr[j]   * kp[j];   s1 += qr[j+1] * kp[j+1];
            s2 += qr[j+2] * kp[j+2]; s3 += qr[j+3] * kp[j+3];
        }
        float d = ((s0 + s1) + (s2 + s3)) * ATT_SCALE;
        if (d > mr + 8.0f) {
            float f = __expf(mr - d);
            sum *= f;
            #pragma unroll
            for (int j = 0; j < 32; ++j) acc[j] *= f;
            mr = d;
        }
        float pr = __expf(d - mr);
        sum += pr;
        #pragma unroll
        for (int j = 0; j < 32; ++j) acc[j] += pr * vls[k * 32 + j];
    }
    __syncthreads();
    float* pb = smem;                        // 64*3*34 floats
    if (wv > 0) {
        int base = (q * 3 + wv - 1) * 34;
        pb[base] = mr; pb[base + 1] = sum;
        #pragma unroll
        for (int j = 0; j < 32; ++j) pb[base + 2 + j] = acc[j];
    }
    __syncthreads();
    if (wv == 0) {
        float M = mr;
        #pragma unroll
        for (int s = 0; s < 3; ++s) M = fmaxf(M, pb[(q * 3 + s) * 34]);
        float f0 = __expf(mr - M);
        float den = sum * f0;
        float fs[3];
        #pragma unroll
        for (int s = 0; s < 3; ++s) {
            int base = (q * 3 + s) * 34;
            fs[s] = __expf(pb[base] - M);
            den += pb[base + 1] * fs[s];
        }
        float inv = 1.0f / den;
        float* ap = abuf2 + ((size_t)(h * WWD + w)) * 128 + m * DHD;
        #pragma unroll
        for (int j4 = 0; j4 < 8; ++j4) {
            float4 o;
            float v0 = acc[4*j4]   * f0, v1 = acc[4*j4+1] * f0;
            float v2 = acc[4*j4+2] * f0, v3 = acc[4*j4+3] * f0;
            #pragma unroll
            for (int s = 0; s < 3; ++s) {
                int base = (q * 3 + s) * 34 + 2;
                v0 += pb[base + 4*j4]     * fs[s];
                v1 += pb[base + 4*j4 + 1] * fs[s];
                v2 += pb[base + 4*j4 + 2] * fs[s];
                v3 += pb[base + 4*j4 + 3] * fs[s];
            }
            o.x = v0 * inv; o.y = v1 * inv; o.z = v2 * inv; o.w = v3 * inv;
            *(float4*)&ap[4 * j4] = o;
        }
    }
}

// ---------- mean over 6 views + window->hw permute ----------
__global__ void k_mean(const float* __restrict__ abuf, float* __restrict__ amean) {
    int t = threadIdx.x;
    for (int rr = 0; rr < 8; ++rr) {
        int hw = blockIdx.x * 8 + rr;
        int h = hw >> 6, w = hw & 63;
        int xw = h >> 3, w1 = h & 7, yw = w >> 3, w2 = w & 7;
        int l = xw * 8 + yw, ww = w1 * 8 + w2;
        const float* src = abuf + ((size_t)(l * 64 + ww)) * 6 * 128;
        float s = 0.f;
        #pragma unroll
        for (int n = 0; n < 6; ++n) s += src[n * 128 + t];
        amean[(size_t)hw * 128 + t] = s * (1.0f / 6.0f);
    }
}

// ---------- depthwise 3x3 + gelu + SE partials ----------
__global__ void k_dwconv(const float* __restrict__ ex, const float* __restrict__ dwgt,
                         float* __restrict__ dwout, float* __restrict__ separt) {
    const int TILE = 16;
    int ch = threadIdx.x;
    int hw0 = blockIdx.x * TILE;
    float wreg[9];
    #pragma unroll
    for (int i = 0; i < 9; ++i) wreg[i] = dwgt[ch * 9 + i];
    float sacc = 0.f;
    for (int ti = 0; ti < TILE; ++ti) {
        int hw = hw0 + ti;
        int h = hw >> 6, w = hw & 63;
        float s = 0.f;
        #pragma unroll
        for (int dy = -1; dy <= 1; ++dy) {
            int h2 = h + dy;
            if (h2 < 0 || h2 >= 64) continue;
            #pragma unroll
            for (int dx = -1; dx <= 1; ++dx) {
                int w2 = w + dx;
                if (w2 < 0 || w2 >= 64) continue;
                s += ex[((size_t)(h2 * 64 + w2)) * 512 + ch] * wreg[(dy + 1) * 3 + (dx + 1)];
            }
        }
        float o = gelu_f(s * BN_S);
        dwout[(size_t)hw * 512 + ch] = o;
        sacc += o;
    }
    separt[(size_t)blockIdx.x * 512 + ch] = sacc;
}

// ---------- SE ----------
__global__ void k_se(const float* __restrict__ separt, int nparts,
                     const float* __restrict__ s1w, const float* __restrict__ s1b,
                     const float* __restrict__ s2w, const float* __restrict__ s2b,
                     float* __restrict__ se) {
    __shared__ float mean[512];
    __shared__ float s1[32];
    int tid = threadIdx.x;
    float s = 0.f;
    for (int b = 0; b < nparts; ++b) s += separt[(size_t)b * 512 + tid];
    mean[tid] = s * (1.0f / 4096.0f);
    __syncthreads();
    if (tid < 32) {
        float acc = s1b[tid];
        const float* wr = s1w + (size_t)tid * 512;
        for (int c = 0; c < 512; ++c) acc += mean[c] * wr[c];
        s1[tid] = gelu_f(acc);
    }
    __syncthreads();
    float acc = s2b[tid];
    const float* wr = s2w + (size_t)tid * 32;
    #pragma unroll
    for (int j = 0; j < 32; ++j) acc += s1[j] * wr[j];
    se[tid] = 1.0f / (1.0f + __expf(-acc));
}

extern "C" void kernel_launch(void* const* d_in, const int* in_sizes, int n_in,
                              void* d_out, int out_size, void* d_ws, size_t ws_size,
                              hipStream_t stream) {
    (void)in_sizes; (void)n_in; (void)out_size; (void)ws_size;
    const float* x      = (const float*)d_in[1];
    const float* feat   = (const float*)d_in[2];
    const float* I_inv  = (const float*)d_in[3];
    const float* E_inv  = (const float*)d_in[4];
    const float* bev    = (const float*)d_in[5];
    const float* fl_w   = (const float*)d_in[6];
    const float* fp_w   = (const float*)d_in[7];
    const float* be_w   = (const float*)d_in[8];
    const float* be_b   = (const float*)d_in[9];
    const float* ie_w   = (const float*)d_in[10];
    const float* ce_w   = (const float*)d_in[11];
    const float* a1_qw  = (const float*)d_in[12];
    const float* a1_qb  = (const float*)d_in[13];
    const float* a1_kw  = (const float*)d_in[14];
    const float* a1_kb  = (const float*)d_in[15];
    const float* a1_vw  = (const float*)d_in[16];
    const float* a1_vb  = (const float*)d_in[17];
    const float* a1_pw  = (const float*)d_in[18];
    const float* a1_pb  = (const float*)d_in[19];
    const float* a2_qw  = (const float*)d_in[20];
    const float* a2_qb  = (const float*)d_in[21];
    const float* a2_kw  = (const float*)d_in[22];
    const float* a2_kb  = (const float*)d_in[23];
    const float* a2_vw  = (const float*)d_in[24];
    const float* a2_vb  = (const float*)d_in[25];
    const float* a2_pw  = (const float*)d_in[26];
    const float* a2_pb  = (const float*)d_in[27];
    const float* m1_w1  = (const float*)d_in[28];
    const float* m1_b1  = (const float*)d_in[29];
    const float* m1_w2  = (const float*)d_in[30];
    const float* m1_b2  = (const float*)d_in[31];
    const float* m2_w1  = (const float*)d_in[32];
    const float* m2_b1  = (const float*)d_in[33];
    const float* m2_w2  = (const float*)d_in[34];
    const float* m2_b2  = (const float*)d_in[35];
    const float* mb_ew  = (const float*)d_in[36];
    const float* mb_dw  = (const float*)d_in[37];
    const float* mb_s1w = (const float*)d_in[38];
    const float* mb_s1b = (const float*)d_in[39];
    const float* mb_s2w = (const float*)d_in[40];
    const float* mb_s2b = (const float*)d_in[41];
    const float* mb_pw  = (const float*)d_in[42];
    const float* pm_w1  = (const float*)d_in[43];
    const float* pm_b1  = (const float*)d_in[44];
    const float* pm_w2  = (const float*)d_in[45];
    const float* pm_b2  = (const float*)d_in[46];
    const float* po_w   = (const float*)d_in[47];
    const float* po_b   = (const float*)d_in[48];

    float* ws = (float*)d_ws;
    // arena (floats), stage-based reuse; peak ~80 MB
    float* S0 = ws + 0;         // 3145728 : query -> abuf -> expandb
    float* S1 = ws + 3145728;   // 3145728 : qh1 -> qh2 -> dwout+separt+sebuf
    float* S2 = ws + 6291456;   // 2359296 : f_cl -> kh1 -> kh2
    float* S3 = ws + 8650752;   // 2359296 : kinit -> vh1 -> vh2
    float* S4 = ws + 11010048;  // 2359296 : key
    float* S5 = ws + 13369344;  // 2359296 : val
    float* amean  = ws + 15728640;  // 524288
    float* qimg   = ws + 16252928;  // 524288
    float* gbuf   = ws + 16777216;  // 1048576
    float* qimg2  = ws + 17825792;  // 524288
    float* zln    = ws + 18350080;  // 524288
    float* abuf2  = ws + 18874368;  // 524288
    float* mbout  = ws + 19398656;  // 524288

    float* f_cl  = S2;
    float* kinit = S3;
    float* key   = S4;
    float* val   = S5;
    float* query = S0;
    float* qh1   = S1;
    float* kh1   = S2;
    float* vh1   = S3;
    float* abuf  = S0;
    float* qh2   = S1;
    float* kh2   = S2;
    float* vh2   = S3;
    float* expandb = S0;
    float* dwout   = S1;
    float* separt  = S1 + 2097152;
    float* sebuf   = S1 + 2097152 + 131072;

    // stage 0: layout transforms + embeddings
    k_trans<<<dim3(96, 4, 6), 256, 0, stream>>>(feat, f_cl);
    k_embed<<<dim3(192, 6), 128, 0, stream>>>(I_inv, E_inv, ie_w, ce_w, kinit);
    k_query<<<dim3(256, 6), 128, 0, stream>>>(x, bev, be_w, be_b, E_inv, ce_w, query);
    // key/val dual GEMM: key = f.fp + kinit ; val = f.fl
    k_gemm<128,128,128,32,2, 0,0,0,0, 1,0,0, 1,0><<<576, 256, 0, stream>>>(
        f_cl, fp_w, nullptr, kinit, nullptr, fl_w, nullptr, val, nullptr, key);

    // stage 1: attn1 + MLP1
    k_gemm<128,128,128,32,2, 1,1,0,0, 0,0,0, 0,0><<<768, 256, 0, stream>>>(
        query, a1_qw, a1_qb, nullptr, nullptr, nullptr, nullptr, nullptr, nullptr, qh1);
    k_gemm<128,128,128,32,2, 1,1,0,0, 0,0,0, 0,0><<<576, 256, 0, stream>>>(
        key, a1_kw, a1_kb, nullptr, nullptr, nullptr, nullptr, nullptr, nullptr, kh1);
    k_gemm<128,128,128,32,2, 1,1,0,0, 0,0,0, 0,0><<<576, 256, 0, stream>>>(
        val, a1_vw, a1_vb, nullptr, nullptr, nullptr, nullptr, nullptr, nullptr, vh1);
    k_attn1<<<dim3(64, HEADS), 384, 0, stream>>>(qh1, kh1, vh1, abuf);
    k_mean<<<512, 128, 0, stream>>>(abuf, amean);
    k_gemm<128,128,128,16,1, 0,1,0,0, 2,0,0, 0,0><<<256, 256, 0, stream>>>(
        amean, a1_pw, a1_pb, x, nullptr, nullptr, nullptr, nullptr, nullptr, qimg);
    k_gemm<128,256,256,16,2, 1,1,1,0, 0,0,0, 0,0><<<256, 256, 0, stream>>>(
        qimg, m1_w1, m1_b1, nullptr, nullptr, nullptr, nullptr, nullptr, nullptr, gbuf);
    k_gemm<256,128,128,16,1, 0,1,0,0, 1,0,0, 0,0><<<256, 256, 0, stream>>>(
        gbuf, m1_w2, m1_b2, qimg, nullptr, nullptr, nullptr, nullptr, nullptr, qimg);

    // stage 2: attn2 + MLP2
    k_gemm<128,128,128,16,1, 1,1,0,0, 0,0,0, 0,0><<<256, 256, 0, stream>>>(
        qimg, a2_qw, a2_qb, nullptr, nullptr, nullptr, nullptr, nullptr, nullptr, qh2);
    k_gemm<128,128,128,32,2, 1,1,0,0, 0,0,0, 0,0><<<576, 256, 0, stream>>>(
        key, a2_kw, a2_kb, nullptr, nullptr, nullptr, nullptr, nullptr, nullptr, kh2);
    k_gemm<128,128,128,32,2, 1,1,0,0, 0,0,0, 0,0><<<576, 256, 0, stream>>>(
        val, a2_vw, a2_vb, nullptr, nullptr, nullptr, nullptr, nullptr, nullptr, vh2);
    k_attn2<<<dim3(64, HEADS), 256, 0, stream>>>(qh2, kh2, vh2, abuf2);
    k_gemm<128,128,128,16,1, 0,1,0,0, 1,0,0, 0,0><<<256, 256, 0, stream>>>(
        abuf2, a2_pw, a2_pb, qimg, nullptr, nullptr, nullptr, nullptr, nullptr, qimg2);
    k_gemm<128,256,256,16,2, 1,1,1,0, 0,0,0, 0,0><<<256, 256, 0, stream>>>(
        qimg2, m2_w1, m2_b1, nullptr, nullptr, nullptr, nullptr, nullptr, nullptr, gbuf);
    k_gemm<256,128,128,16,1, 0,1,0,0, 1,0,0, 0,0><<<256, 256, 0, stream>>>(
        gbuf, m2_w2, m2_b2, qimg2, nullptr, nullptr, nullptr, nullptr, nullptr, qimg2);

    // stage 3: postnorm(LN fused into expand) + MBConv + FFN + proj_out
    k_gemm<128,128,512,16,1, 1,0,1,1, 0,0,0, 0,1><<<dim3(256, 4), 256, 0, stream>>>(
        qimg2, mb_ew, nullptr, nullptr, nullptr, nullptr, nullptr, nullptr, zln, expandb);
    k_dwconv<<<256, 512, 0, stream>>>(expandb, mb_dw, dwout, separt);
    k_se<<<1, 512, 0, stream>>>(separt, 256, mb_s1w, mb_s1b, mb_s2w, mb_s2b, sebuf);
    k_gemm<512,128,128,16,1, 0,0,0,1, 1,0,1, 0,0><<<256, 256, 0, stream>>>(
        dwout, mb_pw, nullptr, zln, sebuf, nullptr, nullptr, nullptr, nullptr, mbout);
    k_gemm<128,256,256,16,2, 0,1,1,0, 0,0,0, 0,0><<<256, 256, 0, stream>>>(
        mbout, pm_w1, pm_b1, nullptr, nullptr, nullptr, nullptr, nullptr, nullptr, gbuf);
    k_gemm<256,128,128,16,1, 0,1,0,0, 1,0,0, 0,0><<<256, 256, 0, stream>>>(
        gbuf, pm_w2, pm_b2, mbout, nullptr, nullptr, nullptr, nullptr, nullptr, mbout);
    k_gemm<128,128,128,16,1, 0,1,1,0, 0,1,0, 0,0><<<256, 256, 0, stream>>>(
        mbout, po_w, po_b, nullptr, nullptr, nullptr, nullptr, nullptr, nullptr, (float*)d_out);
}

// Round 4
// 582.885 us; speedup vs baseline: 3.6953x; 1.0329x over previous
//
#include <hip/hip_runtime.h>
#include <math.h>

#define NV 6
#define FHH 32
#define FWW 96
#define PIMG (FHH*FWW)   // 3072
#define HH 64
#define WWD 64
#define PBEV (HH*WWD)    // 4096
#define HEADS 4
#define DHD 32
#define KROWS 288
#define BN_S 0.9999950000374996f
#define LN_EPS 1e-5f
#define ATT_SCALE 0.17677669529663687f  // 32^-0.5

__device__ __forceinline__ float gelu_f(float x) {
    return 0.5f * x * (1.0f + erff(x * 0.70710678118654752f));
}

__device__ __forceinline__ float blockSum128(float v, float* red, int tid) {
    #pragma unroll
    for (int o = 32; o > 0; o >>= 1) v += __shfl_down(v, o, 64);
    __syncthreads();
    if ((tid & 63) == 0) red[tid >> 6] = v;
    __syncthreads();
    return red[0] + red[1];
}

// ---------- feature transpose + BN*relu : [n][128][3072] -> [n*3072][128] ----------
__global__ void k_trans(const float* __restrict__ feature, float* __restrict__ f_cl) {
    __shared__ float tile[32][33];
    int n = blockIdx.z, c0 = blockIdx.y * 32, p0 = blockIdx.x * 32;
    int tp = threadIdx.x & 31, tg = threadIdx.x >> 5;
    #pragma unroll
    for (int i = 0; i < 4; ++i) {
        int c = tg + 8 * i;
        tile[c][tp] = feature[((size_t)(n * 128 + c0 + c)) * PIMG + p0 + tp];
    }
    __syncthreads();
    int cw = threadIdx.x & 31, pg = threadIdx.x >> 5;
    #pragma unroll
    for (int i = 0; i < 4; ++i) {
        int p = pg + 8 * i;
        float v = fmaxf(tile[cw][p] * BN_S, 0.0f);
        f_cl[((size_t)(n * PIMG + p0 + p)) * 128 + c0 + cw] = v;
    }
}

// ---------- geometric image embedding -> kinit [n*3072][128] ----------
__global__ void k_embed(const float* __restrict__ I_inv, const float* __restrict__ E_inv,
                        const float* __restrict__ ie_w, const float* __restrict__ ce_w,
                        float* __restrict__ kinit) {
    const int TILE = 16;
    int n = blockIdx.y, p0 = blockIdx.x * TILE, t = threadIdx.x;
    __shared__ float red[2];
    const float* E  = E_inv + n * 16;
    const float* Ii = I_inv + n * 9;
    float cemb = E[3]  * ce_w[t*4+0] + E[7]  * ce_w[t*4+1]
               + E[11] * ce_w[t*4+2] + E[15] * ce_w[t*4+3];
    for (int pos = 0; pos < TILE; ++pos) {
        int p = p0 + pos;
        int h = p / FWW, w = p % FWW;
        float gx = (float)w * (768.0f / 95.0f);
        float gy = (float)h * (256.0f / 31.0f);
        float c0 = Ii[0]*gx + Ii[1]*gy + Ii[2];
        float c1 = Ii[3]*gx + Ii[4]*gy + Ii[5];
        float c2 = Ii[6]*gx + Ii[7]*gy + Ii[8];
        float d0 = E[0]*c0  + E[1]*c1  + E[2]*c2  + E[3];
        float d1 = E[4]*c0  + E[5]*c1  + E[6]*c2  + E[7];
        float d2 = E[8]*c0  + E[9]*c1  + E[10]*c2 + E[11];
        float d3 = E[12]*c0 + E[13]*c1 + E[14]*c2 + E[15];
        float emb = d0*ie_w[t*4+0] + d1*ie_w[t*4+1]
                  + d2*ie_w[t*4+2] + d3*ie_w[t*4+3] - cemb;
        float ss = blockSum128(emb * emb, red, t);
        kinit[((size_t)(n * PIMG + p)) * 128 + t] = emb / (sqrtf(ss) + 1e-7f);
    }
}

// ---------- query [n*4096][128] ----------
__global__ void k_query(const float* __restrict__ x, const float* __restrict__ bev,
                        const float* __restrict__ be_w, const float* __restrict__ be_b,
                        const float* __restrict__ E_inv, const float* __restrict__ ce_w,
                        float* __restrict__ query) {
    const int TILE = 16;
    int n = blockIdx.y, p0 = blockIdx.x * TILE, t = threadIdx.x;
    __shared__ float red[2];
    const float* E = E_inv + n * 16;
    float cemb = E[3]  * ce_w[t*4+0] + E[7]  * ce_w[t*4+1]
               + E[11] * ce_w[t*4+2] + E[15] * ce_w[t*4+3];
    float bw0 = be_w[t*2+0], bw1 = be_w[t*2+1], bb = be_b[t];
    for (int pos = 0; pos < TILE; ++pos) {
        int p = p0 + pos;
        float emb = bev[p]*bw0 + bev[PBEV + p]*bw1 + bb - cemb;
        float ss = blockSum128(emb * emb, red, t);
        float qv = emb / (sqrtf(ss) + 1e-7f) + x[(size_t)t * PBEV + p];
        query[((size_t)(n * PBEV + p)) * 128 + t] = qv;
    }
}

// ---------- generic tiled f32 GEMM (256 threads) ----------
template<int NI, int NO, int NOT, int BR, int MR, int LNF, int BIASF, int ACT,
         int SCL, int ADDM, int STM, int ASCL, int DUAL, int WRLN>
__global__ __launch_bounds__(256)
void k_gemm(const float* __restrict__ A, const float* __restrict__ W,
            const float* __restrict__ bias, const float* __restrict__ addb,
            const float* __restrict__ ascale, const float* __restrict__ W2,
            const float* __restrict__ bias2, float* __restrict__ out2,
            float* __restrict__ aux, float* __restrict__ out) {
    constexpr int CG = NO / 8;
    constexpr int RG = 256 / CG;
    static_assert(RG * MR == BR, "tile mismatch");
    __shared__ float a_lds[BR][NI + 4];
    __shared__ float w_lds[32][NO + 4];
    const int t  = threadIdx.x;
    const int rb = blockIdx.x * BR;
    const int co = blockIdx.y * NO;

    constexpr int AF4 = (BR * NI / 4) / 256;
    #pragma unroll
    for (int i = 0; i < AF4; ++i) {
        int f4 = i * 256 + t;
        int row = f4 / (NI / 4), q = f4 % (NI / 4);
        float4 v = *(const float4*)&A[(size_t)(rb + row) * NI + 4 * q];
        if constexpr (ASCL) {
            float4 sc = *(const float4*)&ascale[4 * q];
            v.x *= sc.x; v.y *= sc.y; v.z *= sc.z; v.w *= sc.w;
        }
        *(float4*)&a_lds[row][4 * q] = v;
    }
    __syncthreads();

    if constexpr (LNF) {
        constexpr int TPR = 256 / BR;
        constexpr int CPT = NI / TPR;
        int row = t / TPR, seg = t % TPR, base = seg * CPT;
        float sum = 0.f;
        #pragma unroll
        for (int j = 0; j < CPT / 4; ++j) {
            float4 v = *(float4*)&a_lds[row][base + 4 * j];
            sum += (v.x + v.y) + (v.z + v.w);
        }
        #pragma unroll
        for (int o = 1; o < TPR; o <<= 1) sum += __shfl_xor(sum, o, 64);
        float mu = sum * (1.0f / NI);
        float ss = 0.f;
        #pragma unroll
        for (int j = 0; j < CPT / 4; ++j) {
            float4 v = *(float4*)&a_lds[row][base + 4 * j];
            float a = v.x - mu, b = v.y - mu, c = v.z - mu, d = v.w - mu;
            ss += (a * a + b * b) + (c * c + d * d);
        }
        #pragma unroll
        for (int o = 1; o < TPR; o <<= 1) ss += __shfl_xor(ss, o, 64);
        float rs = rsqrtf(ss * (1.0f / NI) + LN_EPS);
        #pragma unroll
        for (int j = 0; j < CPT / 4; ++j) {
            float4 v = *(float4*)&a_lds[row][base + 4 * j];
            v.x = (v.x - mu) * rs; v.y = (v.y - mu) * rs;
            v.z = (v.z - mu) * rs; v.w = (v.w - mu) * rs;
            *(float4*)&a_lds[row][base + 4 * j] = v;
            if constexpr (WRLN) {
                if (blockIdx.y == 0)
                    *(float4*)&aux[(size_t)(rb + row) * NI + base + 4 * j] = v;
            }
        }
        __syncthreads();
    }

    const int cg = t % CG, rg = t / CG;
    const int c0 = cg * 8, r0 = rg * MR;
    constexpr int NCH = NI / 32;
    constexpr int WF4 = NO / 32;

    #pragma unroll 1
    for (int set = 0; set <= DUAL; ++set) {
        const float* Wc = set ? W2 : W;
        const float* bc = set ? bias2 : bias;
        float* oc = set ? out2 : out;
        float acc[MR][8];
        #pragma unroll
        for (int i = 0; i < MR; ++i)
            #pragma unroll
            for (int j = 0; j < 8; ++j) acc[i][j] = 0.f;

        #pragma unroll 1
        for (int ch = 0; ch < NCH; ++ch) {
            int k0 = ch * 32;
            if (ch || set) __syncthreads();
            #pragma unroll
            for (int i = 0; i < WF4; ++i) {
                int f4 = i * 256 + t;
                int c = f4 >> 3, kq = f4 & 7;
                float4 v = *(const float4*)&Wc[(size_t)(co + c) * NI + k0 + 4 * kq];
                w_lds[4 * kq + 0][c] = v.x; w_lds[4 * kq + 1][c] = v.y;
                w_lds[4 * kq + 2][c] = v.z; w_lds[4 * kq + 3][c] = v.w;
            }
            __syncthreads();
            #pragma unroll
            for (int kk = 0; kk < 32; ++kk) {
                float4 w0 = *(float4*)&w_lds[kk][c0];
                float4 w1 = *(float4*)&w_lds[kk][c0 + 4];
                #pragma unroll
                for (int i = 0; i < MR; ++i) {
                    float a = a_lds[r0 + i][k0 + kk];
                    acc[i][0] += a * w0.x; acc[i][1] += a * w0.y;
                    acc[i][2] += a * w0.z; acc[i][3] += a * w0.w;
                    acc[i][4] += a * w1.x; acc[i][5] += a * w1.y;
                    acc[i][6] += a * w1.z; acc[i][7] += a * w1.w;
                }
            }
        }

        float bi[8];
        if constexpr (BIASF) {
            #pragma unroll
            for (int j = 0; j < 8; ++j) bi[j] = bc[co + c0 + j];
        }
        #pragma unroll
        for (int i = 0; i < MR; ++i)
            #pragma unroll
            for (int j = 0; j < 8; ++j) {
                float v = acc[i][j];
                if constexpr (BIASF) v += bi[j];
                if constexpr (SCL)   v *= BN_S;
                if constexpr (ACT)   v = gelu_f(v);
                acc[i][j] = v;
            }
        if constexpr (ADDM == 1) {
            if (set == 0) {
                #pragma unroll
                for (int i = 0; i < MR; ++i) {
                    float4 a0 = *(const float4*)&addb[(size_t)(rb + r0 + i) * NOT + co + c0];
                    float4 a1 = *(const float4*)&addb[(size_t)(rb + r0 + i) * NOT + co + c0 + 4];
                    acc[i][0] += a0.x; acc[i][1] += a0.y; acc[i][2] += a0.z; acc[i][3] += a0.w;
                    acc[i][4] += a1.x; acc[i][5] += a1.y; acc[i][6] += a1.z; acc[i][7] += a1.w;
                }
            }
        }
        if constexpr (ADDM == 2) {
            if (set == 0) {
                #pragma unroll
                for (int j = 0; j < 8; ++j)
                    #pragma unroll
                    for (int i = 0; i < MR; ++i)
                        acc[i][j] += addb[(size_t)(co + c0 + j) * PBEV + rb + r0 + i];
            }
        }
        if constexpr (STM == 0) {
            #pragma unroll
            for (int i = 0; i < MR; ++i) {
                float4 o0 = {acc[i][0], acc[i][1], acc[i][2], acc[i][3]};
                float4 o1 = {acc[i][4], acc[i][5], acc[i][6], acc[i][7]};
                *(float4*)&oc[(size_t)(rb + r0 + i) * NOT + co + c0]     = o0;
                *(float4*)&oc[(size_t)(rb + r0 + i) * NOT + co + c0 + 4] = o1;
            }
        } else {
            #pragma unroll
            for (int j = 0; j < 8; ++j)
                #pragma unroll
                for (int i = 0; i < MR; ++i)
                    oc[(size_t)(co + c0 + j) * PBEV + rb + r0 + i] = acc[i][j];
        }
    }
}

// ---------- attention 1: 12 waves, 4-way key split, 2 q-rows/thread, 3-phase merge ----------
__global__ __launch_bounds__(768)
void k_attn1(const float* __restrict__ qh, const float* __restrict__ kh,
             const float* __restrict__ vh, float* __restrict__ abuf) {
    const int l = blockIdx.x, m = blockIdx.y;
    const int xw = l >> 3, yw = l & 7;
    const int t = threadIdx.x;
    __shared__ float smem[2 * KROWS * 32];   // 73728 B
    float* kls = smem;
    float* vls = smem + KROWS * 32;
    #pragma unroll
    for (int i = 0; i < 3; ++i) {
        int f4 = i * 768 + t;                // 2304 = 288*8
        int row = f4 >> 3, q4 = f4 & 7;
        int n = row / 48, kk = row % 48;
        int k1 = kk / 12, k2 = kk % 12;
        int h = xw * 4 + k1, w = yw * 12 + k2;
        size_t src = ((size_t)(n * PIMG + h * FWW + w)) * 128 + m * DHD + 4 * q4;
        *(float4*)&kls[row * 32 + 4 * q4] = *(const float4*)&kh[src];
        *(float4*)&vls[row * 32 + 4 * q4] = *(const float4*)&vh[src];
    }
    const int wv = t / 192, p = t % 192;
    float qr[2][32];
    int ww_[2], n_[2];
    #pragma unroll
    for (int b = 0; b < 2; ++b) {
        int q = p + 192 * b;
        int n = q >> 6, ww = q & 63;
        int w1 = ww >> 3, w2 = ww & 7;
        int h = xw * 8 + w1, w = yw * 8 + w2;
        const float* qp = qh + ((size_t)(n * PBEV + h * WWD + w)) * 128 + m * DHD;
        #pragma unroll
        for (int j4 = 0; j4 < 8; ++j4)
            *(float4*)&qr[b][4 * j4] = *(const float4*)&qp[4 * j4];
        ww_[b] = ww; n_[b] = n;
    }
    __syncthreads();

    float mr[2] = {-1e30f, -1e30f}, sum[2] = {0.f, 0.f};
    float acc[2][32];
    #pragma unroll
    for (int b = 0; b < 2; ++b)
        #pragma unroll
        for (int j = 0; j < 32; ++j) acc[b][j] = 0.f;

    const int kbeg = wv * 72, kend = kbeg + 72;
    for (int k = kbeg; k < kend; ++k) {
        float kp[32];
        #pragma unroll
        for (int j4 = 0; j4 < 8; ++j4)
            *(float4*)&kp[4 * j4] = *(const float4*)&kls[k * 32 + 4 * j4];
        float pr[2];
        #pragma unroll
        for (int b = 0; b < 2; ++b) {
            float s0 = 0.f, s1 = 0.f, s2 = 0.f, s3 = 0.f;
            #pragma unroll
            for (int j = 0; j < 32; j += 4) {
                s0 += qr[b][j]   * kp[j];   s1 += qr[b][j+1] * kp[j+1];
                s2 += qr[b][j+2] * kp[j+2]; s3 += qr[b][j+3] * kp[j+3];
            }
            float d = ((s0 + s1) + (s2 + s3)) * ATT_SCALE;
            if (d > mr[b] + 8.0f) {
                float f = __expf(mr[b] - d);
                sum[b] *= f;
                #pragma unroll
                for (int j = 0; j < 32; ++j) acc[b][j] *= f;
                mr[b] = d;
            }
            pr[b] = __expf(d - mr[b]);
            sum[b] += pr[b];
        }
        float vp[32];
        #pragma unroll
        for (int j4 = 0; j4 < 8; ++j4)
            *(float4*)&vp[4 * j4] = *(const float4*)&vls[k * 32 + 4 * j4];
        #pragma unroll
        for (int j = 0; j < 32; ++j) {
            acc[0][j] += pr[0] * vp[j];
            acc[1][j] += pr[1] * vp[j];
        }
    }

    // 3-phase sequential merge into wv==0 (buffer reuses dead K/V LDS: 384*34 floats)
    float* buf = smem;
    #pragma unroll 1
    for (int s = 1; s < 4; ++s) {
        __syncthreads();
        if (wv == s) {
            #pragma unroll
            for (int b = 0; b < 2; ++b) {
                int base = (b * 192 + p) * 34;
                buf[base] = mr[b]; buf[base + 1] = sum[b];
                #pragma unroll
                for (int j = 0; j < 32; ++j) buf[base + 2 + j] = acc[b][j];
            }
        }
        __syncthreads();
        if (wv == 0) {
            #pragma unroll
            for (int b = 0; b < 2; ++b) {
                int base = (b * 192 + p) * 34;
                float m1 = buf[base], s1 = buf[base + 1];
                float M = fmaxf(mr[b], m1);
                float f0 = __expf(mr[b] - M), f1 = __expf(m1 - M);
                sum[b] = sum[b] * f0 + s1 * f1;
                #pragma unroll
                for (int j = 0; j < 32; ++j)
                    acc[b][j] = acc[b][j] * f0 + buf[base + 2 + j] * f1;
                mr[b] = M;
            }
        }
    }
    if (wv == 0) {
        #pragma unroll
        for (int b = 0; b < 2; ++b) {
            float inv = 1.0f / sum[b];
            float* ap = abuf + ((size_t)((l * 64 + ww_[b]) * 6 + n_[b])) * 128 + m * DHD;
            #pragma unroll
            for (int j4 = 0; j4 < 8; ++j4) {
                float4 o = {acc[b][4*j4] * inv, acc[b][4*j4+1] * inv,
                            acc[b][4*j4+2] * inv, acc[b][4*j4+3] * inv};
                *(float4*)&ap[4 * j4] = o;
            }
        }
    }
}

// ---------- attention 2: 8 waves, 8-way key split, parallel 7-slot merge ----------
__global__ __launch_bounds__(512)
void k_attn2(const float* __restrict__ qh, const float* __restrict__ kh,
             const float* __restrict__ vh, float* __restrict__ abuf2) {
    const int l = blockIdx.x, m = blockIdx.y;
    const int xw = l >> 3, yw = l & 7;
    const int t = threadIdx.x;
    __shared__ float smem[2 * KROWS * 32];
    float* kls = smem;
    float* vls = smem + KROWS * 32;
    #pragma unroll
    for (int i = 0; i < 5; ++i) {
        int f4 = i * 512 + t;                // 2304
        if (f4 < 2304) {
            int row = f4 >> 3, q4 = f4 & 7;
            int n = row / 48, kk = row % 48;
            int k1 = kk / 12, k2 = kk % 12;
            int h = k1 * 8 + xw, w = k2 * 8 + yw;
            size_t src = ((size_t)(n * PIMG + h * FWW + w)) * 128 + m * DHD + 4 * q4;
            *(float4*)&kls[row * 32 + 4 * q4] = *(const float4*)&kh[src];
            *(float4*)&vls[row * 32 + 4 * q4] = *(const float4*)&vh[src];
        }
    }
    const int wv = t >> 6, q = t & 63;
    const int w1 = q >> 3, w2 = q & 7;
    const int h = w1 * 8 + xw, w = w2 * 8 + yw;
    float qr[32];
    const float* qp = qh + ((size_t)(h * WWD + w)) * 128 + m * DHD;
    #pragma unroll
    for (int j4 = 0; j4 < 8; ++j4)
        *(float4*)&qr[4 * j4] = *(const float4*)&qp[4 * j4];
    __syncthreads();

    float mr = -1e30f, sum = 0.f, acc[32];
    #pragma unroll
    for (int j = 0; j < 32; ++j) acc[j] = 0.f;
    const int kbeg = wv * 36, kend = kbeg + 36;
    for (int k = kbeg; k < kend; ++k) {
        float kp[32];
        #pragma unroll
        for (int j4 = 0; j4 < 8; ++j4)
            *(float4*)&kp[4 * j4] = *(const float4*)&kls[k * 32 + 4 * j4];
        float s0 = 0.f, s1 = 0.f, s2 = 0.f, s3 = 0.f;
        #pragma unroll
        for (int j = 0; j < 32; j += 4) {
            s0 += qr[j]   * kp[j];   s1 += qr[j+1] * kp[j+1];
            s2 += qr[j+2] * kp[j+2]; s3 += qr[j+3] * kp[j+3];
        }
        float d = ((s0 + s1) + (s2 + s3)) * ATT_SCALE;
        if (d > mr + 8.0f) {
            float f = __expf(mr - d);
            sum *= f;
            #pragma unroll
            for (int j = 0; j < 32; ++j) acc[j] *= f;
            mr = d;
        }
        float pr = __expf(d - mr);
        sum += pr;
        #pragma unroll
        for (int j = 0; j < 32; ++j) acc[j] += pr * vls[k * 32 + j];
    }
    __syncthreads();
    float* pb = smem;                        // 7*64*34 = 15232 floats (fits 18432)
    if (wv > 0) {
        int base = ((wv - 1) * 64 + q) * 34;
        pb[base] = mr; pb[base + 1] = sum;
        #pragma unroll
        for (int j = 0; j < 32; ++j) pb[base + 2 + j] = acc[j];
    }
    __syncthreads();
    if (wv == 0) {
        #pragma unroll 1
        for (int s = 0; s < 7; ++s) {
            int base = (s * 64 + q) * 34;
            float m1 = pb[base], s1 = pb[base + 1];
            float M = fmaxf(mr, m1);
            float f0 = __expf(mr - M), f1 = __expf(m1 - M);
            sum = sum * f0 + s1 * f1;
            #pragma unroll
            for (int j = 0; j < 32; ++j)
                acc[j] = acc[j] * f0 + pb[base + 2 + j] * f1;
            mr = M;
        }
        float inv = 1.0f / sum;
        float* ap = abuf2 + ((size_t)(h * WWD + w)) * 128 + m * DHD;
        #pragma unroll
        for (int j4 = 0; j4 < 8; ++j4) {
            float4 o = {acc[4*j4] * inv, acc[4*j4+1] * inv,
                        acc[4*j4+2] * inv, acc[4*j4+3] * inv};
            *(float4*)&ap[4 * j4] = o;
        }
    }
}

// ---------- mean over 6 views + window->hw permute ----------
__global__ void k_mean(const float* __restrict__ abuf, float* __restrict__ amean) {
    int t = threadIdx.x;
    for (int rr = 0; rr < 8; ++rr) {
        int hw = blockIdx.x * 8 + rr;
        int h = hw >> 6, w = hw & 63;
        int xw = h >> 3, w1 = h & 7, yw = w >> 3, w2 = w & 7;
        int l = xw * 8 + yw, ww = w1 * 8 + w2;
        const float* src = abuf + ((size_t)(l * 64 + ww)) * 6 * 128;
        float s = 0.f;
        #pragma unroll
        for (int n = 0; n < 6; ++n) s += src[n * 128 + t];
        amean[(size_t)hw * 128 + t] = s * (1.0f / 6.0f);
    }
}

// ---------- depthwise 3x3 + gelu + SE partials ----------
__global__ void k_dwconv(const float* __restrict__ ex, const float* __restrict__ dwgt,
                         float* __restrict__ dwout, float* __restrict__ separt) {
    const int TILE = 16;
    int ch = threadIdx.x;
    int hw0 = blockIdx.x * TILE;
    float wreg[9];
    #pragma unroll
    for (int i = 0; i < 9; ++i) wreg[i] = dwgt[ch * 9 + i];
    float sacc = 0.f;
    for (int ti = 0; ti < TILE; ++ti) {
        int hw = hw0 + ti;
        int h = hw >> 6, w = hw & 63;
        float s = 0.f;
        #pragma unroll
        for (int dy = -1; dy <= 1; ++dy) {
            int h2 = h + dy;
            if (h2 < 0 || h2 >= 64) continue;
            #pragma unroll
            for (int dx = -1; dx <= 1; ++dx) {
                int w2 = w + dx;
                if (w2 < 0 || w2 >= 64) continue;
                s += ex[((size_t)(h2 * 64 + w2)) * 512 + ch] * wreg[(dy + 1) * 3 + (dx + 1)];
            }
        }
        float o = gelu_f(s * BN_S);
        dwout[(size_t)hw * 512 + ch] = o;
        sacc += o;
    }
    separt[(size_t)blockIdx.x * 512 + ch] = sacc;
}

// ---------- SE ----------
__global__ void k_se(const float* __restrict__ separt, int nparts,
                     const float* __restrict__ s1w, const float* __restrict__ s1b,
                     const float* __restrict__ s2w, const float* __restrict__ s2b,
                     float* __restrict__ se) {
    __shared__ float mean[512];
    __shared__ float s1[32];
    int tid = threadIdx.x;
    float s = 0.f;
    for (int b = 0; b < nparts; ++b) s += separt[(size_t)b * 512 + tid];
    mean[tid] = s * (1.0f / 4096.0f);
    __syncthreads();
    if (tid < 32) {
        float acc = s1b[tid];
        const float* wr = s1w + (size_t)tid * 512;
        for (int c = 0; c < 512; ++c) acc += mean[c] * wr[c];
        s1[tid] = gelu_f(acc);
    }
    __syncthreads();
    float acc = s2b[tid];
    const float* wr = s2w + (size_t)tid * 32;
    #pragma unroll
    for (int j = 0; j < 32; ++j) acc += s1[j] * wr[j];
    se[tid] = 1.0f / (1.0f + __expf(-acc));
}

extern "C" void kernel_launch(void* const* d_in, const int* in_sizes, int n_in,
                              void* d_out, int out_size, void* d_ws, size_t ws_size,
                              hipStream_t stream) {
    (void)in_sizes; (void)n_in; (void)out_size; (void)ws_size;
    const float* x      = (const float*)d_in[1];
    const float* feat   = (const float*)d_in[2];
    const float* I_inv  = (const float*)d_in[3];
    const float* E_inv  = (const float*)d_in[4];
    const float* bev    = (const float*)d_in[5];
    const float* fl_w   = (const float*)d_in[6];
    const float* fp_w   = (const float*)d_in[7];
    const float* be_w   = (const float*)d_in[8];
    const float* be_b   = (const float*)d_in[9];
    const float* ie_w   = (const float*)d_in[10];
    const float* ce_w   = (const float*)d_in[11];
    const float* a1_qw  = (const float*)d_in[12];
    const float* a1_qb  = (const float*)d_in[13];
    const float* a1_kw  = (const float*)d_in[14];
    const float* a1_kb  = (const float*)d_in[15];
    const float* a1_vw  = (const float*)d_in[16];
    const float* a1_vb  = (const float*)d_in[17];
    const float* a1_pw  = (const float*)d_in[18];
    const float* a1_pb  = (const float*)d_in[19];
    const float* a2_qw  = (const float*)d_in[20];
    const float* a2_qb  = (const float*)d_in[21];
    const float* a2_kw  = (const float*)d_in[22];
    const float* a2_kb  = (const float*)d_in[23];
    const float* a2_vw  = (const float*)d_in[24];
    const float* a2_vb  = (const float*)d_in[25];
    const float* a2_pw  = (const float*)d_in[26];
    const float* a2_pb  = (const float*)d_in[27];
    const float* m1_w1  = (const float*)d_in[28];
    const float* m1_b1  = (const float*)d_in[29];
    const float* m1_w2  = (const float*)d_in[30];
    const float* m1_b2  = (const float*)d_in[31];
    const float* m2_w1  = (const float*)d_in[32];
    const float* m2_b1  = (const float*)d_in[33];
    const float* m2_w2  = (const float*)d_in[34];
    const float* m2_b2  = (const float*)d_in[35];
    const float* mb_ew  = (const float*)d_in[36];
    const float* mb_dw  = (const float*)d_in[37];
    const float* mb_s1w = (const float*)d_in[38];
    const float* mb_s1b = (const float*)d_in[39];
    const float* mb_s2w = (const float*)d_in[40];
    const float* mb_s2b = (const float*)d_in[41];
    const float* mb_pw  = (const float*)d_in[42];
    const float* pm_w1  = (const float*)d_in[43];
    const float* pm_b1  = (const float*)d_in[44];
    const float* pm_w2  = (const float*)d_in[45];
    const float* pm_b2  = (const float*)d_in[46];
    const float* po_w   = (const float*)d_in[47];
    const float* po_b   = (const float*)d_in[48];

    float* ws = (float*)d_ws;
    float* S0 = ws + 0;         // 3145728 : query -> abuf -> expandb
    float* S1 = ws + 3145728;   // 3145728 : qh1 -> qh2 -> dwout+separt+sebuf
    float* S2 = ws + 6291456;   // 2359296 : f_cl -> kh1
    float* S3 = ws + 8650752;   // 2359296 : kinit -> vh1
    float* S4 = ws + 11010048;  // 2359296 : key -> kh2 (in-place)
    float* S5 = ws + 13369344;  // 2359296 : val -> vh2 (in-place)
    float* amean  = ws + 15728640;  // 524288
    float* qimg   = ws + 16252928;  // 524288
    float* gbuf   = ws + 16777216;  // 1048576
    float* qimg2  = ws + 17825792;  // 524288
    float* zln    = ws + 18350080;  // 524288
    float* abuf2  = ws + 18874368;  // 524288
    float* mbout  = ws + 19398656;  // 524288

    float* f_cl  = S2;
    float* kinit = S3;
    float* key   = S4;
    float* val   = S5;
    float* query = S0;
    float* qh1   = S1;
    float* kh1   = S2;
    float* vh1   = S3;
    float* kh2   = S4;
    float* vh2   = S5;
    float* abuf  = S0;
    float* qh2   = S1;
    float* expandb = S0;
    float* dwout   = S1;
    float* separt  = S1 + 2097152;
    float* sebuf   = S1 + 2097152 + 131072;

    // stage 0: layout transforms + embeddings
    k_trans<<<dim3(96, 4, 6), 256, 0, stream>>>(feat, f_cl);
    k_embed<<<dim3(192, 6), 128, 0, stream>>>(I_inv, E_inv, ie_w, ce_w, kinit);
    k_query<<<dim3(256, 6), 128, 0, stream>>>(x, bev, be_w, be_b, E_inv, ce_w, query);
    // key/val dual GEMM: key = f.fp + kinit ; val = f.fl
    k_gemm<128,128,128,32,2, 0,0,0,0, 1,0,0, 1,0><<<576, 256, 0, stream>>>(
        f_cl, fp_w, nullptr, kinit, nullptr, fl_w, nullptr, val, nullptr, key);

    // stage 1: q/k/v heads (k,v produce BOTH attn1 and attn2 heads from one LN+stage)
    k_gemm<128,128,128,32,2, 1,1,0,0, 0,0,0, 0,0><<<768, 256, 0, stream>>>(
        query, a1_qw, a1_qb, nullptr, nullptr, nullptr, nullptr, nullptr, nullptr, qh1);
    k_gemm<128,128,128,32,2, 1,1,0,0, 0,0,0, 1,0><<<576, 256, 0, stream>>>(
        key, a1_kw, a1_kb, nullptr, nullptr, a2_kw, a2_kb, kh2, nullptr, kh1);
    k_gemm<128,128,128,32,2, 1,1,0,0, 0,0,0, 1,0><<<576, 256, 0, stream>>>(
        val, a1_vw, a1_vb, nullptr, nullptr, a2_vw, a2_vb, vh2, nullptr, vh1);
    k_attn1<<<dim3(64, HEADS), 768, 0, stream>>>(qh1, kh1, vh1, abuf);
    k_mean<<<512, 128, 0, stream>>>(abuf, amean);
    k_gemm<128,128,128,16,1, 0,1,0,0, 2,0,0, 0,0><<<256, 256, 0, stream>>>(
        amean, a1_pw, a1_pb, x, nullptr, nullptr, nullptr, nullptr, nullptr, qimg);
    k_gemm<128,256,256,16,2, 1,1,1,0, 0,0,0, 0,0><<<256, 256, 0, stream>>>(
        qimg, m1_w1, m1_b1, nullptr, nullptr, nullptr, nullptr, nullptr, nullptr, gbuf);
    k_gemm<256,128,128,16,1, 0,1,0,0, 1,0,0, 0,0><<<256, 256, 0, stream>>>(
        gbuf, m1_w2, m1_b2, qimg, nullptr, nullptr, nullptr, nullptr, nullptr, qimg);

    // stage 2: attn2 + MLP2
    k_gemm<128,128,128,16,1, 1,1,0,0, 0,0,0, 0,0><<<256, 256, 0, stream>>>(
        qimg, a2_qw, a2_qb, nullptr, nullptr, nullptr, nullptr, nullptr, nullptr, qh2);
    k_attn2<<<dim3(64, HEADS), 512, 0, stream>>>(qh2, kh2, vh2, abuf2);
    k_gemm<128,128,128,16,1, 0,1,0,0, 1,0,0, 0,0><<<256, 256, 0, stream>>>(
        abuf2, a2_pw, a2_pb, qimg, nullptr, nullptr, nullptr, nullptr, nullptr, qimg2);
    k_gemm<128,256,256,16,2, 1,1,1,0, 0,0,0, 0,0><<<256, 256, 0, stream>>>(
        qimg2, m2_w1, m2_b1, nullptr, nullptr, nullptr, nullptr, nullptr, nullptr, gbuf);
    k_gemm<256,128,128,16,1, 0,1,0,0, 1,0,0, 0,0><<<256, 256, 0, stream>>>(
        gbuf, m2_w2, m2_b2, qimg2, nullptr, nullptr, nullptr, nullptr, nullptr, qimg2);

    // stage 3: postnorm(LN fused into expand) + MBConv + FFN + proj_out
    k_gemm<128,128,512,32,2, 1,0,1,1, 0,0,0, 0,1><<<dim3(128, 4), 256, 0, stream>>>(
        qimg2, mb_ew, nullptr, nullptr, nullptr, nullptr, nullptr, nullptr, zln, expandb);
    k_dwconv<<<256, 512, 0, stream>>>(expandb, mb_dw, dwout, separt);
    k_se<<<1, 512, 0, stream>>>(separt, 256, mb_s1w, mb_s1b, mb_s2w, mb_s2b, sebuf);
    k_gemm<512,128,128,16,1, 0,0,0,1, 1,0,1, 0,0><<<256, 256, 0, stream>>>(
        dwout, mb_pw, nullptr, zln, sebuf, nullptr, nullptr, nullptr, nullptr, mbout);
    k_gemm<128,256,256,16,2, 0,1,1,0, 0,0,0, 0,0><<<256, 256, 0, stream>>>(
        mbout, pm_w1, pm_b1, nullptr, nullptr, nullptr, nullptr, nullptr, nullptr, gbuf);
    k_gemm<256,128,128,16,1, 0,1,0,0, 1,0,0, 0,0><<<256, 256, 0, stream>>>(
        gbuf, pm_w2, pm_b2, mbout, nullptr, nullptr, nullptr, nullptr, nullptr, mbout);
    k_gemm<128,128,128,16,1, 0,1,1,0, 0,1,0, 0,0><<<256, 256, 0, stream>>>(
        mbout, po_w, po_b, nullptr, nullptr, nullptr, nullptr, nullptr, nullptr, (float*)d_out);
}

// Round 5
// 488.003 us; speedup vs baseline: 4.4138x; 1.1944x over previous
//
#include <hip/hip_runtime.h>
#include <math.h>

#define NV 6
#define FHH 32
#define FWW 96
#define PIMG (FHH*FWW)   // 3072
#define HH 64
#define WWD 64
#define PBEV (HH*WWD)    // 4096
#define HEADS 4
#define DHD 32
#define KROWS 288
#define BN_S 0.9999950000374996f
#define LN_EPS 1e-5f
#define ATT_SCALE 0.17677669529663687f  // 32^-0.5

typedef __attribute__((ext_vector_type(8))) short short8;
typedef __attribute__((ext_vector_type(4))) float f32x4;
typedef __attribute__((ext_vector_type(8))) unsigned short u16x8;

__device__ __forceinline__ float gelu_f(float x) {
    return 0.5f * x * (1.0f + erff(x * 0.70710678118654752f));
}

__device__ __forceinline__ unsigned short f2bf(float f) {
    union { float f; unsigned int u; } c; c.f = f;
    unsigned int r = (c.u + 0x7fffu + ((c.u >> 16) & 1u)) >> 16;
    return (unsigned short)r;
}

__device__ __forceinline__ float blockSum128(float v, float* red, int tid) {
    #pragma unroll
    for (int o = 32; o > 0; o >>= 1) v += __shfl_down(v, o, 64);
    __syncthreads();
    if ((tid & 63) == 0) red[tid >> 6] = v;
    __syncthreads();
    return red[0] + red[1];
}

// ---------- feature transpose + BN*relu : [n][128][3072] -> [n*3072][128] ----------
__global__ void k_trans(const float* __restrict__ feature, float* __restrict__ f_cl) {
    __shared__ float tile[32][33];
    int n = blockIdx.z, c0 = blockIdx.y * 32, p0 = blockIdx.x * 32;
    int tp = threadIdx.x & 31, tg = threadIdx.x >> 5;
    #pragma unroll
    for (int i = 0; i < 4; ++i) {
        int c = tg + 8 * i;
        tile[c][tp] = feature[((size_t)(n * 128 + c0 + c)) * PIMG + p0 + tp];
    }
    __syncthreads();
    int cw = threadIdx.x & 31, pg = threadIdx.x >> 5;
    #pragma unroll
    for (int i = 0; i < 4; ++i) {
        int p = pg + 8 * i;
        float v = fmaxf(tile[cw][p] * BN_S, 0.0f);
        f_cl[((size_t)(n * PIMG + p0 + p)) * 128 + c0 + cw] = v;
    }
}

// ---------- geometric image embedding -> kinit [n*3072][128] ----------
__global__ void k_embed(const float* __restrict__ I_inv, const float* __restrict__ E_inv,
                        const float* __restrict__ ie_w, const float* __restrict__ ce_w,
                        float* __restrict__ kinit) {
    const int TILE = 16;
    int n = blockIdx.y, p0 = blockIdx.x * TILE, t = threadIdx.x;
    __shared__ float red[2];
    const float* E  = E_inv + n * 16;
    const float* Ii = I_inv + n * 9;
    float cemb = E[3]  * ce_w[t*4+0] + E[7]  * ce_w[t*4+1]
               + E[11] * ce_w[t*4+2] + E[15] * ce_w[t*4+3];
    for (int pos = 0; pos < TILE; ++pos) {
        int p = p0 + pos;
        int h = p / FWW, w = p % FWW;
        float gx = (float)w * (768.0f / 95.0f);
        float gy = (float)h * (256.0f / 31.0f);
        float c0 = Ii[0]*gx + Ii[1]*gy + Ii[2];
        float c1 = Ii[3]*gx + Ii[4]*gy + Ii[5];
        float c2 = Ii[6]*gx + Ii[7]*gy + Ii[8];
        float d0 = E[0]*c0  + E[1]*c1  + E[2]*c2  + E[3];
        float d1 = E[4]*c0  + E[5]*c1  + E[6]*c2  + E[7];
        float d2 = E[8]*c0  + E[9]*c1  + E[10]*c2 + E[11];
        float d3 = E[12]*c0 + E[13]*c1 + E[14]*c2 + E[15];
        float emb = d0*ie_w[t*4+0] + d1*ie_w[t*4+1]
                  + d2*ie_w[t*4+2] + d3*ie_w[t*4+3] - cemb;
        float ss = blockSum128(emb * emb, red, t);
        kinit[((size_t)(n * PIMG + p)) * 128 + t] = emb / (sqrtf(ss) + 1e-7f);
    }
}

// ---------- query [n*4096][128] ----------
__global__ void k_query(const float* __restrict__ x, const float* __restrict__ bev,
                        const float* __restrict__ be_w, const float* __restrict__ be_b,
                        const float* __restrict__ E_inv, const float* __restrict__ ce_w,
                        float* __restrict__ query) {
    const int TILE = 16;
    int n = blockIdx.y, p0 = blockIdx.x * TILE, t = threadIdx.x;
    __shared__ float red[2];
    const float* E = E_inv + n * 16;
    float cemb = E[3]  * ce_w[t*4+0] + E[7]  * ce_w[t*4+1]
               + E[11] * ce_w[t*4+2] + E[15] * ce_w[t*4+3];
    float bw0 = be_w[t*2+0], bw1 = be_w[t*2+1], bb = be_b[t];
    for (int pos = 0; pos < TILE; ++pos) {
        int p = p0 + pos;
        float emb = bev[p]*bw0 + bev[PBEV + p]*bw1 + bb - cemb;
        float ss = blockSum128(emb * emb, red, t);
        float qv = emb / (sqrtf(ss) + 1e-7f) + x[(size_t)t * PBEV + p];
        query[((size_t)(n * PBEV + p)) * 128 + t] = qv;
    }
}

// ---------- generic tiled f32 GEMM (256 threads) ----------
template<int NI, int NO, int NOT, int BR, int MR, int LNF, int BIASF, int ACT,
         int SCL, int ADDM, int STM, int ASCL, int DUAL, int WRLN, int OUTBF>
__global__ __launch_bounds__(256)
void k_gemm(const float* __restrict__ A, const float* __restrict__ W,
            const float* __restrict__ bias, const float* __restrict__ addb,
            const float* __restrict__ ascale, const float* __restrict__ W2,
            const float* __restrict__ bias2, void* __restrict__ out2v,
            float* __restrict__ aux, void* __restrict__ outv) {
    constexpr int CG = NO / 8;
    constexpr int RG = 256 / CG;
    static_assert(RG * MR == BR, "tile mismatch");
    __shared__ float a_lds[BR][NI + 4];
    __shared__ float w_lds[32][NO + 4];
    const int t  = threadIdx.x;
    const int rb = blockIdx.x * BR;
    const int co = blockIdx.y * NO;

    constexpr int AF4 = (BR * NI / 4) / 256;
    #pragma unroll
    for (int i = 0; i < AF4; ++i) {
        int f4 = i * 256 + t;
        int row = f4 / (NI / 4), q = f4 % (NI / 4);
        float4 v = *(const float4*)&A[(size_t)(rb + row) * NI + 4 * q];
        if constexpr (ASCL) {
            float4 sc = *(const float4*)&ascale[4 * q];
            v.x *= sc.x; v.y *= sc.y; v.z *= sc.z; v.w *= sc.w;
        }
        *(float4*)&a_lds[row][4 * q] = v;
    }
    __syncthreads();

    if constexpr (LNF) {
        constexpr int TPR = 256 / BR;
        constexpr int CPT = NI / TPR;
        int row = t / TPR, seg = t % TPR, base = seg * CPT;
        float sum = 0.f;
        #pragma unroll
        for (int j = 0; j < CPT / 4; ++j) {
            float4 v = *(float4*)&a_lds[row][base + 4 * j];
            sum += (v.x + v.y) + (v.z + v.w);
        }
        #pragma unroll
        for (int o = 1; o < TPR; o <<= 1) sum += __shfl_xor(sum, o, 64);
        float mu = sum * (1.0f / NI);
        float ss = 0.f;
        #pragma unroll
        for (int j = 0; j < CPT / 4; ++j) {
            float4 v = *(float4*)&a_lds[row][base + 4 * j];
            float a = v.x - mu, b = v.y - mu, c = v.z - mu, d = v.w - mu;
            ss += (a * a + b * b) + (c * c + d * d);
        }
        #pragma unroll
        for (int o = 1; o < TPR; o <<= 1) ss += __shfl_xor(ss, o, 64);
        float rs = rsqrtf(ss * (1.0f / NI) + LN_EPS);
        #pragma unroll
        for (int j = 0; j < CPT / 4; ++j) {
            float4 v = *(float4*)&a_lds[row][base + 4 * j];
            v.x = (v.x - mu) * rs; v.y = (v.y - mu) * rs;
            v.z = (v.z - mu) * rs; v.w = (v.w - mu) * rs;
            *(float4*)&a_lds[row][base + 4 * j] = v;
            if constexpr (WRLN) {
                if (blockIdx.y == 0)
                    *(float4*)&aux[(size_t)(rb + row) * NI + base + 4 * j] = v;
            }
        }
        __syncthreads();
    }

    const int cg = t % CG, rg = t / CG;
    const int c0 = cg * 8, r0 = rg * MR;
    constexpr int NCH = NI / 32;
    constexpr int WF4 = NO / 32;

    #pragma unroll 1
    for (int set = 0; set <= DUAL; ++set) {
        const float* Wc = set ? W2 : W;
        const float* bc = set ? bias2 : bias;
        void* ocv = set ? out2v : outv;
        float acc[MR][8];
        #pragma unroll
        for (int i = 0; i < MR; ++i)
            #pragma unroll
            for (int j = 0; j < 8; ++j) acc[i][j] = 0.f;

        #pragma unroll 1
        for (int ch = 0; ch < NCH; ++ch) {
            int k0 = ch * 32;
            if (ch || set) __syncthreads();
            #pragma unroll
            for (int i = 0; i < WF4; ++i) {
                int f4 = i * 256 + t;
                int c = f4 >> 3, kq = f4 & 7;
                float4 v = *(const float4*)&Wc[(size_t)(co + c) * NI + k0 + 4 * kq];
                w_lds[4 * kq + 0][c] = v.x; w_lds[4 * kq + 1][c] = v.y;
                w_lds[4 * kq + 2][c] = v.z; w_lds[4 * kq + 3][c] = v.w;
            }
            __syncthreads();
            #pragma unroll
            for (int kk = 0; kk < 32; ++kk) {
                float4 w0 = *(float4*)&w_lds[kk][c0];
                float4 w1 = *(float4*)&w_lds[kk][c0 + 4];
                #pragma unroll
                for (int i = 0; i < MR; ++i) {
                    float a = a_lds[r0 + i][k0 + kk];
                    acc[i][0] += a * w0.x; acc[i][1] += a * w0.y;
                    acc[i][2] += a * w0.z; acc[i][3] += a * w0.w;
                    acc[i][4] += a * w1.x; acc[i][5] += a * w1.y;
                    acc[i][6] += a * w1.z; acc[i][7] += a * w1.w;
                }
            }
        }

        float bi[8];
        if constexpr (BIASF) {
            #pragma unroll
            for (int j = 0; j < 8; ++j) bi[j] = bc[co + c0 + j];
        }
        #pragma unroll
        for (int i = 0; i < MR; ++i)
            #pragma unroll
            for (int j = 0; j < 8; ++j) {
                float v = acc[i][j];
                if constexpr (BIASF) v += bi[j];
                if constexpr (SCL)   v *= BN_S;
                if constexpr (ACT)   v = gelu_f(v);
                acc[i][j] = v;
            }
        if constexpr (ADDM == 1) {
            if (set == 0) {
                #pragma unroll
                for (int i = 0; i < MR; ++i) {
                    float4 a0 = *(const float4*)&addb[(size_t)(rb + r0 + i) * NOT + co + c0];
                    float4 a1 = *(const float4*)&addb[(size_t)(rb + r0 + i) * NOT + co + c0 + 4];
                    acc[i][0] += a0.x; acc[i][1] += a0.y; acc[i][2] += a0.z; acc[i][3] += a0.w;
                    acc[i][4] += a1.x; acc[i][5] += a1.y; acc[i][6] += a1.z; acc[i][7] += a1.w;
                }
            }
        }
        if constexpr (ADDM == 2) {
            if (set == 0) {
                #pragma unroll
                for (int j = 0; j < 8; ++j)
                    #pragma unroll
                    for (int i = 0; i < MR; ++i)
                        acc[i][j] += addb[(size_t)(co + c0 + j) * PBEV + rb + r0 + i];
            }
        }
        if constexpr (STM == 0) {
            if constexpr (OUTBF) {
                unsigned short* ob = (unsigned short*)ocv;
                #pragma unroll
                for (int i = 0; i < MR; ++i) {
                    u16x8 o;
                    #pragma unroll
                    for (int j = 0; j < 8; ++j) o[j] = f2bf(acc[i][j]);
                    *(u16x8*)&ob[(size_t)(rb + r0 + i) * NOT + co + c0] = o;
                }
            } else {
                float* oc = (float*)ocv;
                #pragma unroll
                for (int i = 0; i < MR; ++i) {
                    float4 o0 = {acc[i][0], acc[i][1], acc[i][2], acc[i][3]};
                    float4 o1 = {acc[i][4], acc[i][5], acc[i][6], acc[i][7]};
                    *(float4*)&oc[(size_t)(rb + r0 + i) * NOT + co + c0]     = o0;
                    *(float4*)&oc[(size_t)(rb + r0 + i) * NOT + co + c0 + 4] = o1;
                }
            }
        } else {
            float* oc = (float*)ocv;
            #pragma unroll
            for (int j = 0; j < 8; ++j)
                #pragma unroll
                for (int i = 0; i < MR; ++i)
                    oc[(size_t)(co + c0 + j) * PBEV + rb + r0 + i] = acc[i][j];
        }
    }
}

// ---------- MFMA flash attention (bf16 inputs, f32 softmax/acc) ----------
// MODE 1: Q=384 (6 views), 8 waves x 3 q-tiles. MODE 2: Q=64, 4 waves x 1 q-tile.
template<int MODE>
__global__ __launch_bounds__(MODE == 1 ? 512 : 256)
void k_attn_mfma(const unsigned short* __restrict__ qh, const unsigned short* __restrict__ kh,
                 const unsigned short* __restrict__ vh, float* __restrict__ aout) {
    constexpr int WAVES = (MODE == 1) ? 8 : 4;
    constexpr int QTPW  = (MODE == 1) ? 3 : 1;
    constexpr int T = WAVES * 64;
    const int l = blockIdx.x, m = blockIdx.y;
    const int xw = l >> 3, yw = l & 7;
    const int t = threadIdx.x;
    const int lane = t & 63, wv = t >> 6;
    const int la = lane & 15, g = lane >> 4;

    __shared__ unsigned short Kl[KROWS * 40];          // [288][40] pad
    __shared__ unsigned short Vt[32 * 312];            // [32][312] pad (V transposed)
    __shared__ unsigned short Pl[WAVES * QTPW * 640];  // per-wave [QTPW][16][40]

    // stage K rows + transposed V (4 threads per key row, 8 d each)
    for (int i = t; i < KROWS * 4; i += T) {
        int row = i >> 2, seg = i & 3;
        int n = row / 48, kk = row % 48;
        int k1 = kk / 12, k2 = kk % 12;
        int h, w;
        if (MODE == 1) { h = xw * 4 + k1;  w = yw * 12 + k2; }
        else           { h = k1 * 8 + xw;  w = k2 * 8 + yw;  }
        size_t src = ((size_t)(n * PIMG + h * FWW + w)) * 128 + m * DHD + seg * 8;
        short8 kv = *(const short8*)&kh[src];
        *(short8*)&Kl[row * 40 + seg * 8] = kv;
        short8 vv = *(const short8*)&vh[src];
        #pragma unroll
        for (int j = 0; j < 8; ++j)
            Vt[(seg * 8 + j) * 312 + row] = (unsigned short)vv[j];
    }

    // Q fragments (A layout: row = la, k-offset = g*8)
    short8 qf[QTPW];
    #pragma unroll
    for (int qt = 0; qt < QTPW; ++qt) {
        int q = (wv * QTPW + qt) * 16 + la;
        int row;
        if (MODE == 1) {
            int n = q >> 6, ww = q & 63;
            row = n * PBEV + (xw * 8 + (ww >> 3)) * 64 + yw * 8 + (ww & 7);
        } else {
            row = ((q >> 3) * 8 + xw) * 64 + (q & 7) * 8 + yw;
        }
        qf[qt] = *(const short8*)&qh[(size_t)row * 128 + m * DHD + g * 8];
    }
    __syncthreads();

    f32x4 acc[QTPW][2];
    float mrow[QTPW][4], srow[QTPW][4];
    #pragma unroll
    for (int qt = 0; qt < QTPW; ++qt) {
        acc[qt][0] = (f32x4){0.f, 0.f, 0.f, 0.f};
        acc[qt][1] = (f32x4){0.f, 0.f, 0.f, 0.f};
        #pragma unroll
        for (int r = 0; r < 4; ++r) { mrow[qt][r] = -1e30f; srow[qt][r] = 0.f; }
    }
    unsigned short* Pw = Pl + wv * QTPW * 640;

    #pragma unroll 1
    for (int c = 0; c < 9; ++c) {
        const int kk0 = c * 32;
        short8 kf0 = *(short8*)&Kl[(kk0 + la) * 40 + g * 8];
        short8 kf1 = *(short8*)&Kl[(kk0 + 16 + la) * 40 + g * 8];
        f32x4 S[QTPW][2];
        #pragma unroll
        for (int qt = 0; qt < QTPW; ++qt) {
            S[qt][0] = __builtin_amdgcn_mfma_f32_16x16x32_bf16(qf[qt], kf0, (f32x4){0.f,0.f,0.f,0.f}, 0, 0, 0);
            S[qt][1] = __builtin_amdgcn_mfma_f32_16x16x32_bf16(qf[qt], kf1, (f32x4){0.f,0.f,0.f,0.f}, 0, 0, 0);
        }
        // online softmax per row (C layout: row = g*4+r, col = la)
        #pragma unroll
        for (int qt = 0; qt < QTPW; ++qt) {
            #pragma unroll
            for (int r = 0; r < 4; ++r) {
                float a = S[qt][0][r] * ATT_SCALE;
                float b = S[qt][1][r] * ATT_SCALE;
                float mx = fmaxf(a, b);
                mx = fmaxf(mx, __shfl_xor(mx, 1));
                mx = fmaxf(mx, __shfl_xor(mx, 2));
                mx = fmaxf(mx, __shfl_xor(mx, 4));
                mx = fmaxf(mx, __shfl_xor(mx, 8));
                float M = fmaxf(mrow[qt][r], mx);
                float f = __expf(mrow[qt][r] - M);
                mrow[qt][r] = M;
                float pa = __expf(a - M), pb = __expf(b - M);
                float rs = pa + pb;
                rs += __shfl_xor(rs, 1);
                rs += __shfl_xor(rs, 2);
                rs += __shfl_xor(rs, 4);
                rs += __shfl_xor(rs, 8);
                srow[qt][r] = srow[qt][r] * f + rs;
                acc[qt][0][r] *= f;
                acc[qt][1][r] *= f;
                int prow = g * 4 + r;
                Pw[qt * 640 + prow * 40 + la]      = f2bf(pa);
                Pw[qt * 640 + prow * 40 + 16 + la] = f2bf(pb);
            }
        }
        asm volatile("s_waitcnt lgkmcnt(0)" ::: "memory");
        // PV: A = P (re-read in A layout), B = Vt
        short8 vf0 = *(short8*)&Vt[la * 312 + kk0 + g * 8];
        short8 vf1 = *(short8*)&Vt[(16 + la) * 312 + kk0 + g * 8];
        #pragma unroll
        for (int qt = 0; qt < QTPW; ++qt) {
            short8 pf = *(short8*)&Pw[qt * 640 + la * 40 + g * 8];
            acc[qt][0] = __builtin_amdgcn_mfma_f32_16x16x32_bf16(pf, vf0, acc[qt][0], 0, 0, 0);
            acc[qt][1] = __builtin_amdgcn_mfma_f32_16x16x32_bf16(pf, vf1, acc[qt][1], 0, 0, 0);
        }
    }

    // write out: row q = g*4+r, col d = dt*16+la
    #pragma unroll
    for (int qt = 0; qt < QTPW; ++qt) {
        #pragma unroll
        for (int r = 0; r < 4; ++r) {
            float inv = 1.0f / srow[qt][r];
            int q = (wv * QTPW + qt) * 16 + g * 4 + r;
            size_t orow;
            if (MODE == 1) {
                int n = q >> 6, ww = q & 63;
                orow = (size_t)(l * 64 + ww) * 6 + n;
            } else {
                orow = (size_t)(((q >> 3) * 8 + xw) * 64 + (q & 7) * 8 + yw);
            }
            float* ap = aout + orow * 128 + m * DHD;
            ap[la]      = acc[qt][0][r] * inv;
            ap[16 + la] = acc[qt][1][r] * inv;
        }
    }
}

// ---------- mean over 6 views + window->hw permute ----------
__global__ void k_mean(const float* __restrict__ abuf, float* __restrict__ amean) {
    int t = threadIdx.x;
    for (int rr = 0; rr < 8; ++rr) {
        int hw = blockIdx.x * 8 + rr;
        int h = hw >> 6, w = hw & 63;
        int xw = h >> 3, w1 = h & 7, yw = w >> 3, w2 = w & 7;
        int l = xw * 8 + yw, ww = w1 * 8 + w2;
        const float* src = abuf + ((size_t)(l * 64 + ww)) * 6 * 128;
        float s = 0.f;
        #pragma unroll
        for (int n = 0; n < 6; ++n) s += src[n * 128 + t];
        amean[(size_t)hw * 128 + t] = s * (1.0f / 6.0f);
    }
}

// ---------- depthwise 3x3 + gelu + SE partials ----------
__global__ void k_dwconv(const float* __restrict__ ex, const float* __restrict__ dwgt,
                         float* __restrict__ dwout, float* __restrict__ separt) {
    const int TILE = 16;
    int ch = threadIdx.x;
    int hw0 = blockIdx.x * TILE;
    float wreg[9];
    #pragma unroll
    for (int i = 0; i < 9; ++i) wreg[i] = dwgt[ch * 9 + i];
    float sacc = 0.f;
    for (int ti = 0; ti < TILE; ++ti) {
        int hw = hw0 + ti;
        int h = hw >> 6, w = hw & 63;
        float s = 0.f;
        #pragma unroll
        for (int dy = -1; dy <= 1; ++dy) {
            int h2 = h + dy;
            if (h2 < 0 || h2 >= 64) continue;
            #pragma unroll
            for (int dx = -1; dx <= 1; ++dx) {
                int w2 = w + dx;
                if (w2 < 0 || w2 >= 64) continue;
                s += ex[((size_t)(h2 * 64 + w2)) * 512 + ch] * wreg[(dy + 1) * 3 + (dx + 1)];
            }
        }
        float o = gelu_f(s * BN_S);
        dwout[(size_t)hw * 512 + ch] = o;
        sacc += o;
    }
    separt[(size_t)blockIdx.x * 512 + ch] = sacc;
}

// ---------- SE ----------
__global__ void k_se(const float* __restrict__ separt, int nparts,
                     const float* __restrict__ s1w, const float* __restrict__ s1b,
                     const float* __restrict__ s2w, const float* __restrict__ s2b,
                     float* __restrict__ se) {
    __shared__ float mean[512];
    __shared__ float s1[32];
    int tid = threadIdx.x;
    float s = 0.f;
    for (int b = 0; b < nparts; ++b) s += separt[(size_t)b * 512 + tid];
    mean[tid] = s * (1.0f / 4096.0f);
    __syncthreads();
    if (tid < 32) {
        float acc = s1b[tid];
        const float* wr = s1w + (size_t)tid * 512;
        for (int c = 0; c < 512; ++c) acc += mean[c] * wr[c];
        s1[tid] = gelu_f(acc);
    }
    __syncthreads();
    float acc = s2b[tid];
    const float* wr = s2w + (size_t)tid * 32;
    #pragma unroll
    for (int j = 0; j < 32; ++j) acc += s1[j] * wr[j];
    se[tid] = 1.0f / (1.0f + __expf(-acc));
}

extern "C" void kernel_launch(void* const* d_in, const int* in_sizes, int n_in,
                              void* d_out, int out_size, void* d_ws, size_t ws_size,
                              hipStream_t stream) {
    (void)in_sizes; (void)n_in; (void)out_size; (void)ws_size;
    const float* x      = (const float*)d_in[1];
    const float* feat   = (const float*)d_in[2];
    const float* I_inv  = (const float*)d_in[3];
    const float* E_inv  = (const float*)d_in[4];
    const float* bev    = (const float*)d_in[5];
    const float* fl_w   = (const float*)d_in[6];
    const float* fp_w   = (const float*)d_in[7];
    const float* be_w   = (const float*)d_in[8];
    const float* be_b   = (const float*)d_in[9];
    const float* ie_w   = (const float*)d_in[10];
    const float* ce_w   = (const float*)d_in[11];
    const float* a1_qw  = (const float*)d_in[12];
    const float* a1_qb  = (const float*)d_in[13];
    const float* a1_kw  = (const float*)d_in[14];
    const float* a1_kb  = (const float*)d_in[15];
    const float* a1_vw  = (const float*)d_in[16];
    const float* a1_vb  = (const float*)d_in[17];
    const float* a1_pw  = (const float*)d_in[18];
    const float* a1_pb  = (const float*)d_in[19];
    const float* a2_qw  = (const float*)d_in[20];
    const float* a2_qb  = (const float*)d_in[21];
    const float* a2_kw  = (const float*)d_in[22];
    const float* a2_kb  = (const float*)d_in[23];
    const float* a2_vw  = (const float*)d_in[24];
    const float* a2_vb  = (const float*)d_in[25];
    const float* a2_pw  = (const float*)d_in[26];
    const float* a2_pb  = (const float*)d_in[27];
    const float* m1_w1  = (const float*)d_in[28];
    const float* m1_b1  = (const float*)d_in[29];
    const float* m1_w2  = (const float*)d_in[30];
    const float* m1_b2  = (const float*)d_in[31];
    const float* m2_w1  = (const float*)d_in[32];
    const float* m2_b1  = (const float*)d_in[33];
    const float* m2_w2  = (const float*)d_in[34];
    const float* m2_b2  = (const float*)d_in[35];
    const float* mb_ew  = (const float*)d_in[36];
    const float* mb_dw  = (const float*)d_in[37];
    const float* mb_s1w = (const float*)d_in[38];
    const float* mb_s1b = (const float*)d_in[39];
    const float* mb_s2w = (const float*)d_in[40];
    const float* mb_s2b = (const float*)d_in[41];
    const float* mb_pw  = (const float*)d_in[42];
    const float* pm_w1  = (const float*)d_in[43];
    const float* pm_b1  = (const float*)d_in[44];
    const float* pm_w2  = (const float*)d_in[45];
    const float* pm_b2  = (const float*)d_in[46];
    const float* po_w   = (const float*)d_in[47];
    const float* po_b   = (const float*)d_in[48];

    float* ws = (float*)d_ws;
    float* S0 = ws + 0;         // 3145728 : query -> abuf -> expandb
    float* S1 = ws + 3145728;   // 3145728 : qh1b -> qh2b -> dwout+separt+sebuf
    float* S2 = ws + 6291456;   // 2359296 : f_cl -> kh1b
    float* S3 = ws + 8650752;   // 2359296 : kinit -> vh1b
    float* S4 = ws + 11010048;  // 2359296 : key -> kh2b (in-place)
    float* S5 = ws + 13369344;  // 2359296 : val -> vh2b (in-place)
    float* amean  = ws + 15728640;  // 524288
    float* qimg   = ws + 16252928;  // 524288
    float* gbuf   = ws + 16777216;  // 1048576
    float* qimg2  = ws + 17825792;  // 524288
    float* zln    = ws + 18350080;  // 524288
    float* abuf2  = ws + 18874368;  // 524288
    float* mbout  = ws + 19398656;  // 524288

    float* f_cl  = S2;
    float* kinit = S3;
    float* key   = S4;
    float* val   = S5;
    float* query = S0;
    unsigned short* qh1b = (unsigned short*)S1;
    unsigned short* kh1b = (unsigned short*)S2;
    unsigned short* vh1b = (unsigned short*)S3;
    unsigned short* kh2b = (unsigned short*)S4;
    unsigned short* vh2b = (unsigned short*)S5;
    float* abuf  = S0;
    unsigned short* qh2b = (unsigned short*)S1;
    float* expandb = S0;
    float* dwout   = S1;
    float* separt  = S1 + 2097152;
    float* sebuf   = S1 + 2097152 + 131072;

    // stage 0: layout transforms + embeddings
    k_trans<<<dim3(96, 4, 6), 256, 0, stream>>>(feat, f_cl);
    k_embed<<<dim3(192, 6), 128, 0, stream>>>(I_inv, E_inv, ie_w, ce_w, kinit);
    k_query<<<dim3(256, 6), 128, 0, stream>>>(x, bev, be_w, be_b, E_inv, ce_w, query);
    // key/val dual GEMM: key = f.fp + kinit ; val = f.fl (f32 out)
    k_gemm<128,128,128,32,2, 0,0,0,0, 1,0,0, 1,0,0><<<576, 256, 0, stream>>>(
        f_cl, fp_w, nullptr, kinit, nullptr, fl_w, nullptr, val, nullptr, key);

    // stage 1: q/k/v heads -> bf16 (dual k/v GEMMs produce attn1 + attn2 heads)
    k_gemm<128,128,128,32,2, 1,1,0,0, 0,0,0, 0,0,1><<<768, 256, 0, stream>>>(
        query, a1_qw, a1_qb, nullptr, nullptr, nullptr, nullptr, nullptr, nullptr, qh1b);
    k_gemm<128,128,128,32,2, 1,1,0,0, 0,0,0, 1,0,1><<<576, 256, 0, stream>>>(
        key, a1_kw, a1_kb, nullptr, nullptr, a2_kw, a2_kb, kh2b, nullptr, kh1b);
    k_gemm<128,128,128,32,2, 1,1,0,0, 0,0,0, 1,0,1><<<576, 256, 0, stream>>>(
        val, a1_vw, a1_vb, nullptr, nullptr, a2_vw, a2_vb, vh2b, nullptr, vh1b);
    k_attn_mfma<1><<<dim3(64, HEADS), 512, 0, stream>>>(qh1b, kh1b, vh1b, abuf);
    k_mean<<<512, 128, 0, stream>>>(abuf, amean);
    k_gemm<128,128,128,16,1, 0,1,0,0, 2,0,0, 0,0,0><<<256, 256, 0, stream>>>(
        amean, a1_pw, a1_pb, x, nullptr, nullptr, nullptr, nullptr, nullptr, qimg);
    k_gemm<128,256,256,16,2, 1,1,1,0, 0,0,0, 0,0,0><<<256, 256, 0, stream>>>(
        qimg, m1_w1, m1_b1, nullptr, nullptr, nullptr, nullptr, nullptr, nullptr, gbuf);
    k_gemm<256,128,128,16,1, 0,1,0,0, 1,0,0, 0,0,0><<<256, 256, 0, stream>>>(
        gbuf, m1_w2, m1_b2, qimg, nullptr, nullptr, nullptr, nullptr, nullptr, qimg);

    // stage 2: attn2 + MLP2
    k_gemm<128,128,128,16,1, 1,1,0,0, 0,0,0, 0,0,1><<<256, 256, 0, stream>>>(
        qimg, a2_qw, a2_qb, nullptr, nullptr, nullptr, nullptr, nullptr, nullptr, qh2b);
    k_attn_mfma<2><<<dim3(64, HEADS), 256, 0, stream>>>(qh2b, kh2b, vh2b, abuf2);
    k_gemm<128,128,128,16,1, 0,1,0,0, 1,0,0, 0,0,0><<<256, 256, 0, stream>>>(
        abuf2, a2_pw, a2_pb, qimg, nullptr, nullptr, nullptr, nullptr, nullptr, qimg2);
    k_gemm<128,256,256,16,2, 1,1,1,0, 0,0,0, 0,0,0><<<256, 256, 0, stream>>>(
        qimg2, m2_w1, m2_b1, nullptr, nullptr, nullptr, nullptr, nullptr, nullptr, gbuf);
    k_gemm<256,128,128,16,1, 0,1,0,0, 1,0,0, 0,0,0><<<256, 256, 0, stream>>>(
        gbuf, m2_w2, m2_b2, qimg2, nullptr, nullptr, nullptr, nullptr, nullptr, qimg2);

    // stage 3: postnorm(LN fused into expand) + MBConv + FFN + proj_out
    k_gemm<128,128,512,32,2, 1,0,1,1, 0,0,0, 0,1,0><<<dim3(128, 4), 256, 0, stream>>>(
        qimg2, mb_ew, nullptr, nullptr, nullptr, nullptr, nullptr, nullptr, zln, expandb);
    k_dwconv<<<256, 512, 0, stream>>>(expandb, mb_dw, dwout, separt);
    k_se<<<1, 512, 0, stream>>>(separt, 256, mb_s1w, mb_s1b, mb_s2w, mb_s2b, sebuf);
    k_gemm<512,128,128,16,1, 0,0,0,1, 1,0,1, 0,0,0><<<256, 256, 0, stream>>>(
        dwout, mb_pw, nullptr, zln, sebuf, nullptr, nullptr, nullptr, nullptr, mbout);
    k_gemm<128,256,256,16,2, 0,1,1,0, 0,0,0, 0,0,0><<<256, 256, 0, stream>>>(
        mbout, pm_w1, pm_b1, nullptr, nullptr, nullptr, nullptr, nullptr, nullptr, gbuf);
    k_gemm<256,128,128,16,1, 0,1,0,0, 1,0,0, 0,0,0><<<256, 256, 0, stream>>>(
        gbuf, pm_w2, pm_b2, mbout, nullptr, nullptr, nullptr, nullptr, nullptr, mbout);
    k_gemm<128,128,128,16,1, 0,1,1,0, 0,1,0, 0,0,0><<<256, 256, 0, stream>>>(
        mbout, po_w, po_b, nullptr, nullptr, nullptr, nullptr, nullptr, nullptr, (float*)d_out);
}

// Round 6
// 340.006 us; speedup vs baseline: 6.3350x; 1.4353x over previous
//
#include <hip/hip_runtime.h>
#include <math.h>

#define NV 6
#define FHH 32
#define FWW 96
#define PIMG (FHH*FWW)   // 3072
#define HH 64
#define WWD 64
#define PBEV (HH*WWD)    // 4096
#define HEADS 4
#define DHD 32
#define KROWS 288
#define BN_S 0.9999950000374996f
#define LN_EPS 1e-5f
#define ATT_SCALE 0.17677669529663687f  // 32^-0.5

typedef __attribute__((ext_vector_type(8))) short short8;
typedef __attribute__((ext_vector_type(4))) float f32x4;
typedef __attribute__((ext_vector_type(8))) unsigned short u16x8;

__device__ __forceinline__ float gelu_f(float x) {
    return 0.5f * x * (1.0f + erff(x * 0.70710678118654752f));
}

__device__ __forceinline__ unsigned short f2bf(float f) {
    union { float f; unsigned int u; } c; c.f = f;
    unsigned int r = (c.u + 0x7fffu + ((c.u >> 16) & 1u)) >> 16;
    return (unsigned short)r;
}

__device__ __forceinline__ float blockSum128(float v, float* red, int tid) {
    #pragma unroll
    for (int o = 32; o > 0; o >>= 1) v += __shfl_down(v, o, 64);
    __syncthreads();
    if ((tid & 63) == 0) red[tid >> 6] = v;
    __syncthreads();
    return red[0] + red[1];
}

// ---------- feature transpose + BN*relu : [n][128][3072] -> [n*3072][128] ----------
__global__ void k_trans(const float* __restrict__ feature, float* __restrict__ f_cl) {
    __shared__ float tile[32][33];
    int n = blockIdx.z, c0 = blockIdx.y * 32, p0 = blockIdx.x * 32;
    int tp = threadIdx.x & 31, tg = threadIdx.x >> 5;
    #pragma unroll
    for (int i = 0; i < 4; ++i) {
        int c = tg + 8 * i;
        tile[c][tp] = feature[((size_t)(n * 128 + c0 + c)) * PIMG + p0 + tp];
    }
    __syncthreads();
    int cw = threadIdx.x & 31, pg = threadIdx.x >> 5;
    #pragma unroll
    for (int i = 0; i < 4; ++i) {
        int p = pg + 8 * i;
        float v = fmaxf(tile[cw][p] * BN_S, 0.0f);
        f_cl[((size_t)(n * PIMG + p0 + p)) * 128 + c0 + cw] = v;
    }
}

// ---------- geometric image embedding -> kinit [n*3072][128] ----------
__global__ void k_embed(const float* __restrict__ I_inv, const float* __restrict__ E_inv,
                        const float* __restrict__ ie_w, const float* __restrict__ ce_w,
                        float* __restrict__ kinit) {
    const int TILE = 16;
    int n = blockIdx.y, p0 = blockIdx.x * TILE, t = threadIdx.x;
    __shared__ float red[2];
    const float* E  = E_inv + n * 16;
    const float* Ii = I_inv + n * 9;
    float cemb = E[3]  * ce_w[t*4+0] + E[7]  * ce_w[t*4+1]
               + E[11] * ce_w[t*4+2] + E[15] * ce_w[t*4+3];
    for (int pos = 0; pos < TILE; ++pos) {
        int p = p0 + pos;
        int h = p / FWW, w = p % FWW;
        float gx = (float)w * (768.0f / 95.0f);
        float gy = (float)h * (256.0f / 31.0f);
        float c0 = Ii[0]*gx + Ii[1]*gy + Ii[2];
        float c1 = Ii[3]*gx + Ii[4]*gy + Ii[5];
        float c2 = Ii[6]*gx + Ii[7]*gy + Ii[8];
        float d0 = E[0]*c0  + E[1]*c1  + E[2]*c2  + E[3];
        float d1 = E[4]*c0  + E[5]*c1  + E[6]*c2  + E[7];
        float d2 = E[8]*c0  + E[9]*c1  + E[10]*c2 + E[11];
        float d3 = E[12]*c0 + E[13]*c1 + E[14]*c2 + E[15];
        float emb = d0*ie_w[t*4+0] + d1*ie_w[t*4+1]
                  + d2*ie_w[t*4+2] + d3*ie_w[t*4+3] - cemb;
        float ss = blockSum128(emb * emb, red, t);
        kinit[((size_t)(n * PIMG + p)) * 128 + t] = emb / (sqrtf(ss) + 1e-7f);
    }
}

// ---------- query [n*4096][128] ----------
__global__ void k_query(const float* __restrict__ x, const float* __restrict__ bev,
                        const float* __restrict__ be_w, const float* __restrict__ be_b,
                        const float* __restrict__ E_inv, const float* __restrict__ ce_w,
                        float* __restrict__ query) {
    const int TILE = 16;
    int n = blockIdx.y, p0 = blockIdx.x * TILE, t = threadIdx.x;
    __shared__ float red[2];
    const float* E = E_inv + n * 16;
    float cemb = E[3]  * ce_w[t*4+0] + E[7]  * ce_w[t*4+1]
               + E[11] * ce_w[t*4+2] + E[15] * ce_w[t*4+3];
    float bw0 = be_w[t*2+0], bw1 = be_w[t*2+1], bb = be_b[t];
    for (int pos = 0; pos < TILE; ++pos) {
        int p = p0 + pos;
        float emb = bev[p]*bw0 + bev[PBEV + p]*bw1 + bb - cemb;
        float ss = blockSum128(emb * emb, red, t);
        float qv = emb / (sqrtf(ss) + 1e-7f) + x[(size_t)t * PBEV + p];
        query[((size_t)(n * PBEV + p)) * 128 + t] = qv;
    }
}

// ---------- MFMA 128x128 GEMM, 64 rows/block, optional LN/bias/add/dual, bf16 or f32 out ----------
template<int LNF, int BIASF, int ADDM, int DUAL, int OUTBF>
__global__ __launch_bounds__(256)
void k_gemm_mfma(const float* __restrict__ A, const float* __restrict__ W,
                 const float* __restrict__ bias, const float* __restrict__ addb,
                 const float* __restrict__ W2, const float* __restrict__ bias2,
                 void* __restrict__ out2v, void* __restrict__ outv) {
    __shared__ unsigned short Al[64 * 136];
    __shared__ unsigned short Wl[128 * 136];
    const int t = threadIdx.x;
    const int rb = blockIdx.x * 64;
    const int lane = t & 63, wv = t >> 6;
    const int la = lane & 15, g = lane >> 4;

    // stage A (optionally LN) as bf16; thread t -> (row t>>2, 32-col seg t&3)
    {
        int r = t >> 2, seg = t & 3;
        const float* ar = A + (size_t)(rb + r) * 128 + seg * 32;
        float v[32];
        #pragma unroll
        for (int j = 0; j < 8; ++j)
            *(float4*)&v[4 * j] = *(const float4*)&ar[4 * j];
        if constexpr (LNF) {
            float s = 0.f;
            #pragma unroll
            for (int j = 0; j < 32; ++j) s += v[j];
            s += __shfl_xor(s, 1); s += __shfl_xor(s, 2);
            float mu = s * (1.0f / 128.0f);
            float ss = 0.f;
            #pragma unroll
            for (int j = 0; j < 32; ++j) { float d = v[j] - mu; ss += d * d; }
            ss += __shfl_xor(ss, 1); ss += __shfl_xor(ss, 2);
            float rs = rsqrtf(ss * (1.0f / 128.0f) + LN_EPS);
            #pragma unroll
            for (int j = 0; j < 32; ++j) v[j] = (v[j] - mu) * rs;
        }
        #pragma unroll
        for (int j8 = 0; j8 < 4; ++j8) {
            u16x8 o;
            #pragma unroll
            for (int j = 0; j < 8; ++j) o[j] = f2bf(v[8 * j8 + j]);
            *(u16x8*)&Al[r * 136 + seg * 32 + 8 * j8] = o;
        }
    }

    #pragma unroll 1
    for (int set = 0; set <= DUAL; ++set) {
        const float* Wc = set ? W2 : W;
        const float* bc = set ? bias2 : bias;
        void* ocv = set ? out2v : outv;
        if (set) __syncthreads();
        // stage W as bf16 ([c][k], pad 136)
        #pragma unroll
        for (int i = 0; i < 8; ++i) {
            int chunk = i * 256 + t;
            int c = chunk >> 4, k8 = chunk & 15;
            float4 v0 = *(const float4*)&Wc[(size_t)c * 128 + k8 * 8];
            float4 v1 = *(const float4*)&Wc[(size_t)c * 128 + k8 * 8 + 4];
            u16x8 o = { f2bf(v0.x), f2bf(v0.y), f2bf(v0.z), f2bf(v0.w),
                        f2bf(v1.x), f2bf(v1.y), f2bf(v1.z), f2bf(v1.w) };
            *(u16x8*)&Wl[c * 136 + k8 * 8] = o;
        }
        __syncthreads();

        short8 af[4];
        #pragma unroll
        for (int ks = 0; ks < 4; ++ks)
            af[ks] = *(short8*)&Al[(wv * 16 + la) * 136 + ks * 32 + g * 8];

        #pragma unroll
        for (int ct = 0; ct < 8; ++ct) {
            f32x4 acc = (f32x4){0.f, 0.f, 0.f, 0.f};
            #pragma unroll
            for (int ks = 0; ks < 4; ++ks) {
                short8 bf = *(short8*)&Wl[(ct * 16 + la) * 136 + ks * 32 + g * 8];
                acc = __builtin_amdgcn_mfma_f32_16x16x32_bf16(af[ks], bf, acc, 0, 0, 0);
            }
            int col = ct * 16 + la;
            float bv = 0.f;
            if constexpr (BIASF) bv = bc[col];
            #pragma unroll
            for (int r = 0; r < 4; ++r) {
                int row = rb + wv * 16 + g * 4 + r;
                float v = acc[r] + bv;
                if constexpr (ADDM) { if (set == 0) v += addb[(size_t)row * 128 + col]; }
                if constexpr (OUTBF) ((unsigned short*)ocv)[(size_t)row * 128 + col] = f2bf(v);
                else                 ((float*)ocv)[(size_t)row * 128 + col] = v;
            }
        }
    }
}

// ---------- generic tiled f32 GEMM (256 threads) ----------
template<int NI, int NO, int NOT, int BR, int MR, int LNF, int BIASF, int ACT,
         int SCL, int ADDM, int STM, int ASCL, int DUAL, int WRLN, int OUTBF>
__global__ __launch_bounds__(256)
void k_gemm(const float* __restrict__ A, const float* __restrict__ W,
            const float* __restrict__ bias, const float* __restrict__ addb,
            const float* __restrict__ ascale, const float* __restrict__ W2,
            const float* __restrict__ bias2, void* __restrict__ out2v,
            float* __restrict__ aux, void* __restrict__ outv) {
    constexpr int CG = NO / 8;
    constexpr int RG = 256 / CG;
    static_assert(RG * MR == BR, "tile mismatch");
    __shared__ float a_lds[BR][NI + 4];
    __shared__ float w_lds[32][NO + 4];
    const int t  = threadIdx.x;
    const int rb = blockIdx.x * BR;
    const int co = blockIdx.y * NO;

    constexpr int AF4 = (BR * NI / 4) / 256;
    #pragma unroll
    for (int i = 0; i < AF4; ++i) {
        int f4 = i * 256 + t;
        int row = f4 / (NI / 4), q = f4 % (NI / 4);
        float4 v = *(const float4*)&A[(size_t)(rb + row) * NI + 4 * q];
        if constexpr (ASCL) {
            float4 sc = *(const float4*)&ascale[4 * q];
            v.x *= sc.x; v.y *= sc.y; v.z *= sc.z; v.w *= sc.w;
        }
        *(float4*)&a_lds[row][4 * q] = v;
    }
    __syncthreads();

    if constexpr (LNF) {
        constexpr int TPR = 256 / BR;
        constexpr int CPT = NI / TPR;
        int row = t / TPR, seg = t % TPR, base = seg * CPT;
        float sum = 0.f;
        #pragma unroll
        for (int j = 0; j < CPT / 4; ++j) {
            float4 v = *(float4*)&a_lds[row][base + 4 * j];
            sum += (v.x + v.y) + (v.z + v.w);
        }
        #pragma unroll
        for (int o = 1; o < TPR; o <<= 1) sum += __shfl_xor(sum, o, 64);
        float mu = sum * (1.0f / NI);
        float ss = 0.f;
        #pragma unroll
        for (int j = 0; j < CPT / 4; ++j) {
            float4 v = *(float4*)&a_lds[row][base + 4 * j];
            float a = v.x - mu, b = v.y - mu, c = v.z - mu, d = v.w - mu;
            ss += (a * a + b * b) + (c * c + d * d);
        }
        #pragma unroll
        for (int o = 1; o < TPR; o <<= 1) ss += __shfl_xor(ss, o, 64);
        float rs = rsqrtf(ss * (1.0f / NI) + LN_EPS);
        #pragma unroll
        for (int j = 0; j < CPT / 4; ++j) {
            float4 v = *(float4*)&a_lds[row][base + 4 * j];
            v.x = (v.x - mu) * rs; v.y = (v.y - mu) * rs;
            v.z = (v.z - mu) * rs; v.w = (v.w - mu) * rs;
            *(float4*)&a_lds[row][base + 4 * j] = v;
            if constexpr (WRLN) {
                if (blockIdx.y == 0)
                    *(float4*)&aux[(size_t)(rb + row) * NI + base + 4 * j] = v;
            }
        }
        __syncthreads();
    }

    const int cg = t % CG, rg = t / CG;
    const int c0 = cg * 8, r0 = rg * MR;
    constexpr int NCH = NI / 32;
    constexpr int WF4 = NO / 32;

    #pragma unroll 1
    for (int set = 0; set <= DUAL; ++set) {
        const float* Wc = set ? W2 : W;
        const float* bc = set ? bias2 : bias;
        void* ocv = set ? out2v : outv;
        float acc[MR][8];
        #pragma unroll
        for (int i = 0; i < MR; ++i)
            #pragma unroll
            for (int j = 0; j < 8; ++j) acc[i][j] = 0.f;

        #pragma unroll 1
        for (int ch = 0; ch < NCH; ++ch) {
            int k0 = ch * 32;
            if (ch || set) __syncthreads();
            #pragma unroll
            for (int i = 0; i < WF4; ++i) {
                int f4 = i * 256 + t;
                int c = f4 >> 3, kq = f4 & 7;
                float4 v = *(const float4*)&Wc[(size_t)(co + c) * NI + k0 + 4 * kq];
                w_lds[4 * kq + 0][c] = v.x; w_lds[4 * kq + 1][c] = v.y;
                w_lds[4 * kq + 2][c] = v.z; w_lds[4 * kq + 3][c] = v.w;
            }
            __syncthreads();
            #pragma unroll
            for (int kk = 0; kk < 32; ++kk) {
                float4 w0 = *(float4*)&w_lds[kk][c0];
                float4 w1 = *(float4*)&w_lds[kk][c0 + 4];
                #pragma unroll
                for (int i = 0; i < MR; ++i) {
                    float a = a_lds[r0 + i][k0 + kk];
                    acc[i][0] += a * w0.x; acc[i][1] += a * w0.y;
                    acc[i][2] += a * w0.z; acc[i][3] += a * w0.w;
                    acc[i][4] += a * w1.x; acc[i][5] += a * w1.y;
                    acc[i][6] += a * w1.z; acc[i][7] += a * w1.w;
                }
            }
        }

        float bi[8];
        if constexpr (BIASF) {
            #pragma unroll
            for (int j = 0; j < 8; ++j) bi[j] = bc[co + c0 + j];
        }
        #pragma unroll
        for (int i = 0; i < MR; ++i)
            #pragma unroll
            for (int j = 0; j < 8; ++j) {
                float v = acc[i][j];
                if constexpr (BIASF) v += bi[j];
                if constexpr (SCL)   v *= BN_S;
                if constexpr (ACT)   v = gelu_f(v);
                acc[i][j] = v;
            }
        if constexpr (ADDM == 1) {
            if (set == 0) {
                #pragma unroll
                for (int i = 0; i < MR; ++i) {
                    float4 a0 = *(const float4*)&addb[(size_t)(rb + r0 + i) * NOT + co + c0];
                    float4 a1 = *(const float4*)&addb[(size_t)(rb + r0 + i) * NOT + co + c0 + 4];
                    acc[i][0] += a0.x; acc[i][1] += a0.y; acc[i][2] += a0.z; acc[i][3] += a0.w;
                    acc[i][4] += a1.x; acc[i][5] += a1.y; acc[i][6] += a1.z; acc[i][7] += a1.w;
                }
            }
        }
        if constexpr (ADDM == 2) {
            if (set == 0) {
                #pragma unroll
                for (int j = 0; j < 8; ++j)
                    #pragma unroll
                    for (int i = 0; i < MR; ++i)
                        acc[i][j] += addb[(size_t)(co + c0 + j) * PBEV + rb + r0 + i];
            }
        }
        if constexpr (STM == 0) {
            if constexpr (OUTBF) {
                unsigned short* ob = (unsigned short*)ocv;
                #pragma unroll
                for (int i = 0; i < MR; ++i) {
                    u16x8 o;
                    #pragma unroll
                    for (int j = 0; j < 8; ++j) o[j] = f2bf(acc[i][j]);
                    *(u16x8*)&ob[(size_t)(rb + r0 + i) * NOT + co + c0] = o;
                }
            } else {
                float* oc = (float*)ocv;
                #pragma unroll
                for (int i = 0; i < MR; ++i) {
                    float4 o0 = {acc[i][0], acc[i][1], acc[i][2], acc[i][3]};
                    float4 o1 = {acc[i][4], acc[i][5], acc[i][6], acc[i][7]};
                    *(float4*)&oc[(size_t)(rb + r0 + i) * NOT + co + c0]     = o0;
                    *(float4*)&oc[(size_t)(rb + r0 + i) * NOT + co + c0 + 4] = o1;
                }
            }
        } else {
            float* oc = (float*)ocv;
            #pragma unroll
            for (int j = 0; j < 8; ++j)
                #pragma unroll
                for (int i = 0; i < MR; ++i)
                    oc[(size_t)(co + c0 + j) * PBEV + rb + r0 + i] = acc[i][j];
        }
    }
}

// ---------- MFMA flash attention (bf16 inputs, f32 softmax/acc) ----------
template<int MODE>
__global__ __launch_bounds__(MODE == 1 ? 512 : 256)
void k_attn_mfma(const unsigned short* __restrict__ qh, const unsigned short* __restrict__ kh,
                 const unsigned short* __restrict__ vh, float* __restrict__ aout) {
    constexpr int WAVES = (MODE == 1) ? 8 : 4;
    constexpr int QTPW  = (MODE == 1) ? 3 : 1;
    constexpr int T = WAVES * 64;
    const int l = blockIdx.x, m = blockIdx.y;
    const int xw = l >> 3, yw = l & 7;
    const int t = threadIdx.x;
    const int lane = t & 63, wv = t >> 6;
    const int la = lane & 15, g = lane >> 4;

    __shared__ unsigned short Kl[KROWS * 40];
    __shared__ unsigned short Vt[32 * 312];
    __shared__ unsigned short Pl[WAVES * QTPW * 640];

    for (int i = t; i < KROWS * 4; i += T) {
        int row = i >> 2, seg = i & 3;
        int n = row / 48, kk = row % 48;
        int k1 = kk / 12, k2 = kk % 12;
        int h, w;
        if (MODE == 1) { h = xw * 4 + k1;  w = yw * 12 + k2; }
        else           { h = k1 * 8 + xw;  w = k2 * 8 + yw;  }
        size_t src = ((size_t)(n * PIMG + h * FWW + w)) * 128 + m * DHD + seg * 8;
        short8 kv = *(const short8*)&kh[src];
        *(short8*)&Kl[row * 40 + seg * 8] = kv;
        short8 vv = *(const short8*)&vh[src];
        #pragma unroll
        for (int j = 0; j < 8; ++j)
            Vt[(seg * 8 + j) * 312 + row] = (unsigned short)vv[j];
    }

    short8 qf[QTPW];
    #pragma unroll
    for (int qt = 0; qt < QTPW; ++qt) {
        int q = (wv * QTPW + qt) * 16 + la;
        int row;
        if (MODE == 1) {
            int n = q >> 6, ww = q & 63;
            row = n * PBEV + (xw * 8 + (ww >> 3)) * 64 + yw * 8 + (ww & 7);
        } else {
            row = ((q >> 3) * 8 + xw) * 64 + (q & 7) * 8 + yw;
        }
        qf[qt] = *(const short8*)&qh[(size_t)row * 128 + m * DHD + g * 8];
    }
    __syncthreads();

    f32x4 acc[QTPW][2];
    float mrow[QTPW][4], srow[QTPW][4];
    #pragma unroll
    for (int qt = 0; qt < QTPW; ++qt) {
        acc[qt][0] = (f32x4){0.f, 0.f, 0.f, 0.f};
        acc[qt][1] = (f32x4){0.f, 0.f, 0.f, 0.f};
        #pragma unroll
        for (int r = 0; r < 4; ++r) { mrow[qt][r] = -1e30f; srow[qt][r] = 0.f; }
    }
    unsigned short* Pw = Pl + wv * QTPW * 640;

    #pragma unroll 1
    for (int c = 0; c < 9; ++c) {
        const int kk0 = c * 32;
        short8 kf0 = *(short8*)&Kl[(kk0 + la) * 40 + g * 8];
        short8 kf1 = *(short8*)&Kl[(kk0 + 16 + la) * 40 + g * 8];
        f32x4 S[QTPW][2];
        #pragma unroll
        for (int qt = 0; qt < QTPW; ++qt) {
            S[qt][0] = __builtin_amdgcn_mfma_f32_16x16x32_bf16(qf[qt], kf0, (f32x4){0.f,0.f,0.f,0.f}, 0, 0, 0);
            S[qt][1] = __builtin_amdgcn_mfma_f32_16x16x32_bf16(qf[qt], kf1, (f32x4){0.f,0.f,0.f,0.f}, 0, 0, 0);
        }
        #pragma unroll
        for (int qt = 0; qt < QTPW; ++qt) {
            #pragma unroll
            for (int r = 0; r < 4; ++r) {
                float a = S[qt][0][r] * ATT_SCALE;
                float b = S[qt][1][r] * ATT_SCALE;
                float mx = fmaxf(a, b);
                mx = fmaxf(mx, __shfl_xor(mx, 1));
                mx = fmaxf(mx, __shfl_xor(mx, 2));
                mx = fmaxf(mx, __shfl_xor(mx, 4));
                mx = fmaxf(mx, __shfl_xor(mx, 8));
                float M = fmaxf(mrow[qt][r], mx);
                float f = __expf(mrow[qt][r] - M);
                mrow[qt][r] = M;
                float pa = __expf(a - M), pb = __expf(b - M);
                float rs = pa + pb;
                rs += __shfl_xor(rs, 1);
                rs += __shfl_xor(rs, 2);
                rs += __shfl_xor(rs, 4);
                rs += __shfl_xor(rs, 8);
                srow[qt][r] = srow[qt][r] * f + rs;
                acc[qt][0][r] *= f;
                acc[qt][1][r] *= f;
                int prow = g * 4 + r;
                Pw[qt * 640 + prow * 40 + la]      = f2bf(pa);
                Pw[qt * 640 + prow * 40 + 16 + la] = f2bf(pb);
            }
        }
        asm volatile("s_waitcnt lgkmcnt(0)" ::: "memory");
        short8 vf0 = *(short8*)&Vt[la * 312 + kk0 + g * 8];
        short8 vf1 = *(short8*)&Vt[(16 + la) * 312 + kk0 + g * 8];
        #pragma unroll
        for (int qt = 0; qt < QTPW; ++qt) {
            short8 pf = *(short8*)&Pw[qt * 640 + la * 40 + g * 8];
            acc[qt][0] = __builtin_amdgcn_mfma_f32_16x16x32_bf16(pf, vf0, acc[qt][0], 0, 0, 0);
            acc[qt][1] = __builtin_amdgcn_mfma_f32_16x16x32_bf16(pf, vf1, acc[qt][1], 0, 0, 0);
        }
    }

    #pragma unroll
    for (int qt = 0; qt < QTPW; ++qt) {
        #pragma unroll
        for (int r = 0; r < 4; ++r) {
            float inv = 1.0f / srow[qt][r];
            int q = (wv * QTPW + qt) * 16 + g * 4 + r;
            size_t orow;
            if (MODE == 1) {
                int n = q >> 6, ww = q & 63;
                orow = (size_t)(l * 64 + ww) * 6 + n;
            } else {
                orow = (size_t)(((q >> 3) * 8 + xw) * 64 + (q & 7) * 8 + yw);
            }
            float* ap = aout + orow * 128 + m * DHD;
            ap[la]      = acc[qt][0][r] * inv;
            ap[16 + la] = acc[qt][1][r] * inv;
        }
    }
}

// ---------- mean over 6 views + window->hw permute ----------
__global__ void k_mean(const float* __restrict__ abuf, float* __restrict__ amean) {
    int t = threadIdx.x;
    for (int rr = 0; rr < 8; ++rr) {
        int hw = blockIdx.x * 8 + rr;
        int h = hw >> 6, w = hw & 63;
        int xw = h >> 3, w1 = h & 7, yw = w >> 3, w2 = w & 7;
        int l = xw * 8 + yw, ww = w1 * 8 + w2;
        const float* src = abuf + ((size_t)(l * 64 + ww)) * 6 * 128;
        float s = 0.f;
        #pragma unroll
        for (int n = 0; n < 6; ++n) s += src[n * 128 + t];
        amean[(size_t)hw * 128 + t] = s * (1.0f / 6.0f);
    }
}

// ---------- depthwise 3x3 + gelu + SE partials ----------
__global__ void k_dwconv(const float* __restrict__ ex, const float* __restrict__ dwgt,
                         float* __restrict__ dwout, float* __restrict__ separt) {
    const int TILE = 16;
    int ch = threadIdx.x;
    int hw0 = blockIdx.x * TILE;
    float wreg[9];
    #pragma unroll
    for (int i = 0; i < 9; ++i) wreg[i] = dwgt[ch * 9 + i];
    float sacc = 0.f;
    for (int ti = 0; ti < TILE; ++ti) {
        int hw = hw0 + ti;
        int h = hw >> 6, w = hw & 63;
        float s = 0.f;
        #pragma unroll
        for (int dy = -1; dy <= 1; ++dy) {
            int h2 = h + dy;
            if (h2 < 0 || h2 >= 64) continue;
            #pragma unroll
            for (int dx = -1; dx <= 1; ++dx) {
                int w2 = w + dx;
                if (w2 < 0 || w2 >= 64) continue;
                s += ex[((size_t)(h2 * 64 + w2)) * 512 + ch] * wreg[(dy + 1) * 3 + (dx + 1)];
            }
        }
        float o = gelu_f(s * BN_S);
        dwout[(size_t)hw * 512 + ch] = o;
        sacc += o;
    }
    separt[(size_t)blockIdx.x * 512 + ch] = sacc;
}

// ---------- SE reduce stage 1: [256][512] -> [16][512] ----------
__global__ void k_sered(const float* __restrict__ separt, float* __restrict__ separt2) {
    int t = threadIdx.x, bb = blockIdx.x;
    float s = 0.f;
    #pragma unroll
    for (int i = 0; i < 16; ++i)
        s += separt[(size_t)(bb * 16 + i) * 512 + t];
    separt2[(size_t)bb * 512 + t] = s;
}

// ---------- SE final: reduce + 2 matvecs (parallelized) ----------
__global__ void k_se(const float* __restrict__ separt2,
                     const float* __restrict__ s1w, const float* __restrict__ s1b,
                     const float* __restrict__ s2w, const float* __restrict__ s2b,
                     float* __restrict__ se) {
    __shared__ float mean[512];
    __shared__ float s1[32];
    int t = threadIdx.x;
    float s = 0.f;
    #pragma unroll
    for (int b = 0; b < 16; ++b) s += separt2[b * 512 + t];
    mean[t] = s * (1.0f / 4096.0f);
    __syncthreads();
    int u = t >> 4, seg = t & 15;
    float acc = 0.f;
    #pragma unroll
    for (int j = 0; j < 32; ++j) {
        int c = seg + 16 * j;
        acc += mean[c] * s1w[u * 512 + c];
    }
    acc += __shfl_xor(acc, 1); acc += __shfl_xor(acc, 2);
    acc += __shfl_xor(acc, 4); acc += __shfl_xor(acc, 8);
    if (seg == 0) s1[u] = gelu_f(acc + s1b[u]);
    __syncthreads();
    float a2 = s2b[t];
    #pragma unroll
    for (int j = 0; j < 32; ++j) a2 += s1[j] * s2w[t * 32 + j];
    se[t] = 1.0f / (1.0f + __expf(-a2));
}

extern "C" void kernel_launch(void* const* d_in, const int* in_sizes, int n_in,
                              void* d_out, int out_size, void* d_ws, size_t ws_size,
                              hipStream_t stream) {
    (void)in_sizes; (void)n_in; (void)out_size; (void)ws_size;
    const float* x      = (const float*)d_in[1];
    const float* feat   = (const float*)d_in[2];
    const float* I_inv  = (const float*)d_in[3];
    const float* E_inv  = (const float*)d_in[4];
    const float* bev    = (const float*)d_in[5];
    const float* fl_w   = (const float*)d_in[6];
    const float* fp_w   = (const float*)d_in[7];
    const float* be_w   = (const float*)d_in[8];
    const float* be_b   = (const float*)d_in[9];
    const float* ie_w   = (const float*)d_in[10];
    const float* ce_w   = (const float*)d_in[11];
    const float* a1_qw  = (const float*)d_in[12];
    const float* a1_qb  = (const float*)d_in[13];
    const float* a1_kw  = (const float*)d_in[14];
    const float* a1_kb  = (const float*)d_in[15];
    const float* a1_vw  = (const float*)d_in[16];
    const float* a1_vb  = (const float*)d_in[17];
    const float* a1_pw  = (const float*)d_in[18];
    const float* a1_pb  = (const float*)d_in[19];
    const float* a2_qw  = (const float*)d_in[20];
    const float* a2_qb  = (const float*)d_in[21];
    const float* a2_kw  = (const float*)d_in[22];
    const float* a2_kb  = (const float*)d_in[23];
    const float* a2_vw  = (const float*)d_in[24];
    const float* a2_vb  = (const float*)d_in[25];
    const float* a2_pw  = (const float*)d_in[26];
    const float* a2_pb  = (const float*)d_in[27];
    const float* m1_w1  = (const float*)d_in[28];
    const float* m1_b1  = (const float*)d_in[29];
    const float* m1_w2  = (const float*)d_in[30];
    const float* m1_b2  = (const float*)d_in[31];
    const float* m2_w1  = (const float*)d_in[32];
    const float* m2_b1  = (const float*)d_in[33];
    const float* m2_w2  = (const float*)d_in[34];
    const float* m2_b2  = (const float*)d_in[35];
    const float* mb_ew  = (const float*)d_in[36];
    const float* mb_dw  = (const float*)d_in[37];
    const float* mb_s1w = (const float*)d_in[38];
    const float* mb_s1b = (const float*)d_in[39];
    const float* mb_s2w = (const float*)d_in[40];
    const float* mb_s2b = (const float*)d_in[41];
    const float* mb_pw  = (const float*)d_in[42];
    const float* pm_w1  = (const float*)d_in[43];
    const float* pm_b1  = (const float*)d_in[44];
    const float* pm_w2  = (const float*)d_in[45];
    const float* pm_b2  = (const float*)d_in[46];
    const float* po_w   = (const float*)d_in[47];
    const float* po_b   = (const float*)d_in[48];

    float* ws = (float*)d_ws;
    float* S0 = ws + 0;         // 3145728 : query -> abuf -> expandb
    float* S1 = ws + 3145728;   // 3145728 : qh1b -> qh2b -> dwout+separt+separt2+sebuf
    float* S2 = ws + 6291456;   // 2359296 : f_cl -> kh1b
    float* S3 = ws + 8650752;   // 2359296 : kinit -> vh1b
    float* S4 = ws + 11010048;  // 2359296 : key -> kh2b (in-place)
    float* S5 = ws + 13369344;  // 2359296 : val -> vh2b (in-place)
    float* amean  = ws + 15728640;  // 524288
    float* qimg   = ws + 16252928;  // 524288
    float* gbuf   = ws + 16777216;  // 1048576
    float* qimg2  = ws + 17825792;  // 524288
    float* zln    = ws + 18350080;  // 524288
    float* abuf2  = ws + 18874368;  // 524288
    float* mbout  = ws + 19398656;  // 524288

    float* f_cl  = S2;
    float* kinit = S3;
    float* key   = S4;
    float* val   = S5;
    float* query = S0;
    unsigned short* qh1b = (unsigned short*)S1;
    unsigned short* kh1b = (unsigned short*)S2;
    unsigned short* vh1b = (unsigned short*)S3;
    unsigned short* kh2b = (unsigned short*)S4;
    unsigned short* vh2b = (unsigned short*)S5;
    float* abuf  = S0;
    unsigned short* qh2b = (unsigned short*)S1;
    float* expandb = S0;
    float* dwout   = S1;
    float* separt  = S1 + 2097152;
    float* separt2 = S1 + 2097152 + 131072;
    float* sebuf   = S1 + 2097152 + 131072 + 8192;

    // stage 0: layout transforms + embeddings
    k_trans<<<dim3(96, 4, 6), 256, 0, stream>>>(feat, f_cl);
    k_embed<<<dim3(192, 6), 128, 0, stream>>>(I_inv, E_inv, ie_w, ce_w, kinit);
    k_query<<<dim3(256, 6), 128, 0, stream>>>(x, bev, be_w, be_b, E_inv, ce_w, query);
    // key/val dual MFMA GEMM: key = f.fp + kinit ; val = f.fl (f32 out)
    k_gemm_mfma<0,0,1,1,0><<<288, 256, 0, stream>>>(
        f_cl, fp_w, nullptr, kinit, fl_w, nullptr, val, key);

    // stage 1: q/k/v heads -> bf16 via MFMA (dual k/v for attn1+attn2)
    k_gemm_mfma<1,1,0,0,1><<<384, 256, 0, stream>>>(
        query, a1_qw, a1_qb, nullptr, nullptr, nullptr, nullptr, qh1b);
    k_gemm_mfma<1,1,0,1,1><<<288, 256, 0, stream>>>(
        key, a1_kw, a1_kb, nullptr, a2_kw, a2_kb, kh2b, kh1b);
    k_gemm_mfma<1,1,0,1,1><<<288, 256, 0, stream>>>(
        val, a1_vw, a1_vb, nullptr, a2_vw, a2_vb, vh2b, vh1b);
    k_attn_mfma<1><<<dim3(64, HEADS), 512, 0, stream>>>(qh1b, kh1b, vh1b, abuf);
    k_mean<<<512, 128, 0, stream>>>(abuf, amean);
    k_gemm<128,128,128,16,1, 0,1,0,0, 2,0,0, 0,0,0><<<256, 256, 0, stream>>>(
        amean, a1_pw, a1_pb, x, nullptr, nullptr, nullptr, nullptr, nullptr, qimg);
    k_gemm<128,256,256,16,2, 1,1,1,0, 0,0,0, 0,0,0><<<256, 256, 0, stream>>>(
        qimg, m1_w1, m1_b1, nullptr, nullptr, nullptr, nullptr, nullptr, nullptr, gbuf);
    k_gemm<256,128,128,16,1, 0,1,0,0, 1,0,0, 0,0,0><<<256, 256, 0, stream>>>(
        gbuf, m1_w2, m1_b2, qimg, nullptr, nullptr, nullptr, nullptr, nullptr, qimg);

    // stage 2: attn2 + MLP2
    k_gemm<128,128,128,16,1, 1,1,0,0, 0,0,0, 0,0,1><<<256, 256, 0, stream>>>(
        qimg, a2_qw, a2_qb, nullptr, nullptr, nullptr, nullptr, nullptr, nullptr, qh2b);
    k_attn_mfma<2><<<dim3(64, HEADS), 256, 0, stream>>>(qh2b, kh2b, vh2b, abuf2);
    k_gemm<128,128,128,16,1, 0,1,0,0, 1,0,0, 0,0,0><<<256, 256, 0, stream>>>(
        abuf2, a2_pw, a2_pb, qimg, nullptr, nullptr, nullptr, nullptr, nullptr, qimg2);
    k_gemm<128,256,256,16,2, 1,1,1,0, 0,0,0, 0,0,0><<<256, 256, 0, stream>>>(
        qimg2, m2_w1, m2_b1, nullptr, nullptr, nullptr, nullptr, nullptr, nullptr, gbuf);
    k_gemm<256,128,128,16,1, 0,1,0,0, 1,0,0, 0,0,0><<<256, 256, 0, stream>>>(
        gbuf, m2_w2, m2_b2, qimg2, nullptr, nullptr, nullptr, nullptr, nullptr, qimg2);

    // stage 3: postnorm(LN fused into expand) + MBConv + FFN + proj_out
    k_gemm<128,128,512,32,2, 1,0,1,1, 0,0,0, 0,1,0><<<dim3(128, 4), 256, 0, stream>>>(
        qimg2, mb_ew, nullptr, nullptr, nullptr, nullptr, nullptr, nullptr, zln, expandb);
    k_dwconv<<<256, 512, 0, stream>>>(expandb, mb_dw, dwout, separt);
    k_sered<<<16, 512, 0, stream>>>(separt, separt2);
    k_se<<<1, 512, 0, stream>>>(separt2, mb_s1w, mb_s1b, mb_s2w, mb_s2b, sebuf);
    k_gemm<512,128,128,16,1, 0,0,0,1, 1,0,1, 0,0,0><<<256, 256, 0, stream>>>(
        dwout, mb_pw, nullptr, zln, sebuf, nullptr, nullptr, nullptr, nullptr, mbout);
    k_gemm<128,256,256,16,2, 0,1,1,0, 0,0,0, 0,0,0><<<256, 256, 0, stream>>>(
        mbout, pm_w1, pm_b1, nullptr, nullptr, nullptr, nullptr, nullptr, nullptr, gbuf);
    k_gemm<256,128,128,16,1, 0,1,0,0, 1,0,0, 0,0,0><<<256, 256, 0, stream>>>(
        gbuf, pm_w2, pm_b2, mbout, nullptr, nullptr, nullptr, nullptr, nullptr, mbout);
    k_gemm<128,128,128,16,1, 0,1,1,0, 0,1,0, 0,0,0><<<256, 256, 0, stream>>>(
        mbout, po_w, po_b, nullptr, nullptr, nullptr, nullptr, nullptr, nullptr, (float*)d_out);
}

// Round 7
// 274.653 us; speedup vs baseline: 7.8425x; 1.2380x over previous
//
#include <hip/hip_runtime.h>
#include <math.h>

#define NV 6
#define FHH 32
#define FWW 96
#define PIMG (FHH*FWW)   // 3072
#define HH 64
#define WWD 64
#define PBEV (HH*WWD)    // 4096
#define HEADS 4
#define DHD 32
#define KROWS 288
#define BN_S 0.9999950000374996f
#define LN_EPS 1e-5f
#define ATT_SCALE 0.17677669529663687f  // 32^-0.5

typedef __attribute__((ext_vector_type(8))) short short8;
typedef __attribute__((ext_vector_type(4))) float f32x4;
typedef __attribute__((ext_vector_type(8))) unsigned short u16x8;

__device__ __forceinline__ float gelu_f(float x) {
    return 0.5f * x * (1.0f + erff(x * 0.70710678118654752f));
}

__device__ __forceinline__ unsigned short f2bf(float f) {
    union { float f; unsigned int u; } c; c.f = f;
    unsigned int r = (c.u + 0x7fffu + ((c.u >> 16) & 1u)) >> 16;
    return (unsigned short)r;
}

__device__ __forceinline__ float blockSum128(float v, float* red, int tid) {
    #pragma unroll
    for (int o = 32; o > 0; o >>= 1) v += __shfl_down(v, o, 64);
    __syncthreads();
    if ((tid & 63) == 0) red[tid >> 6] = v;
    __syncthreads();
    return red[0] + red[1];
}

// ---------- feature transpose + BN*relu : [n][128][3072] -> [n*3072][128] ----------
__global__ void k_trans(const float* __restrict__ feature, float* __restrict__ f_cl) {
    __shared__ float tile[32][33];
    int n = blockIdx.z, c0 = blockIdx.y * 32, p0 = blockIdx.x * 32;
    int tp = threadIdx.x & 31, tg = threadIdx.x >> 5;
    #pragma unroll
    for (int i = 0; i < 4; ++i) {
        int c = tg + 8 * i;
        tile[c][tp] = feature[((size_t)(n * 128 + c0 + c)) * PIMG + p0 + tp];
    }
    __syncthreads();
    int cw = threadIdx.x & 31, pg = threadIdx.x >> 5;
    #pragma unroll
    for (int i = 0; i < 4; ++i) {
        int p = pg + 8 * i;
        float v = fmaxf(tile[cw][p] * BN_S, 0.0f);
        f_cl[((size_t)(n * PIMG + p0 + p)) * 128 + c0 + cw] = v;
    }
}

// ---------- geometric image embedding -> kinit [n*3072][128] ----------
__global__ void k_embed(const float* __restrict__ I_inv, const float* __restrict__ E_inv,
                        const float* __restrict__ ie_w, const float* __restrict__ ce_w,
                        float* __restrict__ kinit) {
    const int TILE = 16;
    int n = blockIdx.y, p0 = blockIdx.x * TILE, t = threadIdx.x;
    __shared__ float red[2];
    const float* E  = E_inv + n * 16;
    const float* Ii = I_inv + n * 9;
    float cemb = E[3]  * ce_w[t*4+0] + E[7]  * ce_w[t*4+1]
               + E[11] * ce_w[t*4+2] + E[15] * ce_w[t*4+3];
    for (int pos = 0; pos < TILE; ++pos) {
        int p = p0 + pos;
        int h = p / FWW, w = p % FWW;
        float gx = (float)w * (768.0f / 95.0f);
        float gy = (float)h * (256.0f / 31.0f);
        float c0 = Ii[0]*gx + Ii[1]*gy + Ii[2];
        float c1 = Ii[3]*gx + Ii[4]*gy + Ii[5];
        float c2 = Ii[6]*gx + Ii[7]*gy + Ii[8];
        float d0 = E[0]*c0  + E[1]*c1  + E[2]*c2  + E[3];
        float d1 = E[4]*c0  + E[5]*c1  + E[6]*c2  + E[7];
        float d2 = E[8]*c0  + E[9]*c1  + E[10]*c2 + E[11];
        float d3 = E[12]*c0 + E[13]*c1 + E[14]*c2 + E[15];
        float emb = d0*ie_w[t*4+0] + d1*ie_w[t*4+1]
                  + d2*ie_w[t*4+2] + d3*ie_w[t*4+3] - cemb;
        float ss = blockSum128(emb * emb, red, t);
        kinit[((size_t)(n * PIMG + p)) * 128 + t] = emb / (sqrtf(ss) + 1e-7f);
    }
}

// ---------- query [n*4096][128] ----------
__global__ void k_query(const float* __restrict__ x, const float* __restrict__ bev,
                        const float* __restrict__ be_w, const float* __restrict__ be_b,
                        const float* __restrict__ E_inv, const float* __restrict__ ce_w,
                        float* __restrict__ query) {
    const int TILE = 16;
    int n = blockIdx.y, p0 = blockIdx.x * TILE, t = threadIdx.x;
    __shared__ float red[2];
    const float* E = E_inv + n * 16;
    float cemb = E[3]  * ce_w[t*4+0] + E[7]  * ce_w[t*4+1]
               + E[11] * ce_w[t*4+2] + E[15] * ce_w[t*4+3];
    float bw0 = be_w[t*2+0], bw1 = be_w[t*2+1], bb = be_b[t];
    for (int pos = 0; pos < TILE; ++pos) {
        int p = p0 + pos;
        float emb = bev[p]*bw0 + bev[PBEV + p]*bw1 + bb - cemb;
        float ss = blockSum128(emb * emb, red, t);
        float qv = emb / (sqrtf(ss) + 1e-7f) + x[(size_t)t * PBEV + p];
        query[((size_t)(n * PBEV + p)) * 128 + t] = qv;
    }
}

// ---------- MFMA 128x128 GEMM, 64 rows/block ----------
template<int LNF, int BIASF, int ADDM, int DUAL, int OUTBF, int QSCL>
__global__ __launch_bounds__(256)
void k_gemm_mfma(const float* __restrict__ A, const float* __restrict__ W,
                 const float* __restrict__ bias, const float* __restrict__ addb,
                 const float* __restrict__ W2, const float* __restrict__ bias2,
                 void* __restrict__ out2v, void* __restrict__ outv) {
    __shared__ unsigned short Al[64 * 136];
    __shared__ unsigned short Wl[128 * 136];
    const int t = threadIdx.x;
    const int rb = blockIdx.x * 64;
    const int lane = t & 63, wv = t >> 6;
    const int la = lane & 15, g = lane >> 4;

    {
        int r = t >> 2, seg = t & 3;
        const float* ar = A + (size_t)(rb + r) * 128 + seg * 32;
        float v[32];
        #pragma unroll
        for (int j = 0; j < 8; ++j)
            *(float4*)&v[4 * j] = *(const float4*)&ar[4 * j];
        if constexpr (LNF) {
            float s = 0.f;
            #pragma unroll
            for (int j = 0; j < 32; ++j) s += v[j];
            s += __shfl_xor(s, 1); s += __shfl_xor(s, 2);
            float mu = s * (1.0f / 128.0f);
            float ss = 0.f;
            #pragma unroll
            for (int j = 0; j < 32; ++j) { float d = v[j] - mu; ss += d * d; }
            ss += __shfl_xor(ss, 1); ss += __shfl_xor(ss, 2);
            float rs = rsqrtf(ss * (1.0f / 128.0f) + LN_EPS);
            #pragma unroll
            for (int j = 0; j < 32; ++j) v[j] = (v[j] - mu) * rs;
        }
        #pragma unroll
        for (int j8 = 0; j8 < 4; ++j8) {
            u16x8 o;
            #pragma unroll
            for (int j = 0; j < 8; ++j) o[j] = f2bf(v[8 * j8 + j]);
            *(u16x8*)&Al[r * 136 + seg * 32 + 8 * j8] = o;
        }
    }

    #pragma unroll 1
    for (int set = 0; set <= DUAL; ++set) {
        const float* Wc = set ? W2 : W;
        const float* bc = set ? bias2 : bias;
        void* ocv = set ? out2v : outv;
        if (set) __syncthreads();
        #pragma unroll
        for (int i = 0; i < 8; ++i) {
            int chunk = i * 256 + t;
            int c = chunk >> 4, k8 = chunk & 15;
            float4 v0 = *(const float4*)&Wc[(size_t)c * 128 + k8 * 8];
            float4 v1 = *(const float4*)&Wc[(size_t)c * 128 + k8 * 8 + 4];
            u16x8 o = { f2bf(v0.x), f2bf(v0.y), f2bf(v0.z), f2bf(v0.w),
                        f2bf(v1.x), f2bf(v1.y), f2bf(v1.z), f2bf(v1.w) };
            *(u16x8*)&Wl[c * 136 + k8 * 8] = o;
        }
        __syncthreads();

        short8 af[4];
        #pragma unroll
        for (int ks = 0; ks < 4; ++ks)
            af[ks] = *(short8*)&Al[(wv * 16 + la) * 136 + ks * 32 + g * 8];

        #pragma unroll
        for (int ct = 0; ct < 8; ++ct) {
            f32x4 acc = (f32x4){0.f, 0.f, 0.f, 0.f};
            #pragma unroll
            for (int ks = 0; ks < 4; ++ks) {
                short8 bf = *(short8*)&Wl[(ct * 16 + la) * 136 + ks * 32 + g * 8];
                acc = __builtin_amdgcn_mfma_f32_16x16x32_bf16(af[ks], bf, acc, 0, 0, 0);
            }
            int col = ct * 16 + la;
            float bv = 0.f;
            if constexpr (BIASF) bv = bc[col];
            #pragma unroll
            for (int r = 0; r < 4; ++r) {
                int row = rb + wv * 16 + g * 4 + r;
                float v = acc[r] + bv;
                if constexpr (QSCL) v *= ATT_SCALE;
                if constexpr (ADDM) { if (set == 0) v += addb[(size_t)row * 128 + col]; }
                if constexpr (OUTBF) ((unsigned short*)ocv)[(size_t)row * 128 + col] = f2bf(v);
                else                 ((float*)ocv)[(size_t)row * 128 + col] = v;
            }
        }
    }
}

// ---------- fused MFMA MLP: out = X + W2.gelu(W1.(LN?)(X) + b1) + b2 ----------
template<int LNF>
__global__ __launch_bounds__(256)
void k_mlp_mfma(const float* __restrict__ X, const float* __restrict__ W1,
                const float* __restrict__ b1, const float* __restrict__ W2,
                const float* __restrict__ b2, float* __restrict__ out) {
    __shared__ unsigned short Al[16 * 136];
    __shared__ unsigned short Wl[128 * 72];   // 9216 u16 (>= 64*136=8704)
    __shared__ unsigned short Gl[16 * 264];
    const int t = threadIdx.x;
    const int rb = blockIdx.x * 16;
    const int lane = t & 63, wv = t >> 6;
    const int la = lane & 15, g = lane >> 4;

    // stage A (16 rows x 128), optional LN: thread -> (row t>>4, 8-col seg t&15)
    {
        int r = t >> 4, seg = t & 15;
        const float* ar = X + (size_t)(rb + r) * 128 + seg * 8;
        float v[8];
        *(float4*)&v[0] = *(const float4*)&ar[0];
        *(float4*)&v[4] = *(const float4*)&ar[4];
        if constexpr (LNF) {
            float s = 0.f;
            #pragma unroll
            for (int j = 0; j < 8; ++j) s += v[j];
            s += __shfl_xor(s, 1); s += __shfl_xor(s, 2);
            s += __shfl_xor(s, 4); s += __shfl_xor(s, 8);
            float mu = s * (1.0f / 128.0f);
            float ss = 0.f;
            #pragma unroll
            for (int j = 0; j < 8; ++j) { float d = v[j] - mu; ss += d * d; }
            ss += __shfl_xor(ss, 1); ss += __shfl_xor(ss, 2);
            ss += __shfl_xor(ss, 4); ss += __shfl_xor(ss, 8);
            float rs = rsqrtf(ss * (1.0f / 128.0f) + LN_EPS);
            #pragma unroll
            for (int j = 0; j < 8; ++j) v[j] = (v[j] - mu) * rs;
        }
        u16x8 o;
        #pragma unroll
        for (int j = 0; j < 8; ++j) o[j] = f2bf(v[j]);
        *(u16x8*)&Al[r * 136 + seg * 8] = o;
    }
    __syncthreads();

    short8 af[4];
    #pragma unroll
    for (int ks = 0; ks < 4; ++ks)
        af[ks] = *(short8*)&Al[la * 136 + ks * 32 + g * 8];

    // GEMM1: 4 chunks of 64 hidden cols; each wave does one 16x16 tile per chunk
    #pragma unroll 1
    for (int cc = 0; cc < 4; ++cc) {
        {
            int c = t >> 2, s2 = t & 3;   // c 0..63 local col, s2: 32-k seg
            const float* wr = W1 + (size_t)(cc * 64 + c) * 128 + s2 * 32;
            #pragma unroll
            for (int j8 = 0; j8 < 4; ++j8) {
                float4 v0 = *(const float4*)&wr[8 * j8];
                float4 v1 = *(const float4*)&wr[8 * j8 + 4];
                u16x8 o = { f2bf(v0.x), f2bf(v0.y), f2bf(v0.z), f2bf(v0.w),
                            f2bf(v1.x), f2bf(v1.y), f2bf(v1.z), f2bf(v1.w) };
                *(u16x8*)&Wl[c * 136 + s2 * 32 + 8 * j8] = o;
            }
        }
        __syncthreads();
        f32x4 acc = (f32x4){0.f, 0.f, 0.f, 0.f};
        #pragma unroll
        for (int ks = 0; ks < 4; ++ks) {
            short8 bf = *(short8*)&Wl[(wv * 16 + la) * 136 + ks * 32 + g * 8];
            acc = __builtin_amdgcn_mfma_f32_16x16x32_bf16(af[ks], bf, acc, 0, 0, 0);
        }
        int col = cc * 64 + wv * 16 + la;
        float bv = b1[col];
        #pragma unroll
        for (int r = 0; r < 4; ++r)
            Gl[(g * 4 + r) * 264 + col] = f2bf(gelu_f(acc[r] + bv));
        __syncthreads();
    }

    // GEMM2: out[16][128] = G[16][256] . W2^T, 4 k-chunks of 64
    f32x4 acc2[2];
    acc2[0] = (f32x4){0.f, 0.f, 0.f, 0.f};
    acc2[1] = (f32x4){0.f, 0.f, 0.f, 0.f};
    #pragma unroll 1
    for (int kc = 0; kc < 4; ++kc) {
        {
            int c = t >> 1, s2 = t & 1;   // c 0..127 out col, s2: 32-k seg
            const float* wr = W2 + (size_t)c * 256 + kc * 64 + s2 * 32;
            #pragma unroll
            for (int j8 = 0; j8 < 4; ++j8) {
                float4 v0 = *(const float4*)&wr[8 * j8];
                float4 v1 = *(const float4*)&wr[8 * j8 + 4];
                u16x8 o = { f2bf(v0.x), f2bf(v0.y), f2bf(v0.z), f2bf(v0.w),
                            f2bf(v1.x), f2bf(v1.y), f2bf(v1.z), f2bf(v1.w) };
                *(u16x8*)&Wl[c * 72 + s2 * 32 + 8 * j8] = o;
            }
        }
        __syncthreads();
        #pragma unroll
        for (int half = 0; half < 2; ++half) {
            short8 pf = *(short8*)&Gl[la * 264 + kc * 64 + half * 32 + g * 8];
            #pragma unroll
            for (int ct = 0; ct < 2; ++ct) {
                short8 bf = *(short8*)&Wl[((wv * 2 + ct) * 16 + la) * 72 + half * 32 + g * 8];
                acc2[ct] = __builtin_amdgcn_mfma_f32_16x16x32_bf16(pf, bf, acc2[ct], 0, 0, 0);
            }
        }
        __syncthreads();
    }
    #pragma unroll
    for (int ct = 0; ct < 2; ++ct) {
        int col = (wv * 2 + ct) * 16 + la;
        float bv = b2[col];
        #pragma unroll
        for (int r = 0; r < 4; ++r) {
            int row = rb + g * 4 + r;
            out[(size_t)row * 128 + col] = acc2[ct][r] + bv + X[(size_t)row * 128 + col];
        }
    }
}

// ---------- generic tiled f32 GEMM (256 threads) ----------
template<int NI, int NO, int NOT, int BR, int MR, int LNF, int BIASF, int ACT,
         int SCL, int ADDM, int STM, int ASCL, int DUAL, int WRLN, int OUTBF>
__global__ __launch_bounds__(256)
void k_gemm(const float* __restrict__ A, const float* __restrict__ W,
            const float* __restrict__ bias, const float* __restrict__ addb,
            const float* __restrict__ ascale, const float* __restrict__ W2,
            const float* __restrict__ bias2, void* __restrict__ out2v,
            float* __restrict__ aux, void* __restrict__ outv) {
    constexpr int CG = NO / 8;
    constexpr int RG = 256 / CG;
    static_assert(RG * MR == BR, "tile mismatch");
    __shared__ float a_lds[BR][NI + 4];
    __shared__ float w_lds[32][NO + 4];
    const int t  = threadIdx.x;
    const int rb = blockIdx.x * BR;
    const int co = blockIdx.y * NO;

    constexpr int AF4 = (BR * NI / 4) / 256;
    #pragma unroll
    for (int i = 0; i < AF4; ++i) {
        int f4 = i * 256 + t;
        int row = f4 / (NI / 4), q = f4 % (NI / 4);
        float4 v = *(const float4*)&A[(size_t)(rb + row) * NI + 4 * q];
        if constexpr (ASCL) {
            float4 sc = *(const float4*)&ascale[4 * q];
            v.x *= sc.x; v.y *= sc.y; v.z *= sc.z; v.w *= sc.w;
        }
        *(float4*)&a_lds[row][4 * q] = v;
    }
    __syncthreads();

    if constexpr (LNF) {
        constexpr int TPR = 256 / BR;
        constexpr int CPT = NI / TPR;
        int row = t / TPR, seg = t % TPR, base = seg * CPT;
        float sum = 0.f;
        #pragma unroll
        for (int j = 0; j < CPT / 4; ++j) {
            float4 v = *(float4*)&a_lds[row][base + 4 * j];
            sum += (v.x + v.y) + (v.z + v.w);
        }
        #pragma unroll
        for (int o = 1; o < TPR; o <<= 1) sum += __shfl_xor(sum, o, 64);
        float mu = sum * (1.0f / NI);
        float ss = 0.f;
        #pragma unroll
        for (int j = 0; j < CPT / 4; ++j) {
            float4 v = *(float4*)&a_lds[row][base + 4 * j];
            float a = v.x - mu, b = v.y - mu, c = v.z - mu, d = v.w - mu;
            ss += (a * a + b * b) + (c * c + d * d);
        }
        #pragma unroll
        for (int o = 1; o < TPR; o <<= 1) ss += __shfl_xor(ss, o, 64);
        float rs = rsqrtf(ss * (1.0f / NI) + LN_EPS);
        #pragma unroll
        for (int j = 0; j < CPT / 4; ++j) {
            float4 v = *(float4*)&a_lds[row][base + 4 * j];
            v.x = (v.x - mu) * rs; v.y = (v.y - mu) * rs;
            v.z = (v.z - mu) * rs; v.w = (v.w - mu) * rs;
            *(float4*)&a_lds[row][base + 4 * j] = v;
            if constexpr (WRLN) {
                if (blockIdx.y == 0)
                    *(float4*)&aux[(size_t)(rb + row) * NI + base + 4 * j] = v;
            }
        }
        __syncthreads();
    }

    const int cg = t % CG, rg = t / CG;
    const int c0 = cg * 8, r0 = rg * MR;
    constexpr int NCH = NI / 32;
    constexpr int WF4 = NO / 32;

    #pragma unroll 1
    for (int set = 0; set <= DUAL; ++set) {
        const float* Wc = set ? W2 : W;
        const float* bc = set ? bias2 : bias;
        void* ocv = set ? out2v : outv;
        float acc[MR][8];
        #pragma unroll
        for (int i = 0; i < MR; ++i)
            #pragma unroll
            for (int j = 0; j < 8; ++j) acc[i][j] = 0.f;

        #pragma unroll 1
        for (int ch = 0; ch < NCH; ++ch) {
            int k0 = ch * 32;
            if (ch || set) __syncthreads();
            #pragma unroll
            for (int i = 0; i < WF4; ++i) {
                int f4 = i * 256 + t;
                int c = f4 >> 3, kq = f4 & 7;
                float4 v = *(const float4*)&Wc[(size_t)(co + c) * NI + k0 + 4 * kq];
                w_lds[4 * kq + 0][c] = v.x; w_lds[4 * kq + 1][c] = v.y;
                w_lds[4 * kq + 2][c] = v.z; w_lds[4 * kq + 3][c] = v.w;
            }
            __syncthreads();
            #pragma unroll
            for (int kk = 0; kk < 32; ++kk) {
                float4 w0 = *(float4*)&w_lds[kk][c0];
                float4 w1 = *(float4*)&w_lds[kk][c0 + 4];
                #pragma unroll
                for (int i = 0; i < MR; ++i) {
                    float a = a_lds[r0 + i][k0 + kk];
                    acc[i][0] += a * w0.x; acc[i][1] += a * w0.y;
                    acc[i][2] += a * w0.z; acc[i][3] += a * w0.w;
                    acc[i][4] += a * w1.x; acc[i][5] += a * w1.y;
                    acc[i][6] += a * w1.z; acc[i][7] += a * w1.w;
                }
            }
        }

        float bi[8];
        if constexpr (BIASF) {
            #pragma unroll
            for (int j = 0; j < 8; ++j) bi[j] = bc[co + c0 + j];
        }
        #pragma unroll
        for (int i = 0; i < MR; ++i)
            #pragma unroll
            for (int j = 0; j < 8; ++j) {
                float v = acc[i][j];
                if constexpr (BIASF) v += bi[j];
                if constexpr (SCL == 1) v *= BN_S;
                if constexpr (SCL == 2) v *= ATT_SCALE;
                if constexpr (ACT)   v = gelu_f(v);
                acc[i][j] = v;
            }
        if constexpr (ADDM == 1) {
            if (set == 0) {
                #pragma unroll
                for (int i = 0; i < MR; ++i) {
                    float4 a0 = *(const float4*)&addb[(size_t)(rb + r0 + i) * NOT + co + c0];
                    float4 a1 = *(const float4*)&addb[(size_t)(rb + r0 + i) * NOT + co + c0 + 4];
                    acc[i][0] += a0.x; acc[i][1] += a0.y; acc[i][2] += a0.z; acc[i][3] += a0.w;
                    acc[i][4] += a1.x; acc[i][5] += a1.y; acc[i][6] += a1.z; acc[i][7] += a1.w;
                }
            }
        }
        if constexpr (ADDM == 2) {
            if (set == 0) {
                #pragma unroll
                for (int j = 0; j < 8; ++j)
                    #pragma unroll
                    for (int i = 0; i < MR; ++i)
                        acc[i][j] += addb[(size_t)(co + c0 + j) * PBEV + rb + r0 + i];
            }
        }
        if constexpr (STM == 0) {
            if constexpr (OUTBF) {
                unsigned short* ob = (unsigned short*)ocv;
                #pragma unroll
                for (int i = 0; i < MR; ++i) {
                    u16x8 o;
                    #pragma unroll
                    for (int j = 0; j < 8; ++j) o[j] = f2bf(acc[i][j]);
                    *(u16x8*)&ob[(size_t)(rb + r0 + i) * NOT + co + c0] = o;
                }
            } else {
                float* oc = (float*)ocv;
                #pragma unroll
                for (int i = 0; i < MR; ++i) {
                    float4 o0 = {acc[i][0], acc[i][1], acc[i][2], acc[i][3]};
                    float4 o1 = {acc[i][4], acc[i][5], acc[i][6], acc[i][7]};
                    *(float4*)&oc[(size_t)(rb + r0 + i) * NOT + co + c0]     = o0;
                    *(float4*)&oc[(size_t)(rb + r0 + i) * NOT + co + c0 + 4] = o1;
                }
            }
        } else {
            float* oc = (float*)ocv;
            #pragma unroll
            for (int j = 0; j < 8; ++j)
                #pragma unroll
                for (int i = 0; i < MR; ++i)
                    oc[(size_t)(co + c0 + j) * PBEV + rb + r0 + i] = acc[i][j];
        }
    }
}

// ---------- MFMA flash attention, max-free softmax (qh pre-scaled by ATT_SCALE) ----------
template<int MODE>
__global__ __launch_bounds__(MODE == 1 ? 512 : 256)
void k_attn_mfma(const unsigned short* __restrict__ qh, const unsigned short* __restrict__ kh,
                 const unsigned short* __restrict__ vh, float* __restrict__ aout) {
    constexpr int WAVES = (MODE == 1) ? 8 : 4;
    constexpr int QTPW  = (MODE == 1) ? 3 : 1;
    constexpr int T = WAVES * 64;
    const int l = blockIdx.x, m = blockIdx.y;
    const int xw = l >> 3, yw = l & 7;
    const int t = threadIdx.x;
    const int lane = t & 63, wv = t >> 6;
    const int la = lane & 15, g = lane >> 4;

    __shared__ unsigned short Kl[KROWS * 40];
    __shared__ unsigned short Vt[32 * 312];
    __shared__ unsigned short Pl[WAVES * QTPW * 640];

    for (int i = t; i < KROWS * 4; i += T) {
        int row = i >> 2, seg = i & 3;
        int n = row / 48, kk = row % 48;
        int k1 = kk / 12, k2 = kk % 12;
        int h, w;
        if (MODE == 1) { h = xw * 4 + k1;  w = yw * 12 + k2; }
        else           { h = k1 * 8 + xw;  w = k2 * 8 + yw;  }
        size_t src = ((size_t)(n * PIMG + h * FWW + w)) * 128 + m * DHD + seg * 8;
        short8 kv = *(const short8*)&kh[src];
        *(short8*)&Kl[row * 40 + seg * 8] = kv;
        short8 vv = *(const short8*)&vh[src];
        #pragma unroll
        for (int j = 0; j < 8; ++j)
            Vt[(seg * 8 + j) * 312 + row] = (unsigned short)vv[j];
    }

    short8 qf[QTPW];
    #pragma unroll
    for (int qt = 0; qt < QTPW; ++qt) {
        int q = (wv * QTPW + qt) * 16 + la;
        int row;
        if (MODE == 1) {
            int n = q >> 6, ww = q & 63;
            row = n * PBEV + (xw * 8 + (ww >> 3)) * 64 + yw * 8 + (ww & 7);
        } else {
            row = ((q >> 3) * 8 + xw) * 64 + (q & 7) * 8 + yw;
        }
        qf[qt] = *(const short8*)&qh[(size_t)row * 128 + m * DHD + g * 8];
    }
    __syncthreads();

    f32x4 acc[QTPW][2];
    float srow[QTPW][4];
    #pragma unroll
    for (int qt = 0; qt < QTPW; ++qt) {
        acc[qt][0] = (f32x4){0.f, 0.f, 0.f, 0.f};
        acc[qt][1] = (f32x4){0.f, 0.f, 0.f, 0.f};
        #pragma unroll
        for (int r = 0; r < 4; ++r) srow[qt][r] = 0.f;
    }
    unsigned short* Pw = Pl + wv * QTPW * 640;

    #pragma unroll 1
    for (int c = 0; c < 9; ++c) {
        const int kk0 = c * 32;
        short8 kf0 = *(short8*)&Kl[(kk0 + la) * 40 + g * 8];
        short8 kf1 = *(short8*)&Kl[(kk0 + 16 + la) * 40 + g * 8];
        f32x4 S[QTPW][2];
        #pragma unroll
        for (int qt = 0; qt < QTPW; ++qt) {
            S[qt][0] = __builtin_amdgcn_mfma_f32_16x16x32_bf16(qf[qt], kf0, (f32x4){0.f,0.f,0.f,0.f}, 0, 0, 0);
            S[qt][1] = __builtin_amdgcn_mfma_f32_16x16x32_bf16(qf[qt], kf1, (f32x4){0.f,0.f,0.f,0.f}, 0, 0, 0);
        }
        // max-free: P = exp(S); per-thread partial row sums, no cross-lane ops in loop
        #pragma unroll
        for (int qt = 0; qt < QTPW; ++qt) {
            #pragma unroll
            for (int r = 0; r < 4; ++r) {
                float pa = __expf(S[qt][0][r]);
                float pb = __expf(S[qt][1][r]);
                srow[qt][r] += pa + pb;
                int prow = g * 4 + r;
                Pw[qt * 640 + prow * 40 + la]      = f2bf(pa);
                Pw[qt * 640 + prow * 40 + 16 + la] = f2bf(pb);
            }
        }
        asm volatile("s_waitcnt lgkmcnt(0)" ::: "memory");
        __builtin_amdgcn_sched_barrier(0);
        short8 vf0 = *(short8*)&Vt[la * 312 + kk0 + g * 8];
        short8 vf1 = *(short8*)&Vt[(16 + la) * 312 + kk0 + g * 8];
        #pragma unroll
        for (int qt = 0; qt < QTPW; ++qt) {
            short8 pf = *(short8*)&Pw[qt * 640 + la * 40 + g * 8];
            acc[qt][0] = __builtin_amdgcn_mfma_f32_16x16x32_bf16(pf, vf0, acc[qt][0], 0, 0, 0);
            acc[qt][1] = __builtin_amdgcn_mfma_f32_16x16x32_bf16(pf, vf1, acc[qt][1], 0, 0, 0);
        }
    }

    #pragma unroll
    for (int qt = 0; qt < QTPW; ++qt) {
        #pragma unroll
        for (int r = 0; r < 4; ++r) {
            float s = srow[qt][r];
            s += __shfl_xor(s, 1);
            s += __shfl_xor(s, 2);
            s += __shfl_xor(s, 4);
            s += __shfl_xor(s, 8);
            float inv = 1.0f / s;
            int q = (wv * QTPW + qt) * 16 + g * 4 + r;
            size_t orow;
            if (MODE == 1) {
                int n = q >> 6, ww = q & 63;
                orow = (size_t)(l * 64 + ww) * 6 + n;
            } else {
                orow = (size_t)(((q >> 3) * 8 + xw) * 64 + (q & 7) * 8 + yw);
            }
            float* ap = aout + orow * 128 + m * DHD;
            ap[la]      = acc[qt][0][r] * inv;
            ap[16 + la] = acc[qt][1][r] * inv;
        }
    }
}

// ---------- mean over 6 views + window->hw permute ----------
__global__ void k_mean(const float* __restrict__ abuf, float* __restrict__ amean) {
    int t = threadIdx.x;
    for (int rr = 0; rr < 8; ++rr) {
        int hw = blockIdx.x * 8 + rr;
        int h = hw >> 6, w = hw & 63;
        int xw = h >> 3, w1 = h & 7, yw = w >> 3, w2 = w & 7;
        int l = xw * 8 + yw, ww = w1 * 8 + w2;
        const float* src = abuf + ((size_t)(l * 64 + ww)) * 6 * 128;
        float s = 0.f;
        #pragma unroll
        for (int n = 0; n < 6; ++n) s += src[n * 128 + t];
        amean[(size_t)hw * 128 + t] = s * (1.0f / 6.0f);
    }
}

// ---------- depthwise 3x3 + gelu + SE partials ----------
__global__ void k_dwconv(const float* __restrict__ ex, const float* __restrict__ dwgt,
                         float* __restrict__ dwout, float* __restrict__ separt) {
    const int TILE = 16;
    int ch = threadIdx.x;
    int hw0 = blockIdx.x * TILE;
    float wreg[9];
    #pragma unroll
    for (int i = 0; i < 9; ++i) wreg[i] = dwgt[ch * 9 + i];
    float sacc = 0.f;
    for (int ti = 0; ti < TILE; ++ti) {
        int hw = hw0 + ti;
        int h = hw >> 6, w = hw & 63;
        float s = 0.f;
        #pragma unroll
        for (int dy = -1; dy <= 1; ++dy) {
            int h2 = h + dy;
            if (h2 < 0 || h2 >= 64) continue;
            #pragma unroll
            for (int dx = -1; dx <= 1; ++dx) {
                int w2 = w + dx;
                if (w2 < 0 || w2 >= 64) continue;
                s += ex[((size_t)(h2 * 64 + w2)) * 512 + ch] * wreg[(dy + 1) * 3 + (dx + 1)];
            }
        }
        float o = gelu_f(s * BN_S);
        dwout[(size_t)hw * 512 + ch] = o;
        sacc += o;
    }
    separt[(size_t)blockIdx.x * 512 + ch] = sacc;
}

// ---------- SE reduce stage 1: [256][512] -> [16][512] ----------
__global__ void k_sered(const float* __restrict__ separt, float* __restrict__ separt2) {
    int t = threadIdx.x, bb = blockIdx.x;
    float s = 0.f;
    #pragma unroll
    for (int i = 0; i < 16; ++i)
        s += separt[(size_t)(bb * 16 + i) * 512 + t];
    separt2[(size_t)bb * 512 + t] = s;
}

// ---------- SE final ----------
__global__ void k_se(const float* __restrict__ separt2,
                     const float* __restrict__ s1w, const float* __restrict__ s1b,
                     const float* __restrict__ s2w, const float* __restrict__ s2b,
                     float* __restrict__ se) {
    __shared__ float mean[512];
    __shared__ float s1[32];
    int t = threadIdx.x;
    float s = 0.f;
    #pragma unroll
    for (int b = 0; b < 16; ++b) s += separt2[b * 512 + t];
    mean[t] = s * (1.0f / 4096.0f);
    __syncthreads();
    int u = t >> 4, seg = t & 15;
    float acc = 0.f;
    #pragma unroll
    for (int j = 0; j < 32; ++j) {
        int c = seg + 16 * j;
        acc += mean[c] * s1w[u * 512 + c];
    }
    acc += __shfl_xor(acc, 1); acc += __shfl_xor(acc, 2);
    acc += __shfl_xor(acc, 4); acc += __shfl_xor(acc, 8);
    if (seg == 0) s1[u] = gelu_f(acc + s1b[u]);
    __syncthreads();
    float a2 = s2b[t];
    #pragma unroll
    for (int j = 0; j < 32; ++j) a2 += s1[j] * s2w[t * 32 + j];
    se[t] = 1.0f / (1.0f + __expf(-a2));
}

extern "C" void kernel_launch(void* const* d_in, const int* in_sizes, int n_in,
                              void* d_out, int out_size, void* d_ws, size_t ws_size,
                              hipStream_t stream) {
    (void)in_sizes; (void)n_in; (void)out_size; (void)ws_size;
    const float* x      = (const float*)d_in[1];
    const float* feat   = (const float*)d_in[2];
    const float* I_inv  = (const float*)d_in[3];
    const float* E_inv  = (const float*)d_in[4];
    const float* bev    = (const float*)d_in[5];
    const float* fl_w   = (const float*)d_in[6];
    const float* fp_w   = (const float*)d_in[7];
    const float* be_w   = (const float*)d_in[8];
    const float* be_b   = (const float*)d_in[9];
    const float* ie_w   = (const float*)d_in[10];
    const float* ce_w   = (const float*)d_in[11];
    const float* a1_qw  = (const float*)d_in[12];
    const float* a1_qb  = (const float*)d_in[13];
    const float* a1_kw  = (const float*)d_in[14];
    const float* a1_kb  = (const float*)d_in[15];
    const float* a1_vw  = (const float*)d_in[16];
    const float* a1_vb  = (const float*)d_in[17];
    const float* a1_pw  = (const float*)d_in[18];
    const float* a1_pb  = (const float*)d_in[19];
    const float* a2_qw  = (const float*)d_in[20];
    const float* a2_qb  = (const float*)d_in[21];
    const float* a2_kw  = (const float*)d_in[22];
    const float* a2_kb  = (const float*)d_in[23];
    const float* a2_vw  = (const float*)d_in[24];
    const float* a2_vb  = (const float*)d_in[25];
    const float* a2_pw  = (const float*)d_in[26];
    const float* a2_pb  = (const float*)d_in[27];
    const float* m1_w1  = (const float*)d_in[28];
    const float* m1_b1  = (const float*)d_in[29];
    const float* m1_w2  = (const float*)d_in[30];
    const float* m1_b2  = (const float*)d_in[31];
    const float* m2_w1  = (const float*)d_in[32];
    const float* m2_b1  = (const float*)d_in[33];
    const float* m2_w2  = (const float*)d_in[34];
    const float* m2_b2  = (const float*)d_in[35];
    const float* mb_ew  = (const float*)d_in[36];
    const float* mb_dw  = (const float*)d_in[37];
    const float* mb_s1w = (const float*)d_in[38];
    const float* mb_s1b = (const float*)d_in[39];
    const float* mb_s2w = (const float*)d_in[40];
    const float* mb_s2b = (const float*)d_in[41];
    const float* mb_pw  = (const float*)d_in[42];
    const float* pm_w1  = (const float*)d_in[43];
    const float* pm_b1  = (const float*)d_in[44];
    const float* pm_w2  = (const float*)d_in[45];
    const float* pm_b2  = (const float*)d_in[46];
    const float* po_w   = (const float*)d_in[47];
    const float* po_b   = (const float*)d_in[48];

    float* ws = (float*)d_ws;
    float* S0 = ws + 0;         // query -> abuf -> expandb
    float* S1 = ws + 3145728;   // qh1b -> qh2b -> dwout+separt+separt2+sebuf
    float* S2 = ws + 6291456;   // f_cl -> kh1b
    float* S3 = ws + 8650752;   // kinit -> vh1b
    float* S4 = ws + 11010048;  // key -> kh2b (in-place)
    float* S5 = ws + 13369344;  // val -> vh2b (in-place)
    float* amean  = ws + 15728640;
    float* qimg   = ws + 16252928;
    float* qimg2  = ws + 17825792;
    float* zln    = ws + 18350080;
    float* abuf2  = ws + 18874368;
    float* mbout  = ws + 19398656;

    float* f_cl  = S2;
    float* kinit = S3;
    float* key   = S4;
    float* val   = S5;
    float* query = S0;
    unsigned short* qh1b = (unsigned short*)S1;
    unsigned short* kh1b = (unsigned short*)S2;
    unsigned short* vh1b = (unsigned short*)S3;
    unsigned short* kh2b = (unsigned short*)S4;
    unsigned short* vh2b = (unsigned short*)S5;
    float* abuf  = S0;
    unsigned short* qh2b = (unsigned short*)S1;
    float* expandb = S0;
    float* dwout   = S1;
    float* separt  = S1 + 2097152;
    float* separt2 = S1 + 2097152 + 131072;
    float* sebuf   = S1 + 2097152 + 131072 + 8192;

    // stage 0: layout transforms + embeddings
    k_trans<<<dim3(96, 4, 6), 256, 0, stream>>>(feat, f_cl);
    k_embed<<<dim3(192, 6), 128, 0, stream>>>(I_inv, E_inv, ie_w, ce_w, kinit);
    k_query<<<dim3(256, 6), 128, 0, stream>>>(x, bev, be_w, be_b, E_inv, ce_w, query);
    k_gemm_mfma<0,0,1,1,0,0><<<288, 256, 0, stream>>>(
        f_cl, fp_w, nullptr, kinit, fl_w, nullptr, val, key);

    // stage 1: q/k/v heads -> bf16 (q pre-scaled by ATT_SCALE)
    k_gemm_mfma<1,1,0,0,1,1><<<384, 256, 0, stream>>>(
        query, a1_qw, a1_qb, nullptr, nullptr, nullptr, nullptr, qh1b);
    k_gemm_mfma<1,1,0,1,1,0><<<288, 256, 0, stream>>>(
        key, a1_kw, a1_kb, nullptr, a2_kw, a2_kb, kh2b, kh1b);
    k_gemm_mfma<1,1,0,1,1,0><<<288, 256, 0, stream>>>(
        val, a1_vw, a1_vb, nullptr, a2_vw, a2_vb, vh2b, vh1b);
    k_attn_mfma<1><<<dim3(64, HEADS), 512, 0, stream>>>(qh1b, kh1b, vh1b, abuf);
    k_mean<<<512, 128, 0, stream>>>(abuf, amean);
    k_gemm<128,128,128,16,1, 0,1,0,0, 2,0,0, 0,0,0><<<256, 256, 0, stream>>>(
        amean, a1_pw, a1_pb, x, nullptr, nullptr, nullptr, nullptr, nullptr, qimg);
    k_mlp_mfma<1><<<256, 256, 0, stream>>>(qimg, m1_w1, m1_b1, m1_w2, m1_b2, qimg);

    // stage 2: attn2 + MLP2
    k_gemm<128,128,128,16,1, 1,1,0,2, 0,0,0, 0,0,1><<<256, 256, 0, stream>>>(
        qimg, a2_qw, a2_qb, nullptr, nullptr, nullptr, nullptr, nullptr, nullptr, qh2b);
    k_attn_mfma<2><<<dim3(64, HEADS), 256, 0, stream>>>(qh2b, kh2b, vh2b, abuf2);
    k_gemm<128,128,128,16,1, 0,1,0,0, 1,0,0, 0,0,0><<<256, 256, 0, stream>>>(
        abuf2, a2_pw, a2_pb, qimg, nullptr, nullptr, nullptr, nullptr, nullptr, qimg2);
    k_mlp_mfma<1><<<256, 256, 0, stream>>>(qimg2, m2_w1, m2_b1, m2_w2, m2_b2, qimg2);

    // stage 3: postnorm(LN fused into expand) + MBConv + FFN + proj_out
    k_gemm<128,128,512,32,2, 1,0,1,1, 0,0,0, 0,1,0><<<dim3(128, 4), 256, 0, stream>>>(
        qimg2, mb_ew, nullptr, nullptr, nullptr, nullptr, nullptr, nullptr, zln, expandb);
    k_dwconv<<<256, 512, 0, stream>>>(expandb, mb_dw, dwout, separt);
    k_sered<<<16, 512, 0, stream>>>(separt, separt2);
    k_se<<<1, 512, 0, stream>>>(separt2, mb_s1w, mb_s1b, mb_s2w, mb_s2b, sebuf);
    k_gemm<512,128,128,16,1, 0,0,0,1, 1,0,1, 0,0,0><<<256, 256, 0, stream>>>(
        dwout, mb_pw, nullptr, zln, sebuf, nullptr, nullptr, nullptr, nullptr, mbout);
    k_mlp_mfma<0><<<256, 256, 0, stream>>>(mbout, pm_w1, pm_b1, pm_w2, pm_b2, mbout);
    k_gemm<128,128,128,16,1, 0,1,1,0, 0,1,0, 0,0,0><<<256, 256, 0, stream>>>(
        mbout, po_w, po_b, nullptr, nullptr, nullptr, nullptr, nullptr, nullptr, (float*)d_out);
}